// Round 11
// baseline (128.793 us; speedup 1.0000x reference)
//
#include <hip/hip_runtime.h>
#include <math.h>

#define NCLS 80
#define PRE 1000
#define MAXD 100
#define THR_SCORE 0.05f
#define TFIX 0.98f             // fixed collection threshold (fast path)

#define SUBS 16                // sub-lists per class
#define SUBCAP 512             // depth per sub-list
#define K3B 2048               // collect blocks
#define BT 512                 // kAD block threads

typedef unsigned long long u64;

__device__ __forceinline__ u64 readlane64(u64 v, int l) {
  unsigned lo = (unsigned)__builtin_amdgcn_readlane((int)(unsigned)v, l);
  unsigned hi = (unsigned)__builtin_amdgcn_readlane((int)(unsigned)(v >> 32), l);
  return ((u64)hi << 32) | lo;
}

// =====================================================================
// K0: zero the push counters.
__global__ __launch_bounds__(256) void k0_init(unsigned* __restrict__ ccnt) {
  int i = blockIdx.x * 256 + threadIdx.x;
  if (i < NCLS * SUBS) ccnt[i] = 0u;
}

// K3: coalesced float4 pass; push candidates with s >= TFIX into sub-lists.
__global__ __launch_bounds__(256) void k3_collect(
    const float4* __restrict__ cls4, int total4,
    unsigned* __restrict__ ccnt, u64* __restrict__ cand)
{
  const int t = threadIdx.x;
  const int sub = blockIdx.x & (SUBS - 1);
  const int stride = gridDim.x * 256;
  for (int q = blockIdx.x * 256 + t; q < total4; q += stride) {
    float4 v = cls4[q];
    int c0 = 4 * (q % 20);
    unsigned a = (unsigned)(q / 20);
    float sv[4] = {v.x, v.y, v.z, v.w};
#pragma unroll
    for (int e = 0; e < 4; e++) {
      float s = sv[e];
      if (s >= TFIX) {
        int c = c0 + e;
        unsigned p = atomicAdd(&ccnt[c * SUBS + sub], 1u);
        if (p < SUBCAP)
          cand[((size_t)(c * SUBS + sub)) * SUBCAP + p] =
              ((u64)__float_as_uint(s) << 32) | (u64)(~a);
      }
    }
  }
}

// NMS over sorted rows in LDS; wave 0 of the block (caller guards t<64).
__device__ __forceinline__ void nms_scan64(
    int windows, const float4* box4, const float* area, const float* ssc,
    float* fx, float* fy, float* fXX, float* fYY, float* fAA,
    float* wx, float* wy, float* wXX, float* wYY, float* wAA,
    u64* s_keep, unsigned* s_pre, unsigned* s_total, int lane)
{
#pragma clang fp contract(off)
  const double MID = 0x1.000001p-1;
  unsigned acc = 0;
  int nf = 0;
  for (int w = 0; w < windows; w++) {
    const int r = w * 64 + lane;
    const float4 rb = box4[r];
    const float ra = area[r];
    bool dead = (ssc[r] == -INFINITY);
    for (int f = 0; f < nf; f++) {
      float ltx = fmaxf(rb.x, fx[f]);
      float lty = fmaxf(rb.y, fy[f]);
      float rbx = fminf(rb.z, fXX[f]);
      float rby = fminf(rb.w, fYY[f]);
      float ww = fmaxf(rbx - ltx, 0.0f);
      float hh = fmaxf(rby - lty, 0.0f);
      float inter = ww * hh;
      float denom = ((ra + fAA[f]) - inter) + 1e-8f;
      dead = dead | ((double)inter > MID * (double)denom);
    }
    u64 alive = __ballot(!dead);
    u64 F = 0ull;
    if (alive) {
      wx[lane] = rb.x; wy[lane] = rb.y; wXX[lane] = rb.z; wYY[lane] = rb.w; wAA[lane] = ra;
      u64 Rw = 0ull;
#pragma unroll 4
      for (int i = 0; i < 64; i++) {
        float ltx = fmaxf(wx[i], rb.x);
        float lty = fmaxf(wy[i], rb.y);
        float rbx = fminf(wXX[i], rb.z);
        float rby = fminf(wYY[i], rb.w);
        float ww = fmaxf(rbx - ltx, 0.0f);
        float hh = fmaxf(rby - lty, 0.0f);
        float inter = ww * hh;
        float denom = ((wAA[i] + ra) - inter) + 1e-8f;
        bool io = (double)inter > MID * (double)denom;
        u64 m = __ballot(io & (lane > i));
        Rw = (lane == i) ? m : Rw;
      }
      while (alive) {
        int b = __builtin_ctzll(alive);
        F |= (1ull << b);
        u64 rbw = readlane64(Rw, b);
        alive &= ~(rbw | (1ull << b));
      }
      if ((F >> lane) & 1ull) {
        int pos = nf + (int)__popcll(F & ((1ull << lane) - 1ull));
        if (pos < 192) {
          fx[pos] = rb.x; fy[pos] = rb.y; fXX[pos] = rb.z; fYY[pos] = rb.w; fAA[pos] = ra;
        }
      }
    }
    if (lane == 0) { s_keep[w] = F; s_pre[w] = acc; }
    acc += (unsigned)__popcll(F);
    nf += (int)__popcll(F);
    if (acc >= (unsigned)MAXD) break;
  }
  if (lane == 0) *s_total = acc;
}

__device__ __forceinline__ void decode_one(
    u64 key, const float4* a4, const float4* r4, float W, float H,
    float4* obox, float* oarea, float* ossc, unsigned* oidx)
{
#pragma clang fp contract(off)
  float sc; unsigned idx;
  if (key != 0ull) {
    sc = __uint_as_float((unsigned)(key >> 32));
    idx = ~((unsigned)(key & 0xFFFFFFFFull));
  } else {
    sc = -INFINITY; idx = 0u;
  }
  float4 av = a4[idx];
  float4 rv = r4[idx];
  float w = av.z - av.x, h = av.w - av.y;
  float cx = av.x + 0.5f * w, cy = av.y + 0.5f * h;
  float dx = rv.x * 0.1f, dy = rv.y * 0.1f, dw = rv.z * 0.2f, dh = rv.w * 0.2f;
  float pcx = cx + dx * w, pcy = cy + dy * h;
  float pw = (float)exp((double)dw) * w;
  float ph = (float)exp((double)dh) * h;
  float x1 = fminf(fmaxf(pcx - 0.5f * pw, 0.0f), W);
  float y1 = fminf(fmaxf(pcy - 0.5f * ph, 0.0f), H);
  float x2 = fminf(fmaxf(pcx + 0.5f * pw, 0.0f), W);
  float y2 = fminf(fmaxf(pcy + 0.5f * ph, 0.0f), H);
  *obox = make_float4(x1, y1, x2, y2);
  *oarea = (x2 - x1) * (y2 - y1);
  *ossc = sc;
  *oidx = idx;
}

// kAD: fast path = bit-hist prefix (>=256 rows) over global cand -> compact
// <=512 -> sort-512 -> decode -> early-exit NMS. Exact iff no sub-list
// overflow and kept>=100; otherwise complete in-kernel legacy path from cls.
__global__ __launch_bounds__(BT) void kAD_sort_nms(
    const unsigned* __restrict__ ccnt, const u64* __restrict__ cand,
    const float* __restrict__ cls, int A,
    const float* __restrict__ anch, const float* __restrict__ reg,
    const float* __restrict__ dist,
    const int* __restrict__ img_h_p, const int* __restrict__ img_w_p,
    float* __restrict__ out_s, float* __restrict__ out_id,
    float* __restrict__ out_b, float* __restrict__ out_d)
{
#pragma clang fp contract(off)
  const int c = blockIdx.x;
  const int t = threadIdx.x;
  const int lane = t & 63;
  // carved LDS: slow path uses full regions; fast path aliases prefixes
  __shared__ __align__(16) char smem[61440];
  u64* candS = (u64*)smem;                          // slow: 2048 u64 | fast M: 512 u64
  unsigned* histS = (unsigned*)(smem + 16384);      // slow: 4096 u32 | fast h2: 512 u32
  float4* box4 = (float4*)(smem + 32768);           // 1024 float4
  float* area  = (float*)(smem + 49152);            // 1024 f32
  float* ssc   = (float*)(smem + 53248);            // 1024 f32
  unsigned* sidb = (unsigned*)(smem + 57344);       // 1024 u32
  __shared__ unsigned scnt[SUBS];
  __shared__ unsigned s_ovf, s_abv, s_push, s_thr, s_cnt;
  __shared__ int s_mode, s_cb;
  __shared__ float fx[192], fy[192], fX[192], fY[192], fA[192];
  __shared__ float wx[64], wy[64], wX[64], wY[64], wA[64];
  __shared__ u64 s_keep[16];
  __shared__ unsigned s_pre[16];
  __shared__ unsigned s_total;

  if (t == 0) { s_ovf = 0u; s_abv = 0u; s_push = 0u; s_cnt = 0u; s_total = 0u; }
  if (t < 16) { s_keep[t] = 0ull; s_pre[t] = 0u; }
  histS[t] = 0u;            // h2[0..512)
  candS[t] = 0ull;          // M[0..512)
  __syncthreads();
  if (t < SUBS) {
    unsigned nn = ccnt[c * SUBS + t];
    scnt[t] = nn > SUBCAP ? SUBCAP : nn;
    if (nn > SUBCAP) atomicOr(&s_ovf, 1u);
  }
  __syncthreads();

  // ---- fast: 512-bin integer histogram over global cand keys ----
  for (int s = 0; s < SUBS; s++) {
    unsigned nn = scnt[s];
    const u64* src = cand + ((size_t)(c * SUBS + s)) * SUBCAP;
    for (unsigned i = t; i < nn; i += BT) {
      unsigned u = (unsigned)(src[i] >> 32);
      if (u >= 0x3F800000u) atomicAdd(&s_abv, 1u);
      else if (u >= 0x3F700000u) atomicAdd(&histS[(u - 0x3F700000u) >> 11], 1u);
      else atomicAdd(&histS[0], 1u);   // below-range guard (thr would exclude; short-fill safe)
    }
  }
  __syncthreads();
  if (t == 0) {
    unsigned a = s_abv;
    int r = 512;
    if (a < 256u) {
      for (int b = 511; b >= 0; b--) {
        a += histS[b];
        if (a >= 256u) { r = b; break; }
      }
      if (a < 256u) r = 0;
    }
    while (a > 512u && r < 512) { a -= histS[r]; r++; }
    s_thr = 0x3F700000u + ((unsigned)r << 11);
    s_mode = (s_ovf == 0u && a >= 1u && a <= 512u) ? 0 : 1;  // 0=fast, 1=slow
  }
  __syncthreads();

  const float W = (float)img_w_p[0];
  const float H = (float)img_h_p[0];
  const float4* a4 = (const float4*)anch;
  const float4* r4 = (const float4*)reg;
  bool slow = (s_mode != 0);

  if (!slow) {
    // ---- compact prefix into M ----
    const unsigned thr = s_thr;
    for (int s = 0; s < SUBS; s++) {
      unsigned nn = scnt[s];
      const u64* src = cand + ((size_t)(c * SUBS + s)) * SUBCAP;
      for (unsigned i = t; i < nn; i += BT) {
        u64 key = src[i];
        if ((unsigned)(key >> 32) >= thr) {
          unsigned p = atomicAdd(&s_push, 1u);
          if (p < 512u) candS[p] = key;
        }
      }
    }
    __syncthreads();
    // ---- hybrid bitonic sort of 512 desc (1 elem/thread; proven round-10) ----
    u64* SW = candS;
    {
      u64 v = SW[t];
#pragma unroll
      for (int k = 2; k <= 64; k <<= 1) {
#pragma unroll
        for (int j = k >> 1; j > 0; j >>= 1) {
          u64 p = __shfl_xor(v, j);
          bool iLower = (lane & j) == 0;
          bool desc = (t & k) == 0;
          bool keepMax = (iLower == desc);
          bool pGreater = p > v;
          v = (keepMax == pGreater) ? p : v;
        }
      }
      SW[t] = v;
      __syncthreads();
      for (int k = 128; k <= 512; k <<= 1) {
        for (int j = k >> 1; j >= 64; j >>= 1) {
          if ((t & j) == 0) {
            u64 a = SW[t], b = SW[t ^ j];
            bool desc = ((t & k) == 0);
            if (desc ? (a < b) : (a > b)) { SW[t] = b; SW[t ^ j] = a; }
          }
          __syncthreads();
        }
        u64 v2 = SW[t];
        bool desc = ((t & k) == 0);
#pragma unroll
        for (int j = 32; j > 0; j >>= 1) {
          u64 p = __shfl_xor(v2, j);
          bool iLower = (lane & j) == 0;
          bool keepMax = (iLower == desc);
          bool pGreater = p > v2;
          v2 = (keepMax == pGreater) ? p : v2;
        }
        SW[t] = v2;
        __syncthreads();
      }
    }
    // ---- decode row t ----
    decode_one(SW[t], a4, r4, W, H, &box4[t], &area[t], &ssc[t], &sidb[t]);
    __syncthreads();
    if (t < 64)
      nms_scan64(8, box4, area, ssc, fx, fy, fX, fY, fA, wx, wy, wX, wY, wA,
                 s_keep, s_pre, &s_total, lane);
    __syncthreads();
    slow = (s_total < (unsigned)MAXD);   // kept>=100 => provably exact
  }

  if (slow) {
    // ---- complete legacy path from cls (round-1 proven; correctness-only) ----
    if (t == 0) { s_cnt = 0u; s_total = 0u; }
    if (t < 16) { s_keep[t] = 0ull; s_pre[t] = 0u; }
    for (int i = t; i < 4096; i += BT) histS[i] = 0u;
    __syncthreads();
    for (int a = t; a < A; a += BT) {
      float s = cls[(size_t)a * NCLS + c];
      if (s > THR_SCORE) {
        int b = (int)(s * 4096.0f);
        b = b < 0 ? 0 : (b > 4095 ? 4095 : b);
        atomicAdd(&histS[b], 1u);
      }
    }
    __syncthreads();
    if (t == 0) {
      unsigned acc = 0;
      int cb = 0;
      for (int b = 4095; b >= 0; b--) {
        acc += histS[b];
        if (acc >= (unsigned)PRE) { cb = b; break; }
      }
      if (acc < (unsigned)PRE) cb = 0;
      while (acc > 2048u && cb < 4095) { acc -= histS[cb]; cb++; }
      s_cb = cb;
    }
    __syncthreads();
    const int cb = s_cb;
    for (int i = t; i < 2048; i += BT) candS[i] = 0ull;
    __syncthreads();
    for (int a = t; a < A; a += BT) {
      float s = cls[(size_t)a * NCLS + c];
      if (s > THR_SCORE) {
        int b = (int)(s * 4096.0f);
        b = b < 0 ? 0 : (b > 4095 ? 4095 : b);
        if (b >= cb) {
          unsigned p = atomicAdd(&s_cnt, 1u);
          if (p < 2048u)
            candS[p] = ((u64)__float_as_uint(s) << 32) | (u64)(~(unsigned)a);
        }
      }
    }
    __syncthreads();
    for (int k = 2; k <= 2048; k <<= 1) {
      for (int j = k >> 1; j > 0; j >>= 1) {
        for (int i = t; i < 2048; i += BT) {
          int ixj = i ^ j;
          if (ixj > i) {
            u64 va = candS[i], vb = candS[ixj];
            bool desc = ((i & k) == 0);
            if (desc ? (va < vb) : (va > vb)) { candS[i] = vb; candS[ixj] = va; }
          }
        }
        __syncthreads();
      }
    }
    for (int i = t; i < 1024; i += BT) {
      u64 key = (i < PRE) ? candS[i] : 0ull;
      decode_one(key, a4, r4, W, H, &box4[i], &area[i], &ssc[i], &sidb[i]);
      if (i >= PRE) ssc[i] = -INFINITY;
    }
    __syncthreads();
    if (t < 64)
      nms_scan64(16, box4, area, ssc, fx, fy, fX, fY, fA, wx, wy, wX, wY, wA,
                 s_keep, s_pre, &s_total, lane);
    __syncthreads();
  }

  // ---- output ----
  const unsigned total = s_total;
  for (int k = t; k < PRE; k += BT) {
    int w = k >> 6, b = k & 63;
    u64 kw = s_keep[w];
    if ((kw >> b) & 1ull) {
      unsigned rank = s_pre[w] + (unsigned)__popcll(kw & ((1ull << b) - 1ull));
      if (rank < MAXD) {
        int slot = c * MAXD + (int)rank;
        out_s[slot] = ssc[k];
        out_id[slot] = (float)c;
        ((float4*)out_b)[slot] = box4[k];
        out_d[slot] = dist[sidb[k]];
      }
    }
  }
  unsigned tk = total < (unsigned)MAXD ? total : (unsigned)MAXD;
  for (int r2 = (int)tk + t; r2 < MAXD; r2 += BT) {
    int slot = c * MAXD + r2;
    out_s[slot] = 0.0f;
    out_id[slot] = -1.0f;
    ((float4*)out_b)[slot] = make_float4(0.f, 0.f, 0.f, 0.f);
    out_d[slot] = 0.0f;
  }
}

// =====================================================================
// FALLBACK PATH (round-1, proven correct; used only if ws is too small)
// =====================================================================
#define NBUCK 4096
#define CANDF 2048

__global__ __launch_bounds__(256) void select_topk(
    const float* __restrict__ cls, int A,
    float* __restrict__ topscore, unsigned* __restrict__ topidx)
{
  const int c = blockIdx.x;
  const int t = threadIdx.x;
  __shared__ unsigned hist[NBUCK];
  __shared__ u64 cand[CANDF];
  __shared__ unsigned chunk[256];
  __shared__ int s_cb;
  __shared__ int s_cnt;
  for (int i = t; i < NBUCK; i += 256) hist[i] = 0u;
  if (t == 0) s_cnt = 0;
  __syncthreads();
  for (int a = t; a < A; a += 256) {
    float s = cls[(size_t)a * NCLS + c];
    if (s > THR_SCORE) {
      int b = (int)(s * (float)NBUCK);
      b = b < 0 ? 0 : (b > NBUCK - 1 ? NBUCK - 1 : b);
      atomicAdd(&hist[b], 1u);
    }
  }
  __syncthreads();
  {
    unsigned cs = 0;
    for (int i = 0; i < NBUCK / 256; i++) cs += hist[t * (NBUCK / 256) + i];
    chunk[t] = cs;
  }
  __syncthreads();
  if (t == 0) {
    unsigned acc = 0;
    int cb = 0;
    int ch;
    for (ch = 255; ch >= 0; ch--) {
      if (acc + chunk[ch] >= (unsigned)PRE) break;
      acc += chunk[ch];
    }
    if (ch < 0) cb = 0;
    else {
      const int bpc = NBUCK / 256;
      int b = ch * bpc + bpc - 1;
      for (; b >= ch * bpc; b--) { acc += hist[b]; if (acc >= (unsigned)PRE) break; }
      if (b < ch * bpc) b = ch * bpc;
      cb = b;
      while (acc > (unsigned)CANDF && cb < NBUCK - 1) { acc -= hist[cb]; cb++; }
    }
    s_cb = cb;
  }
  __syncthreads();
  const int cb = s_cb;
  for (int a = t; a < A; a += 256) {
    float s = cls[(size_t)a * NCLS + c];
    if (s > THR_SCORE) {
      int b = (int)(s * (float)NBUCK);
      b = b < 0 ? 0 : (b > NBUCK - 1 ? NBUCK - 1 : b);
      if (b >= cb) {
        int p = atomicAdd(&s_cnt, 1);
        if (p < CANDF)
          cand[p] = ((u64)__float_as_uint(s) << 32) | (u64)(~(unsigned)a);
      }
    }
  }
  __syncthreads();
  int n = s_cnt < CANDF ? s_cnt : CANDF;
  for (int i = n + t; i < CANDF; i += 256) cand[i] = 0ull;
  __syncthreads();
  for (int k = 2; k <= CANDF; k <<= 1) {
    for (int j = k >> 1; j > 0; j >>= 1) {
      for (int i = t; i < CANDF; i += 256) {
        int ixj = i ^ j;
        if (ixj > i) {
          u64 va = cand[i], vb = cand[ixj];
          bool desc = ((i & k) == 0);
          if (desc ? (va < vb) : (va > vb)) { cand[i] = vb; cand[ixj] = va; }
        }
      }
      __syncthreads();
    }
  }
  for (int k = t; k < PRE; k += 256) {
    u64 key = cand[k];
    float sc; unsigned idx;
    if (key != 0ull) { sc = __uint_as_float((unsigned)(key >> 32)); idx = ~((unsigned)(key & 0xFFFFFFFFull)); }
    else { sc = -INFINITY; idx = 0u; }
    topscore[c * PRE + k] = sc;
    topidx[c * PRE + k] = idx;
  }
}

__global__ __launch_bounds__(256) void nms_out(
    const float* __restrict__ anch, const float* __restrict__ reg,
    const float* __restrict__ dist,
    const float* __restrict__ topscore, const unsigned* __restrict__ topidx,
    const int* __restrict__ img_h_p, const int* __restrict__ img_w_p,
    float* __restrict__ out_s, float* __restrict__ out_id,
    float* __restrict__ out_b, float* __restrict__ out_d)
{
#pragma clang fp contract(off)
  const int c = blockIdx.x;
  const int t = threadIdx.x;
  __shared__ float bx[PRE], by[PRE], bX[PRE], bY[PRE], bar[PRE], ssc[PRE];
  __shared__ u64 supm[PRE * 16];
  __shared__ u64 keepw[16];
  __shared__ unsigned wpre[17];
  const float W = (float)img_w_p[0];
  const float H = (float)img_h_p[0];
  for (int k = t; k < PRE; k += 256) {
    float sc = topscore[c * PRE + k];
    unsigned idx = topidx[c * PRE + k];
    ssc[k] = sc;
    float a0 = anch[(size_t)idx * 4 + 0], a1 = anch[(size_t)idx * 4 + 1];
    float a2 = anch[(size_t)idx * 4 + 2], a3 = anch[(size_t)idx * 4 + 3];
    float r0 = reg[(size_t)idx * 4 + 0], r1 = reg[(size_t)idx * 4 + 1];
    float r2 = reg[(size_t)idx * 4 + 2], r3 = reg[(size_t)idx * 4 + 3];
    float w = a2 - a0, h = a3 - a1;
    float cx = a0 + 0.5f * w, cy = a1 + 0.5f * h;
    float dx = r0 * 0.1f, dy = r1 * 0.1f, dw = r2 * 0.2f, dh = r3 * 0.2f;
    float pcx = cx + dx * w, pcy = cy + dy * h;
    float pw = (float)exp((double)dw) * w;
    float ph = (float)exp((double)dh) * h;
    float x1 = fminf(fmaxf(pcx - 0.5f * pw, 0.0f), W);
    float y1 = fminf(fmaxf(pcy - 0.5f * ph, 0.0f), H);
    float x2 = fminf(fmaxf(pcx + 0.5f * pw, 0.0f), W);
    float y2 = fminf(fmaxf(pcy + 0.5f * ph, 0.0f), H);
    bx[k] = x1; by[k] = y1; bX[k] = x2; bY[k] = y2;
    bar[k] = (x2 - x1) * (y2 - y1);
  }
  __syncthreads();
  const int wave = t >> 6, lane = t & 63;
  for (int i = wave; i < PRE; i += 4) {
    float x1 = bx[i], y1 = by[i], X1 = bX[i], Y1 = bY[i], ai = bar[i];
    for (int g = 0; g < 16; g++) {
      int j = g * 64 + lane;
      bool s = false;
      if (j > i && j < PRE) {
        float ltx = fmaxf(x1, bx[j]);
        float lty = fmaxf(y1, by[j]);
        float rbx = fminf(X1, bX[j]);
        float rby = fminf(Y1, bY[j]);
        float ww = fmaxf(rbx - ltx, 0.0f);
        float hh = fmaxf(rby - lty, 0.0f);
        float inter = ww * hh;
        float iou = inter / ((ai + bar[j]) - inter + 1e-8f);
        s = iou > 0.5f;
      }
      u64 m = __ballot(s);
      if (lane == 0) supm[i * 16 + g] = m;
    }
  }
  __syncthreads();
  if (t < 64) {
    u64 kw = 0ull;
    if (t < 16) {
      for (int b = 0; b < 64; b++) {
        int k = t * 64 + b;
        if (k < PRE && ssc[k] != -INFINITY) kw |= (1ull << b);
      }
    }
    for (int i = 0; i < PRE; i++) {
      u64 ow = __shfl(kw, i >> 6);
      if ((ow >> (i & 63)) & 1ull) {
        if (t < 16) kw &= ~supm[i * 16 + t];
      }
    }
    if (t < 16) keepw[t] = kw;
  }
  __syncthreads();
  if (t == 0) {
    unsigned acc = 0;
    for (int w = 0; w < 16; w++) { wpre[w] = acc; acc += (unsigned)__popcll(keepw[w]); }
    wpre[16] = acc;
  }
  __syncthreads();
  const unsigned total = wpre[16];
  for (int k = t; k < PRE; k += 256) {
    int w = k >> 6, b = k & 63;
    u64 kw = keepw[w];
    if ((kw >> b) & 1ull) {
      unsigned rank = wpre[w] + (unsigned)__popcll(kw & ((1ull << b) - 1ull));
      if (rank < MAXD) {
        int slot = c * MAXD + (int)rank;
        out_s[slot] = ssc[k];
        out_id[slot] = (float)c;
        out_b[slot * 4 + 0] = bx[k];
        out_b[slot * 4 + 1] = by[k];
        out_b[slot * 4 + 2] = bX[k];
        out_b[slot * 4 + 3] = bY[k];
        out_d[slot] = dist[topidx[c * PRE + k]];
      }
    }
  }
  unsigned tk = total < MAXD ? total : MAXD;
  for (int r = (int)tk + t; r < MAXD; r += 256) {
    int slot = c * MAXD + r;
    out_s[slot] = 0.0f;
    out_id[slot] = -1.0f;
    out_b[slot * 4 + 0] = 0.0f; out_b[slot * 4 + 1] = 0.0f;
    out_b[slot * 4 + 2] = 0.0f; out_b[slot * 4 + 3] = 0.0f;
    out_d[slot] = 0.0f;
  }
}

// =====================================================================

static inline size_t align512(size_t x) { return (x + 511) & ~(size_t)511; }

extern "C" void kernel_launch(void* const* d_in, const int* in_sizes, int n_in,
                              void* d_out, int out_size, void* d_ws, size_t ws_size,
                              hipStream_t stream) {
  const float* cls  = (const float*)d_in[0];   // (1, A, 80)
  const float* reg  = (const float*)d_in[1];   // (1, A, 4)
  const float* dist = (const float*)d_in[2];   // (1, A, 1)
  const float* anch = (const float*)d_in[3];   // (1, A, 4)
  const int* img_h  = (const int*)d_in[4];
  const int* img_w  = (const int*)d_in[5];
  const int A = in_sizes[3] / 4;

  float* o = (float*)d_out;
  float* out_s  = o;                      // 8000
  float* out_id = o + NCLS * MAXD;        // 8000
  float* out_b  = o + 2 * NCLS * MAXD;    // 32000
  float* out_d  = o + 6 * NCLS * MAXD;    // 8000

  size_t off = 0;
  const size_t o_cand = off; off += align512((size_t)NCLS * SUBS * SUBCAP * sizeof(u64)); // 5.24 MB
  const size_t o_ccnt = off; off += align512((size_t)NCLS * SUBS * sizeof(unsigned));
  const size_t needed = off;

  if (ws_size >= needed) {
    char* ws = (char*)d_ws;
    u64* cand = (u64*)(ws + o_cand);
    unsigned* ccnt = (unsigned*)(ws + o_ccnt);
    const int total4 = A * 20;  // A*80/4

    k0_init<<<(NCLS * SUBS + 255) / 256, 256, 0, stream>>>(ccnt);
    k3_collect<<<K3B, 256, 0, stream>>>((const float4*)cls, total4, ccnt, cand);
    kAD_sort_nms<<<NCLS, BT, 0, stream>>>(ccnt, cand, cls, A, anch, reg, dist,
                                          img_h, img_w, out_s, out_id, out_b, out_d);
  } else {
    // fallback: proven round-1 path (needs only ~0.64 MB)
    float* topscore = (float*)d_ws;
    unsigned* topidx = (unsigned*)((char*)d_ws + NCLS * PRE * sizeof(float));
    select_topk<<<NCLS, 256, 0, stream>>>(cls, A, topscore, topidx);
    nms_out<<<NCLS, 256, 0, stream>>>(anch, reg, dist, topscore, topidx,
                                      img_h, img_w, out_s, out_id, out_b, out_d);
  }
}

// Round 12
// 81.892 us; speedup vs baseline: 1.5727x; 1.5727x over previous
//
#include <hip/hip_runtime.h>
#include <math.h>

#define NCLS 80
#define PRE 1000
#define MAXD 100
#define THR_SCORE 0.05f
#define TFIX 0.992f            // fixed collection threshold (fast path)

#define SUBS 16                // sub-lists per class
#define SUBCAP 512             // depth per sub-list
#define BT 512                 // kAD block threads
#define K3K 8                  // float4 loads per thread in k3 (MLP depth)

typedef unsigned long long u64;

__device__ __forceinline__ u64 readlane64(u64 v, int l) {
  unsigned lo = (unsigned)__builtin_amdgcn_readlane((int)(unsigned)v, l);
  unsigned hi = (unsigned)__builtin_amdgcn_readlane((int)(unsigned)(v >> 32), l);
  return ((u64)hi << 32) | lo;
}

// =====================================================================
// K0: zero the push counters.
__global__ __launch_bounds__(256) void k0_init(unsigned* __restrict__ ccnt) {
  int i = blockIdx.x * 256 + threadIdx.x;
  if (i < NCLS * SUBS) ccnt[i] = 0u;
}

// K3: tiled coalesced pass with 8-deep independent loads per thread.
__global__ __launch_bounds__(256) void k3_collect(
    const float4* __restrict__ cls4, int total4,
    unsigned* __restrict__ ccnt, u64* __restrict__ cand)
{
  const int t = threadIdx.x;
  const int sub = blockIdx.x & (SUBS - 1);
  const int base = blockIdx.x * (256 * K3K) + t;
  float4 v[K3K];
#pragma unroll
  for (int k = 0; k < K3K; k++) {
    int q = base + k * 256;
    v[k] = (q < total4) ? cls4[q] : make_float4(0.f, 0.f, 0.f, 0.f);
  }
#pragma unroll
  for (int k = 0; k < K3K; k++) {
    int q = base + k * 256;
    if (q < total4) {
      int c0 = 4 * (q % 20);
      unsigned a = (unsigned)(q / 20);
      float sv[4] = {v[k].x, v[k].y, v[k].z, v[k].w};
#pragma unroll
      for (int e = 0; e < 4; e++) {
        float s = sv[e];
        if (s >= TFIX) {
          int c = c0 + e;
          unsigned p = atomicAdd(&ccnt[c * SUBS + sub], 1u);
          if (p < SUBCAP)
            cand[((size_t)(c * SUBS + sub)) * SUBCAP + p] =
                ((u64)__float_as_uint(s) << 32) | (u64)(~a);
        }
      }
    }
  }
}

// NMS over sorted rows in LDS; wave 0 of the block (caller guards t<64).
__device__ __forceinline__ void nms_scan64(
    int windows, const float4* box4, const float* area, const float* ssc,
    float* fx, float* fy, float* fXX, float* fYY, float* fAA,
    float* wx, float* wy, float* wXX, float* wYY, float* wAA,
    u64* s_keep, unsigned* s_pre, unsigned* s_total, int lane)
{
#pragma clang fp contract(off)
  const double MID = 0x1.000001p-1;
  unsigned acc = 0;
  int nf = 0;
  for (int w = 0; w < windows; w++) {
    const int r = w * 64 + lane;
    const float4 rb = box4[r];
    const float ra = area[r];
    bool dead = (ssc[r] == -INFINITY);
    for (int f = 0; f < nf; f++) {
      float ltx = fmaxf(rb.x, fx[f]);
      float lty = fmaxf(rb.y, fy[f]);
      float rbx = fminf(rb.z, fXX[f]);
      float rby = fminf(rb.w, fYY[f]);
      float ww = fmaxf(rbx - ltx, 0.0f);
      float hh = fmaxf(rby - lty, 0.0f);
      float inter = ww * hh;
      float denom = ((ra + fAA[f]) - inter) + 1e-8f;
      dead = dead | ((double)inter > MID * (double)denom);
    }
    u64 alive = __ballot(!dead);
    u64 F = 0ull;
    if (alive) {
      wx[lane] = rb.x; wy[lane] = rb.y; wXX[lane] = rb.z; wYY[lane] = rb.w; wAA[lane] = ra;
      u64 Rw = 0ull;
#pragma unroll 4
      for (int i = 0; i < 64; i++) {
        float ltx = fmaxf(wx[i], rb.x);
        float lty = fmaxf(wy[i], rb.y);
        float rbx = fminf(wXX[i], rb.z);
        float rby = fminf(wYY[i], rb.w);
        float ww = fmaxf(rbx - ltx, 0.0f);
        float hh = fmaxf(rby - lty, 0.0f);
        float inter = ww * hh;
        float denom = ((wAA[i] + ra) - inter) + 1e-8f;
        bool io = (double)inter > MID * (double)denom;
        u64 m = __ballot(io & (lane > i));
        Rw = (lane == i) ? m : Rw;
      }
      while (alive) {
        int b = __builtin_ctzll(alive);
        F |= (1ull << b);
        u64 rbw = readlane64(Rw, b);
        alive &= ~(rbw | (1ull << b));
      }
      if ((F >> lane) & 1ull) {
        int pos = nf + (int)__popcll(F & ((1ull << lane) - 1ull));
        if (pos < 192) {
          fx[pos] = rb.x; fy[pos] = rb.y; fXX[pos] = rb.z; fYY[pos] = rb.w; fAA[pos] = ra;
        }
      }
    }
    if (lane == 0) { s_keep[w] = F; s_pre[w] = acc; }
    acc += (unsigned)__popcll(F);
    nf += (int)__popcll(F);
    if (acc >= (unsigned)MAXD) break;
  }
  if (lane == 0) *s_total = acc;
}

__device__ __forceinline__ void decode_one(
    u64 key, const float4* a4, const float4* r4, float W, float H,
    float4* obox, float* oarea, float* ossc, unsigned* oidx)
{
#pragma clang fp contract(off)
  float sc; unsigned idx;
  if (key != 0ull) {
    sc = __uint_as_float((unsigned)(key >> 32));
    idx = ~((unsigned)(key & 0xFFFFFFFFull));
  } else {
    sc = -INFINITY; idx = 0u;
  }
  float4 av = a4[idx];
  float4 rv = r4[idx];
  float w = av.z - av.x, h = av.w - av.y;
  float cx = av.x + 0.5f * w, cy = av.y + 0.5f * h;
  float dx = rv.x * 0.1f, dy = rv.y * 0.1f, dw = rv.z * 0.2f, dh = rv.w * 0.2f;
  float pcx = cx + dx * w, pcy = cy + dy * h;
  float pw = (float)exp((double)dw) * w;
  float ph = (float)exp((double)dh) * h;
  float x1 = fminf(fmaxf(pcx - 0.5f * pw, 0.0f), W);
  float y1 = fminf(fmaxf(pcy - 0.5f * ph, 0.0f), H);
  float x2 = fminf(fmaxf(pcx + 0.5f * pw, 0.0f), W);
  float y2 = fminf(fmaxf(pcy + 0.5f * ph, 0.0f), H);
  *obox = make_float4(x1, y1, x2, y2);
  *oarea = (x2 - x1) * (y2 - y1);
  *ossc = sc;
  *oidx = idx;
}

// kAD: flat LDS gather (n<=2048) -> 512-bin bit-hist -> parallel suffix-scan
// threshold (boundary-guarded) -> compact <=512 -> sort-512 -> decode ->
// early-exit NMS. Exact iff no overflow, thr above TFIX bin boundary, and
// kept>=100; otherwise complete in-kernel legacy path from cls.
__global__ __launch_bounds__(BT) void kAD_sort_nms(
    const unsigned* __restrict__ ccnt, const u64* __restrict__ cand,
    const float* __restrict__ cls, int A,
    const float* __restrict__ anch, const float* __restrict__ reg,
    const float* __restrict__ dist,
    const int* __restrict__ img_h_p, const int* __restrict__ img_w_p,
    float* __restrict__ out_s, float* __restrict__ out_id,
    float* __restrict__ out_b, float* __restrict__ out_d)
{
#pragma clang fp contract(off)
  const int c = blockIdx.x;
  const int t = threadIdx.x;
  const int lane = t & 63;
  // carved LDS: slow path uses full regions; fast path aliases prefixes
  __shared__ __align__(16) char smem[61440];
  u64* candS = (u64*)smem;                          // 2048 u64 (fast: gathered keys | slow: sort buf)
  unsigned* histS = (unsigned*)(smem + 16384);      // slow: 4096 u32 | fast: 512 u32 at head
  u64* M = (u64*)(smem + 18432);                    // fast: 512 u64 (inside histS slow region)
  float4* box4 = (float4*)(smem + 32768);           // 1024 float4
  float* area  = (float*)(smem + 49152);            // 1024 f32
  float* ssc   = (float*)(smem + 53248);            // 1024 f32
  unsigned* sidb = (unsigned*)(smem + 57344);       // 1024 u32
  __shared__ unsigned scnt[SUBS];
  __shared__ unsigned sbase[SUBS + 1];
  __shared__ unsigned s_ovf, s_abv, s_push, s_thr, s_cnt, s_r0, s_r1;
  __shared__ int s_mode, s_cb;
  __shared__ float fx[192], fy[192], fX[192], fY[192], fA[192];
  __shared__ float wx[64], wy[64], wX[64], wY[64], wA[64];
  __shared__ u64 s_keep[16];
  __shared__ unsigned s_pre[16];
  __shared__ unsigned s_total;

  if (t == 0) { s_ovf = 0u; s_abv = 0u; s_push = 0u; s_cnt = 0u; s_total = 0u;
                s_r0 = 0u; s_r1 = 512u; s_mode = 1; }
  if (t < 16) { s_keep[t] = 0ull; s_pre[t] = 0u; }
  histS[t] = 0u;         // fast hist bins [0,512)
  M[t] = 0ull;
  if (t < SUBS) {
    unsigned nn = ccnt[c * SUBS + t];
    scnt[t] = nn > SUBCAP ? SUBCAP : nn;
    if (nn > SUBCAP) atomicOr(&s_ovf, 1u);
  }
  __syncthreads();
  if (t == 0) {
    unsigned a = 0;
    for (int s = 0; s < SUBS; s++) { sbase[s] = a; a += scnt[s]; }
    sbase[SUBS] = a;
  }
  __syncthreads();
  const unsigned n = sbase[SUBS];
  const bool fits = (s_ovf == 0u) && (n >= 1u) && (n <= 2048u);

  const float W = (float)img_w_p[0];
  const float H = (float)img_h_p[0];
  const float4* a4 = (const float4*)anch;
  const float4* r4 = (const float4*)reg;
  bool slow = true;

  if (fits) {
    // ---- flat gather of all candidates into LDS ----
    for (unsigned g = t; g < n; g += BT) {
      int s = 0;
      while (g >= sbase[s + 1]) s++;
      candS[g] = cand[((size_t)(c * SUBS + s)) * SUBCAP + (g - sbase[s])];
    }
    __syncthreads();
    // ---- 512-bin integer histogram on float bits in [0x3F700000, 0x3F800000) ----
    for (unsigned i = t; i < n; i += BT) {
      unsigned u = (unsigned)(candS[i] >> 32);
      if (u >= 0x3F800000u) atomicAdd(&s_abv, 1u);
      else if (u >= 0x3F700000u) atomicAdd(&histS[(u - 0x3F700000u) >> 11], 1u);
      // u < 0x3F700000: below any admissible thr (guard) -> excluded; ignore.
    }
    __syncthreads();
    // ---- parallel suffix sum (Hillis-Steele, 9 rounds) ----
    for (int d = 1; d < 512; d <<= 1) {
      unsigned add = (t + d < 512) ? histS[t + d] : 0u;
      __syncthreads();
      histS[t] += add;
      __syncthreads();
    }
    // ---- threshold pick: r0 = max b with tot>=256; r = min b>=r0 with tot<=512 ----
    {
      unsigned tot = s_abv + histS[t];
      if (tot >= 256u) atomicMax(&s_r0, (unsigned)t);
      __syncthreads();
      if ((unsigned)t >= s_r0 && tot <= 512u) atomicMin(&s_r1, (unsigned)t);
      __syncthreads();
      if (t == 0) {
        unsigned r = s_r1;
        unsigned a = (r < 512u) ? (s_abv + histS[r]) : s_abv;
        unsigned thr = 0x3F700000u + (r << 11);
        unsigned guard = ((__float_as_uint(TFIX) >> 11) + 1u) << 11;  // first bin fully above TFIX
        s_thr = thr;
        s_cnt = a;
        s_mode = (a >= 1u && a <= 512u && thr >= guard) ? 0 : 1;
      }
      __syncthreads();
    }
    if (s_mode == 0) {
      // ---- compact prefix into M ----
      const unsigned thr = s_thr;
      for (unsigned i = t; i < n; i += BT) {
        u64 key = candS[i];
        if ((unsigned)(key >> 32) >= thr) {
          unsigned p = atomicAdd(&s_push, 1u);
          if (p < 512u) M[p] = key;
        }
      }
      __syncthreads();
      // ---- hybrid bitonic sort of 512 desc (1 elem/thread) ----
      u64* SW = M;
      {
        u64 v = SW[t];
#pragma unroll
        for (int k = 2; k <= 64; k <<= 1) {
#pragma unroll
          for (int j = k >> 1; j > 0; j >>= 1) {
            u64 p = __shfl_xor(v, j);
            bool iLower = (lane & j) == 0;
            bool desc = (t & k) == 0;
            bool keepMax = (iLower == desc);
            bool pGreater = p > v;
            v = (keepMax == pGreater) ? p : v;
          }
        }
        SW[t] = v;
        __syncthreads();
        for (int k = 128; k <= 512; k <<= 1) {
          for (int j = k >> 1; j >= 64; j >>= 1) {
            if ((t & j) == 0) {
              u64 a = SW[t], b = SW[t ^ j];
              bool desc = ((t & k) == 0);
              if (desc ? (a < b) : (a > b)) { SW[t] = b; SW[t ^ j] = a; }
            }
            __syncthreads();
          }
          u64 v2 = SW[t];
          bool desc = ((t & k) == 0);
#pragma unroll
          for (int j = 32; j > 0; j >>= 1) {
            u64 p = __shfl_xor(v2, j);
            bool iLower = (lane & j) == 0;
            bool keepMax = (iLower == desc);
            bool pGreater = p > v2;
            v2 = (keepMax == pGreater) ? p : v2;
          }
          SW[t] = v2;
          __syncthreads();
        }
      }
      // ---- decode row t ----
      decode_one(SW[t], a4, r4, W, H, &box4[t], &area[t], &ssc[t], &sidb[t]);
      __syncthreads();
      if (t < 64)
        nms_scan64(8, box4, area, ssc, fx, fy, fX, fY, fA, wx, wy, wX, wY, wA,
                   s_keep, s_pre, &s_total, lane);
      __syncthreads();
      slow = (s_total < (unsigned)MAXD);   // kept>=100 => provably exact
    }
  }

  if (slow) {
    // ---- complete legacy path from cls (round-1 proven; correctness-only) ----
    if (t == 0) { s_cnt = 0u; s_total = 0u; }
    if (t < 16) { s_keep[t] = 0ull; s_pre[t] = 0u; }
    for (int i = t; i < 4096; i += BT) histS[i] = 0u;
    __syncthreads();
    for (int a = t; a < A; a += BT) {
      float s = cls[(size_t)a * NCLS + c];
      if (s > THR_SCORE) {
        int b = (int)(s * 4096.0f);
        b = b < 0 ? 0 : (b > 4095 ? 4095 : b);
        atomicAdd(&histS[b], 1u);
      }
    }
    __syncthreads();
    if (t == 0) {
      unsigned acc = 0;
      int cb = 0;
      for (int b = 4095; b >= 0; b--) {
        acc += histS[b];
        if (acc >= (unsigned)PRE) { cb = b; break; }
      }
      if (acc < (unsigned)PRE) cb = 0;
      while (acc > 2048u && cb < 4095) { acc -= histS[cb]; cb++; }
      s_cb = cb;
    }
    __syncthreads();
    const int cb = s_cb;
    for (int i = t; i < 2048; i += BT) candS[i] = 0ull;
    __syncthreads();
    for (int a = t; a < A; a += BT) {
      float s = cls[(size_t)a * NCLS + c];
      if (s > THR_SCORE) {
        int b = (int)(s * 4096.0f);
        b = b < 0 ? 0 : (b > 4095 ? 4095 : b);
        if (b >= cb) {
          unsigned p = atomicAdd(&s_cnt, 1u);
          if (p < 2048u)
            candS[p] = ((u64)__float_as_uint(s) << 32) | (u64)(~(unsigned)a);
        }
      }
    }
    __syncthreads();
    for (int k = 2; k <= 2048; k <<= 1) {
      for (int j = k >> 1; j > 0; j >>= 1) {
        for (int i = t; i < 2048; i += BT) {
          int ixj = i ^ j;
          if (ixj > i) {
            u64 va = candS[i], vb = candS[ixj];
            bool desc = ((i & k) == 0);
            if (desc ? (va < vb) : (va > vb)) { candS[i] = vb; candS[ixj] = va; }
          }
        }
        __syncthreads();
      }
    }
    for (int i = t; i < 1024; i += BT) {
      u64 key = (i < PRE) ? candS[i] : 0ull;
      decode_one(key, a4, r4, W, H, &box4[i], &area[i], &ssc[i], &sidb[i]);
      if (i >= PRE) ssc[i] = -INFINITY;
    }
    __syncthreads();
    if (t < 64)
      nms_scan64(16, box4, area, ssc, fx, fy, fX, fY, fA, wx, wy, wX, wY, wA,
                 s_keep, s_pre, &s_total, lane);
    __syncthreads();
  }

  // ---- output ----
  const unsigned total = s_total;
  for (int k = t; k < PRE; k += BT) {
    int w = k >> 6, b = k & 63;
    u64 kw = s_keep[w];
    if ((kw >> b) & 1ull) {
      unsigned rank = s_pre[w] + (unsigned)__popcll(kw & ((1ull << b) - 1ull));
      if (rank < MAXD) {
        int slot = c * MAXD + (int)rank;
        out_s[slot] = ssc[k];
        out_id[slot] = (float)c;
        ((float4*)out_b)[slot] = box4[k];
        out_d[slot] = dist[sidb[k]];
      }
    }
  }
  unsigned tk = total < (unsigned)MAXD ? total : (unsigned)MAXD;
  for (int r2 = (int)tk + t; r2 < MAXD; r2 += BT) {
    int slot = c * MAXD + r2;
    out_s[slot] = 0.0f;
    out_id[slot] = -1.0f;
    ((float4*)out_b)[slot] = make_float4(0.f, 0.f, 0.f, 0.f);
    out_d[slot] = 0.0f;
  }
}

// =====================================================================
// FALLBACK PATH (round-1, proven correct; used only if ws is too small)
// =====================================================================
#define NBUCK 4096
#define CANDF 2048

__global__ __launch_bounds__(256) void select_topk(
    const float* __restrict__ cls, int A,
    float* __restrict__ topscore, unsigned* __restrict__ topidx)
{
  const int c = blockIdx.x;
  const int t = threadIdx.x;
  __shared__ unsigned hist[NBUCK];
  __shared__ u64 cand[CANDF];
  __shared__ unsigned chunk[256];
  __shared__ int s_cb;
  __shared__ int s_cnt;
  for (int i = t; i < NBUCK; i += 256) hist[i] = 0u;
  if (t == 0) s_cnt = 0;
  __syncthreads();
  for (int a = t; a < A; a += 256) {
    float s = cls[(size_t)a * NCLS + c];
    if (s > THR_SCORE) {
      int b = (int)(s * (float)NBUCK);
      b = b < 0 ? 0 : (b > NBUCK - 1 ? NBUCK - 1 : b);
      atomicAdd(&hist[b], 1u);
    }
  }
  __syncthreads();
  {
    unsigned cs = 0;
    for (int i = 0; i < NBUCK / 256; i++) cs += hist[t * (NBUCK / 256) + i];
    chunk[t] = cs;
  }
  __syncthreads();
  if (t == 0) {
    unsigned acc = 0;
    int cb = 0;
    int ch;
    for (ch = 255; ch >= 0; ch--) {
      if (acc + chunk[ch] >= (unsigned)PRE) break;
      acc += chunk[ch];
    }
    if (ch < 0) cb = 0;
    else {
      const int bpc = NBUCK / 256;
      int b = ch * bpc + bpc - 1;
      for (; b >= ch * bpc; b--) { acc += hist[b]; if (acc >= (unsigned)PRE) break; }
      if (b < ch * bpc) b = ch * bpc;
      cb = b;
      while (acc > (unsigned)CANDF && cb < NBUCK - 1) { acc -= hist[cb]; cb++; }
    }
    s_cb = cb;
  }
  __syncthreads();
  const int cb = s_cb;
  for (int a = t; a < A; a += 256) {
    float s = cls[(size_t)a * NCLS + c];
    if (s > THR_SCORE) {
      int b = (int)(s * (float)NBUCK);
      b = b < 0 ? 0 : (b > NBUCK - 1 ? NBUCK - 1 : b);
      if (b >= cb) {
        int p = atomicAdd(&s_cnt, 1);
        if (p < CANDF)
          cand[p] = ((u64)__float_as_uint(s) << 32) | (u64)(~(unsigned)a);
      }
    }
  }
  __syncthreads();
  int n = s_cnt < CANDF ? s_cnt : CANDF;
  for (int i = n + t; i < CANDF; i += 256) cand[i] = 0ull;
  __syncthreads();
  for (int k = 2; k <= CANDF; k <<= 1) {
    for (int j = k >> 1; j > 0; j >>= 1) {
      for (int i = t; i < CANDF; i += 256) {
        int ixj = i ^ j;
        if (ixj > i) {
          u64 va = cand[i], vb = cand[ixj];
          bool desc = ((i & k) == 0);
          if (desc ? (va < vb) : (va > vb)) { cand[i] = vb; cand[ixj] = va; }
        }
      }
      __syncthreads();
    }
  }
  for (int k = t; k < PRE; k += 256) {
    u64 key = cand[k];
    float sc; unsigned idx;
    if (key != 0ull) { sc = __uint_as_float((unsigned)(key >> 32)); idx = ~((unsigned)(key & 0xFFFFFFFFull)); }
    else { sc = -INFINITY; idx = 0u; }
    topscore[c * PRE + k] = sc;
    topidx[c * PRE + k] = idx;
  }
}

__global__ __launch_bounds__(256) void nms_out(
    const float* __restrict__ anch, const float* __restrict__ reg,
    const float* __restrict__ dist,
    const float* __restrict__ topscore, const unsigned* __restrict__ topidx,
    const int* __restrict__ img_h_p, const int* __restrict__ img_w_p,
    float* __restrict__ out_s, float* __restrict__ out_id,
    float* __restrict__ out_b, float* __restrict__ out_d)
{
#pragma clang fp contract(off)
  const int c = blockIdx.x;
  const int t = threadIdx.x;
  __shared__ float bx[PRE], by[PRE], bX[PRE], bY[PRE], bar[PRE], ssc[PRE];
  __shared__ u64 supm[PRE * 16];
  __shared__ u64 keepw[16];
  __shared__ unsigned wpre[17];
  const float W = (float)img_w_p[0];
  const float H = (float)img_h_p[0];
  for (int k = t; k < PRE; k += 256) {
    float sc = topscore[c * PRE + k];
    unsigned idx = topidx[c * PRE + k];
    ssc[k] = sc;
    float a0 = anch[(size_t)idx * 4 + 0], a1 = anch[(size_t)idx * 4 + 1];
    float a2 = anch[(size_t)idx * 4 + 2], a3 = anch[(size_t)idx * 4 + 3];
    float r0 = reg[(size_t)idx * 4 + 0], r1 = reg[(size_t)idx * 4 + 1];
    float r2 = reg[(size_t)idx * 4 + 2], r3 = reg[(size_t)idx * 4 + 3];
    float w = a2 - a0, h = a3 - a1;
    float cx = a0 + 0.5f * w, cy = a1 + 0.5f * h;
    float dx = r0 * 0.1f, dy = r1 * 0.1f, dw = r2 * 0.2f, dh = r3 * 0.2f;
    float pcx = cx + dx * w, pcy = cy + dy * h;
    float pw = (float)exp((double)dw) * w;
    float ph = (float)exp((double)dh) * h;
    float x1 = fminf(fmaxf(pcx - 0.5f * pw, 0.0f), W);
    float y1 = fminf(fmaxf(pcy - 0.5f * ph, 0.0f), H);
    float x2 = fminf(fmaxf(pcx + 0.5f * pw, 0.0f), W);
    float y2 = fminf(fmaxf(pcy + 0.5f * ph, 0.0f), H);
    bx[k] = x1; by[k] = y1; bX[k] = x2; bY[k] = y2;
    bar[k] = (x2 - x1) * (y2 - y1);
  }
  __syncthreads();
  const int wave = t >> 6, lane = t & 63;
  for (int i = wave; i < PRE; i += 4) {
    float x1 = bx[i], y1 = by[i], X1 = bX[i], Y1 = bY[i], ai = bar[i];
    for (int g = 0; g < 16; g++) {
      int j = g * 64 + lane;
      bool s = false;
      if (j > i && j < PRE) {
        float ltx = fmaxf(x1, bx[j]);
        float lty = fmaxf(y1, by[j]);
        float rbx = fminf(X1, bX[j]);
        float rby = fminf(Y1, bY[j]);
        float ww = fmaxf(rbx - ltx, 0.0f);
        float hh = fmaxf(rby - lty, 0.0f);
        float inter = ww * hh;
        float iou = inter / ((ai + bar[j]) - inter + 1e-8f);
        s = iou > 0.5f;
      }
      u64 m = __ballot(s);
      if (lane == 0) supm[i * 16 + g] = m;
    }
  }
  __syncthreads();
  if (t < 64) {
    u64 kw = 0ull;
    if (t < 16) {
      for (int b = 0; b < 64; b++) {
        int k = t * 64 + b;
        if (k < PRE && ssc[k] != -INFINITY) kw |= (1ull << b);
      }
    }
    for (int i = 0; i < PRE; i++) {
      u64 ow = __shfl(kw, i >> 6);
      if ((ow >> (i & 63)) & 1ull) {
        if (t < 16) kw &= ~supm[i * 16 + t];
      }
    }
    if (t < 16) keepw[t] = kw;
  }
  __syncthreads();
  if (t == 0) {
    unsigned acc = 0;
    for (int w = 0; w < 16; w++) { wpre[w] = acc; acc += (unsigned)__popcll(keepw[w]); }
    wpre[16] = acc;
  }
  __syncthreads();
  const unsigned total = wpre[16];
  for (int k = t; k < PRE; k += 256) {
    int w = k >> 6, b = k & 63;
    u64 kw = keepw[w];
    if ((kw >> b) & 1ull) {
      unsigned rank = wpre[w] + (unsigned)__popcll(kw & ((1ull << b) - 1ull));
      if (rank < MAXD) {
        int slot = c * MAXD + (int)rank;
        out_s[slot] = ssc[k];
        out_id[slot] = (float)c;
        out_b[slot * 4 + 0] = bx[k];
        out_b[slot * 4 + 1] = by[k];
        out_b[slot * 4 + 2] = bX[k];
        out_b[slot * 4 + 3] = bY[k];
        out_d[slot] = dist[topidx[c * PRE + k]];
      }
    }
  }
  unsigned tk = total < MAXD ? total : MAXD;
  for (int r = (int)tk + t; r < MAXD; r += 256) {
    int slot = c * MAXD + r;
    out_s[slot] = 0.0f;
    out_id[slot] = -1.0f;
    out_b[slot * 4 + 0] = 0.0f; out_b[slot * 4 + 1] = 0.0f;
    out_b[slot * 4 + 2] = 0.0f; out_b[slot * 4 + 3] = 0.0f;
    out_d[slot] = 0.0f;
  }
}

// =====================================================================

static inline size_t align512(size_t x) { return (x + 511) & ~(size_t)511; }

extern "C" void kernel_launch(void* const* d_in, const int* in_sizes, int n_in,
                              void* d_out, int out_size, void* d_ws, size_t ws_size,
                              hipStream_t stream) {
  const float* cls  = (const float*)d_in[0];   // (1, A, 80)
  const float* reg  = (const float*)d_in[1];   // (1, A, 4)
  const float* dist = (const float*)d_in[2];   // (1, A, 1)
  const float* anch = (const float*)d_in[3];   // (1, A, 4)
  const int* img_h  = (const int*)d_in[4];
  const int* img_w  = (const int*)d_in[5];
  const int A = in_sizes[3] / 4;

  float* o = (float*)d_out;
  float* out_s  = o;                      // 8000
  float* out_id = o + NCLS * MAXD;        // 8000
  float* out_b  = o + 2 * NCLS * MAXD;    // 32000
  float* out_d  = o + 6 * NCLS * MAXD;    // 8000

  size_t off = 0;
  const size_t o_cand = off; off += align512((size_t)NCLS * SUBS * SUBCAP * sizeof(u64)); // 5.24 MB
  const size_t o_ccnt = off; off += align512((size_t)NCLS * SUBS * sizeof(unsigned));
  const size_t needed = off;

  if (ws_size >= needed) {
    char* ws = (char*)d_ws;
    u64* cand = (u64*)(ws + o_cand);
    unsigned* ccnt = (unsigned*)(ws + o_ccnt);
    const int total4 = A * 20;  // A*80/4
    const int k3grid = (total4 + 256 * K3K - 1) / (256 * K3K);

    k0_init<<<(NCLS * SUBS + 255) / 256, 256, 0, stream>>>(ccnt);
    k3_collect<<<k3grid, 256, 0, stream>>>((const float4*)cls, total4, ccnt, cand);
    kAD_sort_nms<<<NCLS, BT, 0, stream>>>(ccnt, cand, cls, A, anch, reg, dist,
                                          img_h, img_w, out_s, out_id, out_b, out_d);
  } else {
    // fallback: proven round-1 path (needs only ~0.64 MB)
    float* topscore = (float*)d_ws;
    unsigned* topidx = (unsigned*)((char*)d_ws + NCLS * PRE * sizeof(float));
    select_topk<<<NCLS, 256, 0, stream>>>(cls, A, topscore, topidx);
    nms_out<<<NCLS, 256, 0, stream>>>(anch, reg, dist, topscore, topidx,
                                      img_h, img_w, out_s, out_id, out_b, out_d);
  }
}

// Round 13
// 63.530 us; speedup vs baseline: 2.0273x; 1.2890x over previous
//
#include <hip/hip_runtime.h>
#include <math.h>

#define NCLS 80
#define PRE 1000
#define MAXD 100
#define THR_SCORE 0.05f
#define TFIX 0.996f            // fixed collection threshold (fast path)

#define SUBS 16                // sub-lists per class
#define SUBCAP 512             // depth per sub-list
#define BT 512                 // kAD block threads
#define K3K 8                  // float4 loads per thread in k3 (MLP depth)

typedef unsigned long long u64;
typedef float vfloat4 __attribute__((ext_vector_type(4)));

__device__ __forceinline__ u64 readlane64(u64 v, int l) {
  unsigned lo = (unsigned)__builtin_amdgcn_readlane((int)(unsigned)v, l);
  unsigned hi = (unsigned)__builtin_amdgcn_readlane((int)(unsigned)(v >> 32), l);
  return ((u64)hi << 32) | lo;
}

// =====================================================================
// K3: tiled coalesced pass, 8-deep MLP, non-temporal reads (cls is streamed
// once per call; nt avoids L3 churn that fragments the HBM stream).
__global__ __launch_bounds__(256) void k3_collect(
    const vfloat4* __restrict__ cls4, int total4,
    unsigned* __restrict__ ccnt, u64* __restrict__ cand)
{
  const int t = threadIdx.x;
  const int sub = blockIdx.x & (SUBS - 1);
  const int base = blockIdx.x * (256 * K3K) + t;
  vfloat4 v[K3K];
#pragma unroll
  for (int k = 0; k < K3K; k++) {
    int q = base + k * 256;
    if (q < total4) v[k] = __builtin_nontemporal_load(&cls4[q]);
    else v[k] = (vfloat4)(0.f);
  }
#pragma unroll
  for (int k = 0; k < K3K; k++) {
    int q = base + k * 256;
    if (q < total4) {
      int c0 = 4 * (q % 20);
      unsigned a = (unsigned)(q / 20);
      float sv[4] = {v[k].x, v[k].y, v[k].z, v[k].w};
#pragma unroll
      for (int e = 0; e < 4; e++) {
        float s = sv[e];
        if (s >= TFIX) {
          int c = c0 + e;
          unsigned p = atomicAdd(&ccnt[c * SUBS + sub], 1u);
          if (p < SUBCAP)
            cand[((size_t)(c * SUBS + sub)) * SUBCAP + p] =
                ((u64)__float_as_uint(s) << 32) | (u64)(~a);
        }
      }
    }
  }
}

// NMS over sorted rows in LDS; wave 0 of the block (caller guards t<64).
__device__ __forceinline__ void nms_scan64(
    int windows, const float4* box4, const float* area, const float* ssc,
    float* fx, float* fy, float* fXX, float* fYY, float* fAA,
    float* wx, float* wy, float* wXX, float* wYY, float* wAA,
    u64* s_keep, unsigned* s_pre, unsigned* s_total, int lane)
{
#pragma clang fp contract(off)
  const double MID = 0x1.000001p-1;
  unsigned acc = 0;
  int nf = 0;
  for (int w = 0; w < windows; w++) {
    const int r = w * 64 + lane;
    const float4 rb = box4[r];
    const float ra = area[r];
    bool dead = (ssc[r] == -INFINITY);
    for (int f = 0; f < nf; f++) {
      float ltx = fmaxf(rb.x, fx[f]);
      float lty = fmaxf(rb.y, fy[f]);
      float rbx = fminf(rb.z, fXX[f]);
      float rby = fminf(rb.w, fYY[f]);
      float ww = fmaxf(rbx - ltx, 0.0f);
      float hh = fmaxf(rby - lty, 0.0f);
      float inter = ww * hh;
      float denom = ((ra + fAA[f]) - inter) + 1e-8f;
      dead = dead | ((double)inter > MID * (double)denom);
    }
    u64 alive = __ballot(!dead);
    u64 F = 0ull;
    if (alive) {
      wx[lane] = rb.x; wy[lane] = rb.y; wXX[lane] = rb.z; wYY[lane] = rb.w; wAA[lane] = ra;
      u64 Rw = 0ull;
#pragma unroll 4
      for (int i = 0; i < 64; i++) {
        float ltx = fmaxf(wx[i], rb.x);
        float lty = fmaxf(wy[i], rb.y);
        float rbx = fminf(wXX[i], rb.z);
        float rby = fminf(wYY[i], rb.w);
        float ww = fmaxf(rbx - ltx, 0.0f);
        float hh = fmaxf(rby - lty, 0.0f);
        float inter = ww * hh;
        float denom = ((wAA[i] + ra) - inter) + 1e-8f;
        bool io = (double)inter > MID * (double)denom;
        u64 m = __ballot(io & (lane > i));
        Rw = (lane == i) ? m : Rw;
      }
      while (alive) {
        int b = __builtin_ctzll(alive);
        F |= (1ull << b);
        u64 rbw = readlane64(Rw, b);
        alive &= ~(rbw | (1ull << b));
      }
      if ((F >> lane) & 1ull) {
        int pos = nf + (int)__popcll(F & ((1ull << lane) - 1ull));
        if (pos < 192) {
          fx[pos] = rb.x; fy[pos] = rb.y; fXX[pos] = rb.z; fYY[pos] = rb.w; fAA[pos] = ra;
        }
      }
    }
    if (lane == 0) { s_keep[w] = F; s_pre[w] = acc; }
    acc += (unsigned)__popcll(F);
    nf += (int)__popcll(F);
    if (acc >= (unsigned)MAXD) break;
  }
  if (lane == 0) *s_total = acc;
}

__device__ __forceinline__ void decode_one(
    u64 key, const float4* a4, const float4* r4, float W, float H,
    float4* obox, float* oarea, float* ossc, unsigned* oidx)
{
#pragma clang fp contract(off)
  float sc; unsigned idx;
  if (key != 0ull) {
    sc = __uint_as_float((unsigned)(key >> 32));
    idx = ~((unsigned)(key & 0xFFFFFFFFull));
  } else {
    sc = -INFINITY; idx = 0u;
  }
  float4 av = a4[idx];
  float4 rv = r4[idx];
  float w = av.z - av.x, h = av.w - av.y;
  float cx = av.x + 0.5f * w, cy = av.y + 0.5f * h;
  float dx = rv.x * 0.1f, dy = rv.y * 0.1f, dw = rv.z * 0.2f, dh = rv.w * 0.2f;
  float pcx = cx + dx * w, pcy = cy + dy * h;
  float pw = (float)exp((double)dw) * w;
  float ph = (float)exp((double)dh) * h;
  float x1 = fminf(fmaxf(pcx - 0.5f * pw, 0.0f), W);
  float y1 = fminf(fmaxf(pcy - 0.5f * ph, 0.0f), H);
  float x2 = fminf(fmaxf(pcx + 0.5f * pw, 0.0f), W);
  float y2 = fminf(fmaxf(pcy + 0.5f * ph, 0.0f), H);
  *obox = make_float4(x1, y1, x2, y2);
  *oarea = (x2 - x1) * (y2 - y1);
  *ossc = sc;
  *oidx = idx;
}

// kAD: flat LDS gather (n<=2048) -> 512-bin bit-hist -> parallel suffix-scan
// threshold (boundary-guarded) -> compact <=512 -> sort-512 -> decode ->
// early-exit NMS. Exact iff no overflow, thr above TFIX bin boundary, and
// kept>=100; otherwise complete in-kernel legacy path from cls.
__global__ __launch_bounds__(BT) void kAD_sort_nms(
    const unsigned* __restrict__ ccnt, const u64* __restrict__ cand,
    const float* __restrict__ cls, int A,
    const float* __restrict__ anch, const float* __restrict__ reg,
    const float* __restrict__ dist,
    const int* __restrict__ img_h_p, const int* __restrict__ img_w_p,
    float* __restrict__ out_s, float* __restrict__ out_id,
    float* __restrict__ out_b, float* __restrict__ out_d)
{
#pragma clang fp contract(off)
  const int c = blockIdx.x;
  const int t = threadIdx.x;
  const int lane = t & 63;
  // carved LDS: slow path uses full regions; fast path aliases prefixes
  __shared__ __align__(16) char smem[61440];
  u64* candS = (u64*)smem;                          // 2048 u64 (fast: gathered keys | slow: sort buf)
  unsigned* histS = (unsigned*)(smem + 16384);      // slow: 4096 u32 | fast: 512 u32 at head
  u64* M = (u64*)(smem + 18432);                    // fast: 512 u64 (inside histS slow region)
  float4* box4 = (float4*)(smem + 32768);           // 1024 float4
  float* area  = (float*)(smem + 49152);            // 1024 f32
  float* ssc   = (float*)(smem + 53248);            // 1024 f32
  unsigned* sidb = (unsigned*)(smem + 57344);       // 1024 u32
  __shared__ unsigned scnt[SUBS];
  __shared__ unsigned sbase[SUBS + 1];
  __shared__ unsigned s_ovf, s_abv, s_push, s_thr, s_cnt, s_r0, s_r1;
  __shared__ int s_mode, s_cb;
  __shared__ float fx[192], fy[192], fX[192], fY[192], fA[192];
  __shared__ float wx[64], wy[64], wX[64], wY[64], wA[64];
  __shared__ u64 s_keep[16];
  __shared__ unsigned s_pre[16];
  __shared__ unsigned s_total;

  if (t == 0) { s_ovf = 0u; s_abv = 0u; s_push = 0u; s_cnt = 0u; s_total = 0u;
                s_r0 = 0u; s_r1 = 512u; s_mode = 1; }
  if (t < 16) { s_keep[t] = 0ull; s_pre[t] = 0u; }
  histS[t] = 0u;         // fast hist bins [0,512)
  M[t] = 0ull;
  if (t < SUBS) {
    unsigned nn = ccnt[c * SUBS + t];
    scnt[t] = nn > SUBCAP ? SUBCAP : nn;
    if (nn > SUBCAP) atomicOr(&s_ovf, 1u);
  }
  __syncthreads();
  if (t == 0) {
    unsigned a = 0;
    for (int s = 0; s < SUBS; s++) { sbase[s] = a; a += scnt[s]; }
    sbase[SUBS] = a;
  }
  __syncthreads();
  const unsigned n = sbase[SUBS];
  const bool fits = (s_ovf == 0u) && (n >= 1u) && (n <= 2048u);

  const float W = (float)img_w_p[0];
  const float H = (float)img_h_p[0];
  const float4* a4 = (const float4*)anch;
  const float4* r4 = (const float4*)reg;
  bool slow = true;

  if (fits) {
    // ---- flat gather of all candidates into LDS ----
    for (unsigned g = t; g < n; g += BT) {
      int s = 0;
      while (g >= sbase[s + 1]) s++;
      candS[g] = cand[((size_t)(c * SUBS + s)) * SUBCAP + (g - sbase[s])];
    }
    __syncthreads();
    // ---- 512-bin integer histogram on float bits in [0x3F700000, 0x3F800000) ----
    for (unsigned i = t; i < n; i += BT) {
      unsigned u = (unsigned)(candS[i] >> 32);
      if (u >= 0x3F800000u) atomicAdd(&s_abv, 1u);
      else if (u >= 0x3F700000u) atomicAdd(&histS[(u - 0x3F700000u) >> 11], 1u);
      // u < 0x3F700000 impossible: collected keys have s >= TFIX > 0.9375.
    }
    __syncthreads();
    // ---- parallel suffix sum (Hillis-Steele, 9 rounds) ----
    for (int d = 1; d < 512; d <<= 1) {
      unsigned add = (t + d < 512) ? histS[t + d] : 0u;
      __syncthreads();
      histS[t] += add;
      __syncthreads();
    }
    // ---- threshold pick: r0 = max b with tot>=256; r = min b>=r0 with tot<=512 ----
    {
      unsigned tot = s_abv + histS[t];
      if (tot >= 256u) atomicMax(&s_r0, (unsigned)t);
      __syncthreads();
      if ((unsigned)t >= s_r0 && tot <= 512u) atomicMin(&s_r1, (unsigned)t);
      __syncthreads();
      if (t == 0) {
        unsigned r = s_r1;
        unsigned a = (r < 512u) ? (s_abv + histS[r]) : s_abv;
        unsigned thr = 0x3F700000u + (r << 11);
        unsigned guard = ((__float_as_uint(TFIX) >> 11) + 1u) << 11;  // first bin fully above TFIX
        s_thr = thr;
        s_cnt = a;
        s_mode = (a >= 1u && a <= 512u && thr >= guard) ? 0 : 1;
      }
      __syncthreads();
    }
    if (s_mode == 0) {
      // ---- compact prefix into M ----
      const unsigned thr = s_thr;
      for (unsigned i = t; i < n; i += BT) {
        u64 key = candS[i];
        if ((unsigned)(key >> 32) >= thr) {
          unsigned p = atomicAdd(&s_push, 1u);
          if (p < 512u) M[p] = key;
        }
      }
      __syncthreads();
      // ---- hybrid bitonic sort of 512 desc (1 elem/thread) ----
      u64* SW = M;
      {
        u64 v = SW[t];
#pragma unroll
        for (int k = 2; k <= 64; k <<= 1) {
#pragma unroll
          for (int j = k >> 1; j > 0; j >>= 1) {
            u64 p = __shfl_xor(v, j);
            bool iLower = (lane & j) == 0;
            bool desc = (t & k) == 0;
            bool keepMax = (iLower == desc);
            bool pGreater = p > v;
            v = (keepMax == pGreater) ? p : v;
          }
        }
        SW[t] = v;
        __syncthreads();
        for (int k = 128; k <= 512; k <<= 1) {
          for (int j = k >> 1; j >= 64; j >>= 1) {
            if ((t & j) == 0) {
              u64 a = SW[t], b = SW[t ^ j];
              bool desc = ((t & k) == 0);
              if (desc ? (a < b) : (a > b)) { SW[t] = b; SW[t ^ j] = a; }
            }
            __syncthreads();
          }
          u64 v2 = SW[t];
          bool desc = ((t & k) == 0);
#pragma unroll
          for (int j = 32; j > 0; j >>= 1) {
            u64 p = __shfl_xor(v2, j);
            bool iLower = (lane & j) == 0;
            bool keepMax = (iLower == desc);
            bool pGreater = p > v2;
            v2 = (keepMax == pGreater) ? p : v2;
          }
          SW[t] = v2;
          __syncthreads();
        }
      }
      // ---- decode row t ----
      decode_one(SW[t], a4, r4, W, H, &box4[t], &area[t], &ssc[t], &sidb[t]);
      __syncthreads();
      if (t < 64)
        nms_scan64(8, box4, area, ssc, fx, fy, fX, fY, fA, wx, wy, wX, wY, wA,
                   s_keep, s_pre, &s_total, lane);
      __syncthreads();
      slow = (s_total < (unsigned)MAXD);   // kept>=100 => provably exact
    }
  }

  if (slow) {
    // ---- complete legacy path from cls (round-1 proven; correctness-only) ----
    if (t == 0) { s_cnt = 0u; s_total = 0u; }
    if (t < 16) { s_keep[t] = 0ull; s_pre[t] = 0u; }
    for (int i = t; i < 4096; i += BT) histS[i] = 0u;
    __syncthreads();
    for (int a = t; a < A; a += BT) {
      float s = cls[(size_t)a * NCLS + c];
      if (s > THR_SCORE) {
        int b = (int)(s * 4096.0f);
        b = b < 0 ? 0 : (b > 4095 ? 4095 : b);
        atomicAdd(&histS[b], 1u);
      }
    }
    __syncthreads();
    if (t == 0) {
      unsigned acc = 0;
      int cb = 0;
      for (int b = 4095; b >= 0; b--) {
        acc += histS[b];
        if (acc >= (unsigned)PRE) { cb = b; break; }
      }
      if (acc < (unsigned)PRE) cb = 0;
      while (acc > 2048u && cb < 4095) { acc -= histS[cb]; cb++; }
      s_cb = cb;
    }
    __syncthreads();
    const int cb = s_cb;
    for (int i = t; i < 2048; i += BT) candS[i] = 0ull;
    __syncthreads();
    for (int a = t; a < A; a += BT) {
      float s = cls[(size_t)a * NCLS + c];
      if (s > THR_SCORE) {
        int b = (int)(s * 4096.0f);
        b = b < 0 ? 0 : (b > 4095 ? 4095 : b);
        if (b >= cb) {
          unsigned p = atomicAdd(&s_cnt, 1u);
          if (p < 2048u)
            candS[p] = ((u64)__float_as_uint(s) << 32) | (u64)(~(unsigned)a);
        }
      }
    }
    __syncthreads();
    for (int k = 2; k <= 2048; k <<= 1) {
      for (int j = k >> 1; j > 0; j >>= 1) {
        for (int i = t; i < 2048; i += BT) {
          int ixj = i ^ j;
          if (ixj > i) {
            u64 va = candS[i], vb = candS[ixj];
            bool desc = ((i & k) == 0);
            if (desc ? (va < vb) : (va > vb)) { candS[i] = vb; candS[ixj] = va; }
          }
        }
        __syncthreads();
      }
    }
    for (int i = t; i < 1024; i += BT) {
      u64 key = (i < PRE) ? candS[i] : 0ull;
      decode_one(key, a4, r4, W, H, &box4[i], &area[i], &ssc[i], &sidb[i]);
      if (i >= PRE) ssc[i] = -INFINITY;
    }
    __syncthreads();
    if (t < 64)
      nms_scan64(16, box4, area, ssc, fx, fy, fX, fY, fA, wx, wy, wX, wY, wA,
                 s_keep, s_pre, &s_total, lane);
    __syncthreads();
  }

  // ---- output ----
  const unsigned total = s_total;
  for (int k = t; k < PRE; k += BT) {
    int w = k >> 6, b = k & 63;
    u64 kw = s_keep[w];
    if ((kw >> b) & 1ull) {
      unsigned rank = s_pre[w] + (unsigned)__popcll(kw & ((1ull << b) - 1ull));
      if (rank < MAXD) {
        int slot = c * MAXD + (int)rank;
        out_s[slot] = ssc[k];
        out_id[slot] = (float)c;
        ((float4*)out_b)[slot] = box4[k];
        out_d[slot] = dist[sidb[k]];
      }
    }
  }
  unsigned tk = total < (unsigned)MAXD ? total : (unsigned)MAXD;
  for (int r2 = (int)tk + t; r2 < MAXD; r2 += BT) {
    int slot = c * MAXD + r2;
    out_s[slot] = 0.0f;
    out_id[slot] = -1.0f;
    ((float4*)out_b)[slot] = make_float4(0.f, 0.f, 0.f, 0.f);
    out_d[slot] = 0.0f;
  }
}

// =====================================================================
// FALLBACK PATH (round-1, proven correct; used only if ws is too small)
// =====================================================================
#define NBUCK 4096
#define CANDF 2048

__global__ __launch_bounds__(256) void select_topk(
    const float* __restrict__ cls, int A,
    float* __restrict__ topscore, unsigned* __restrict__ topidx)
{
  const int c = blockIdx.x;
  const int t = threadIdx.x;
  __shared__ unsigned hist[NBUCK];
  __shared__ u64 cand[CANDF];
  __shared__ unsigned chunk[256];
  __shared__ int s_cb;
  __shared__ int s_cnt;
  for (int i = t; i < NBUCK; i += 256) hist[i] = 0u;
  if (t == 0) s_cnt = 0;
  __syncthreads();
  for (int a = t; a < A; a += 256) {
    float s = cls[(size_t)a * NCLS + c];
    if (s > THR_SCORE) {
      int b = (int)(s * (float)NBUCK);
      b = b < 0 ? 0 : (b > NBUCK - 1 ? NBUCK - 1 : b);
      atomicAdd(&hist[b], 1u);
    }
  }
  __syncthreads();
  {
    unsigned cs = 0;
    for (int i = 0; i < NBUCK / 256; i++) cs += hist[t * (NBUCK / 256) + i];
    chunk[t] = cs;
  }
  __syncthreads();
  if (t == 0) {
    unsigned acc = 0;
    int cb = 0;
    int ch;
    for (ch = 255; ch >= 0; ch--) {
      if (acc + chunk[ch] >= (unsigned)PRE) break;
      acc += chunk[ch];
    }
    if (ch < 0) cb = 0;
    else {
      const int bpc = NBUCK / 256;
      int b = ch * bpc + bpc - 1;
      for (; b >= ch * bpc; b--) { acc += hist[b]; if (acc >= (unsigned)PRE) break; }
      if (b < ch * bpc) b = ch * bpc;
      cb = b;
      while (acc > (unsigned)CANDF && cb < NBUCK - 1) { acc -= hist[cb]; cb++; }
    }
    s_cb = cb;
  }
  __syncthreads();
  const int cb = s_cb;
  for (int a = t; a < A; a += 256) {
    float s = cls[(size_t)a * NCLS + c];
    if (s > THR_SCORE) {
      int b = (int)(s * (float)NBUCK);
      b = b < 0 ? 0 : (b > NBUCK - 1 ? NBUCK - 1 : b);
      if (b >= cb) {
        int p = atomicAdd(&s_cnt, 1);
        if (p < CANDF)
          cand[p] = ((u64)__float_as_uint(s) << 32) | (u64)(~(unsigned)a);
      }
    }
  }
  __syncthreads();
  int n = s_cnt < CANDF ? s_cnt : CANDF;
  for (int i = n + t; i < CANDF; i += 256) cand[i] = 0ull;
  __syncthreads();
  for (int k = 2; k <= CANDF; k <<= 1) {
    for (int j = k >> 1; j > 0; j >>= 1) {
      for (int i = t; i < CANDF; i += 256) {
        int ixj = i ^ j;
        if (ixj > i) {
          u64 va = cand[i], vb = cand[ixj];
          bool desc = ((i & k) == 0);
          if (desc ? (va < vb) : (va > vb)) { cand[i] = vb; cand[ixj] = va; }
        }
      }
      __syncthreads();
    }
  }
  for (int k = t; k < PRE; k += 256) {
    u64 key = cand[k];
    float sc; unsigned idx;
    if (key != 0ull) { sc = __uint_as_float((unsigned)(key >> 32)); idx = ~((unsigned)(key & 0xFFFFFFFFull)); }
    else { sc = -INFINITY; idx = 0u; }
    topscore[c * PRE + k] = sc;
    topidx[c * PRE + k] = idx;
  }
}

__global__ __launch_bounds__(256) void nms_out(
    const float* __restrict__ anch, const float* __restrict__ reg,
    const float* __restrict__ dist,
    const float* __restrict__ topscore, const unsigned* __restrict__ topidx,
    const int* __restrict__ img_h_p, const int* __restrict__ img_w_p,
    float* __restrict__ out_s, float* __restrict__ out_id,
    float* __restrict__ out_b, float* __restrict__ out_d)
{
#pragma clang fp contract(off)
  const int c = blockIdx.x;
  const int t = threadIdx.x;
  __shared__ float bx[PRE], by[PRE], bX[PRE], bY[PRE], bar[PRE], ssc[PRE];
  __shared__ u64 supm[PRE * 16];
  __shared__ u64 keepw[16];
  __shared__ unsigned wpre[17];
  const float W = (float)img_w_p[0];
  const float H = (float)img_h_p[0];
  for (int k = t; k < PRE; k += 256) {
    float sc = topscore[c * PRE + k];
    unsigned idx = topidx[c * PRE + k];
    ssc[k] = sc;
    float a0 = anch[(size_t)idx * 4 + 0], a1 = anch[(size_t)idx * 4 + 1];
    float a2 = anch[(size_t)idx * 4 + 2], a3 = anch[(size_t)idx * 4 + 3];
    float r0 = reg[(size_t)idx * 4 + 0], r1 = reg[(size_t)idx * 4 + 1];
    float r2 = reg[(size_t)idx * 4 + 2], r3 = reg[(size_t)idx * 4 + 3];
    float w = a2 - a0, h = a3 - a1;
    float cx = a0 + 0.5f * w, cy = a1 + 0.5f * h;
    float dx = r0 * 0.1f, dy = r1 * 0.1f, dw = r2 * 0.2f, dh = r3 * 0.2f;
    float pcx = cx + dx * w, pcy = cy + dy * h;
    float pw = (float)exp((double)dw) * w;
    float ph = (float)exp((double)dh) * h;
    float x1 = fminf(fmaxf(pcx - 0.5f * pw, 0.0f), W);
    float y1 = fminf(fmaxf(pcy - 0.5f * ph, 0.0f), H);
    float x2 = fminf(fmaxf(pcx + 0.5f * pw, 0.0f), W);
    float y2 = fminf(fmaxf(pcy + 0.5f * ph, 0.0f), H);
    bx[k] = x1; by[k] = y1; bX[k] = x2; bY[k] = y2;
    bar[k] = (x2 - x1) * (y2 - y1);
  }
  __syncthreads();
  const int wave = t >> 6, lane = t & 63;
  for (int i = wave; i < PRE; i += 4) {
    float x1 = bx[i], y1 = by[i], X1 = bX[i], Y1 = bY[i], ai = bar[i];
    for (int g = 0; g < 16; g++) {
      int j = g * 64 + lane;
      bool s = false;
      if (j > i && j < PRE) {
        float ltx = fmaxf(x1, bx[j]);
        float lty = fmaxf(y1, by[j]);
        float rbx = fminf(X1, bX[j]);
        float rby = fminf(Y1, bY[j]);
        float ww = fmaxf(rbx - ltx, 0.0f);
        float hh = fmaxf(rby - lty, 0.0f);
        float inter = ww * hh;
        float iou = inter / ((ai + bar[j]) - inter + 1e-8f);
        s = iou > 0.5f;
      }
      u64 m = __ballot(s);
      if (lane == 0) supm[i * 16 + g] = m;
    }
  }
  __syncthreads();
  if (t < 64) {
    u64 kw = 0ull;
    if (t < 16) {
      for (int b = 0; b < 64; b++) {
        int k = t * 64 + b;
        if (k < PRE && ssc[k] != -INFINITY) kw |= (1ull << b);
      }
    }
    for (int i = 0; i < PRE; i++) {
      u64 ow = __shfl(kw, i >> 6);
      if ((ow >> (i & 63)) & 1ull) {
        if (t < 16) kw &= ~supm[i * 16 + t];
      }
    }
    if (t < 16) keepw[t] = kw;
  }
  __syncthreads();
  if (t == 0) {
    unsigned acc = 0;
    for (int w = 0; w < 16; w++) { wpre[w] = acc; acc += (unsigned)__popcll(keepw[w]); }
    wpre[16] = acc;
  }
  __syncthreads();
  const unsigned total = wpre[16];
  for (int k = t; k < PRE; k += 256) {
    int w = k >> 6, b = k & 63;
    u64 kw = keepw[w];
    if ((kw >> b) & 1ull) {
      unsigned rank = wpre[w] + (unsigned)__popcll(kw & ((1ull << b) - 1ull));
      if (rank < MAXD) {
        int slot = c * MAXD + (int)rank;
        out_s[slot] = ssc[k];
        out_id[slot] = (float)c;
        out_b[slot * 4 + 0] = bx[k];
        out_b[slot * 4 + 1] = by[k];
        out_b[slot * 4 + 2] = bX[k];
        out_b[slot * 4 + 3] = bY[k];
        out_d[slot] = dist[topidx[c * PRE + k]];
      }
    }
  }
  unsigned tk = total < MAXD ? total : MAXD;
  for (int r = (int)tk + t; r < MAXD; r += 256) {
    int slot = c * MAXD + r;
    out_s[slot] = 0.0f;
    out_id[slot] = -1.0f;
    out_b[slot * 4 + 0] = 0.0f; out_b[slot * 4 + 1] = 0.0f;
    out_b[slot * 4 + 2] = 0.0f; out_b[slot * 4 + 3] = 0.0f;
    out_d[slot] = 0.0f;
  }
}

// =====================================================================

static inline size_t align512(size_t x) { return (x + 511) & ~(size_t)511; }

extern "C" void kernel_launch(void* const* d_in, const int* in_sizes, int n_in,
                              void* d_out, int out_size, void* d_ws, size_t ws_size,
                              hipStream_t stream) {
  const float* cls  = (const float*)d_in[0];   // (1, A, 80)
  const float* reg  = (const float*)d_in[1];   // (1, A, 4)
  const float* dist = (const float*)d_in[2];   // (1, A, 1)
  const float* anch = (const float*)d_in[3];   // (1, A, 4)
  const int* img_h  = (const int*)d_in[4];
  const int* img_w  = (const int*)d_in[5];
  const int A = in_sizes[3] / 4;

  float* o = (float*)d_out;
  float* out_s  = o;                      // 8000
  float* out_id = o + NCLS * MAXD;        // 8000
  float* out_b  = o + 2 * NCLS * MAXD;    // 32000
  float* out_d  = o + 6 * NCLS * MAXD;    // 8000

  size_t off = 0;
  const size_t o_cand = off; off += align512((size_t)NCLS * SUBS * SUBCAP * sizeof(u64)); // 5.24 MB
  const size_t o_ccnt = off; off += align512((size_t)NCLS * SUBS * sizeof(unsigned));
  const size_t needed = off;

  if (ws_size >= needed) {
    char* ws = (char*)d_ws;
    u64* cand = (u64*)(ws + o_cand);
    unsigned* ccnt = (unsigned*)(ws + o_ccnt);
    const int total4 = A * 20;  // A*80/4
    const int k3grid = (total4 + 256 * K3K - 1) / (256 * K3K);

    hipMemsetAsync(ccnt, 0, (size_t)NCLS * SUBS * sizeof(unsigned), stream);
    k3_collect<<<k3grid, 256, 0, stream>>>((const vfloat4*)cls, total4, ccnt, cand);
    kAD_sort_nms<<<NCLS, BT, 0, stream>>>(ccnt, cand, cls, A, anch, reg, dist,
                                          img_h, img_w, out_s, out_id, out_b, out_d);
  } else {
    // fallback: proven round-1 path (needs only ~0.64 MB)
    float* topscore = (float*)d_ws;
    unsigned* topidx = (unsigned*)((char*)d_ws + NCLS * PRE * sizeof(float));
    select_topk<<<NCLS, 256, 0, stream>>>(cls, A, topscore, topidx);
    nms_out<<<NCLS, 256, 0, stream>>>(anch, reg, dist, topscore, topidx,
                                      img_h, img_w, out_s, out_id, out_b, out_d);
  }
}

// Round 14
// 63.526 us; speedup vs baseline: 2.0274x; 1.0001x over previous
//
#include <hip/hip_runtime.h>
#include <math.h>

#define NCLS 80
#define PRE 1000
#define MAXD 100
#define THR_SCORE 0.05f
#define TFIX 0.996f            // fixed collection threshold (fast path)

#define SUBS 16                // sub-lists per class
#define SUBCAP 512             // depth per sub-list
#define BT 512                 // kAD block threads
#define K3K 8                  // float4 loads per thread in k3 (MLP depth)

typedef unsigned long long u64;
typedef float vfloat4 __attribute__((ext_vector_type(4)));

__device__ __forceinline__ u64 readlane64(u64 v, int l) {
  unsigned lo = (unsigned)__builtin_amdgcn_readlane((int)(unsigned)v, l);
  unsigned hi = (unsigned)__builtin_amdgcn_readlane((int)(unsigned)(v >> 32), l);
  return ((u64)hi << 32) | lo;
}

// =====================================================================
// K0: zero the push counters (custom kernel: the rocclr fillBuffer path
// costs ~39us for a 5KB fill; this takes ~2us).
__global__ __launch_bounds__(256) void k0_init(unsigned* __restrict__ ccnt) {
  int i = blockIdx.x * 256 + threadIdx.x;
  if (i < NCLS * SUBS) ccnt[i] = 0u;
}

// K3: tiled coalesced pass, 8-deep MLP, non-temporal reads.
__global__ __launch_bounds__(256) void k3_collect(
    const vfloat4* __restrict__ cls4, int total4,
    unsigned* __restrict__ ccnt, u64* __restrict__ cand)
{
  const int t = threadIdx.x;
  const int sub = blockIdx.x & (SUBS - 1);
  const int base = blockIdx.x * (256 * K3K) + t;
  vfloat4 v[K3K];
#pragma unroll
  for (int k = 0; k < K3K; k++) {
    int q = base + k * 256;
    if (q < total4) v[k] = __builtin_nontemporal_load(&cls4[q]);
    else v[k] = (vfloat4)(0.f);
  }
#pragma unroll
  for (int k = 0; k < K3K; k++) {
    int q = base + k * 256;
    if (q < total4) {
      int c0 = 4 * (q % 20);
      unsigned a = (unsigned)(q / 20);
      float sv[4] = {v[k].x, v[k].y, v[k].z, v[k].w};
#pragma unroll
      for (int e = 0; e < 4; e++) {
        float s = sv[e];
        if (s >= TFIX) {
          int c = c0 + e;
          unsigned p = atomicAdd(&ccnt[c * SUBS + sub], 1u);
          if (p < SUBCAP)
            cand[((size_t)(c * SUBS + sub)) * SUBCAP + p] =
                ((u64)__float_as_uint(s) << 32) | (u64)(~a);
        }
      }
    }
  }
}

// NMS over sorted rows in LDS; wave 0 of the block (caller guards t<64).
__device__ __forceinline__ void nms_scan64(
    int windows, const float4* box4, const float* area, const float* ssc,
    float* fx, float* fy, float* fXX, float* fYY, float* fAA,
    float* wx, float* wy, float* wXX, float* wYY, float* wAA,
    u64* s_keep, unsigned* s_pre, unsigned* s_total, int lane)
{
#pragma clang fp contract(off)
  const double MID = 0x1.000001p-1;
  unsigned acc = 0;
  int nf = 0;
  for (int w = 0; w < windows; w++) {
    const int r = w * 64 + lane;
    const float4 rb = box4[r];
    const float ra = area[r];
    bool dead = (ssc[r] == -INFINITY);
    for (int f = 0; f < nf; f++) {
      float ltx = fmaxf(rb.x, fx[f]);
      float lty = fmaxf(rb.y, fy[f]);
      float rbx = fminf(rb.z, fXX[f]);
      float rby = fminf(rb.w, fYY[f]);
      float ww = fmaxf(rbx - ltx, 0.0f);
      float hh = fmaxf(rby - lty, 0.0f);
      float inter = ww * hh;
      float denom = ((ra + fAA[f]) - inter) + 1e-8f;
      dead = dead | ((double)inter > MID * (double)denom);
    }
    u64 alive = __ballot(!dead);
    u64 F = 0ull;
    if (alive) {
      wx[lane] = rb.x; wy[lane] = rb.y; wXX[lane] = rb.z; wYY[lane] = rb.w; wAA[lane] = ra;
      u64 Rw = 0ull;
#pragma unroll 4
      for (int i = 0; i < 64; i++) {
        float ltx = fmaxf(wx[i], rb.x);
        float lty = fmaxf(wy[i], rb.y);
        float rbx = fminf(wXX[i], rb.z);
        float rby = fminf(wYY[i], rb.w);
        float ww = fmaxf(rbx - ltx, 0.0f);
        float hh = fmaxf(rby - lty, 0.0f);
        float inter = ww * hh;
        float denom = ((wAA[i] + ra) - inter) + 1e-8f;
        bool io = (double)inter > MID * (double)denom;
        u64 m = __ballot(io & (lane > i));
        Rw = (lane == i) ? m : Rw;
      }
      while (alive) {
        int b = __builtin_ctzll(alive);
        F |= (1ull << b);
        u64 rbw = readlane64(Rw, b);
        alive &= ~(rbw | (1ull << b));
      }
      if ((F >> lane) & 1ull) {
        int pos = nf + (int)__popcll(F & ((1ull << lane) - 1ull));
        if (pos < 192) {
          fx[pos] = rb.x; fy[pos] = rb.y; fXX[pos] = rb.z; fYY[pos] = rb.w; fAA[pos] = ra;
        }
      }
    }
    if (lane == 0) { s_keep[w] = F; s_pre[w] = acc; }
    acc += (unsigned)__popcll(F);
    nf += (int)__popcll(F);
    if (acc >= (unsigned)MAXD) break;
  }
  if (lane == 0) *s_total = acc;
}

__device__ __forceinline__ void decode_one(
    u64 key, const float4* a4, const float4* r4, float W, float H,
    float4* obox, float* oarea, float* ossc, unsigned* oidx)
{
#pragma clang fp contract(off)
  float sc; unsigned idx;
  if (key != 0ull) {
    sc = __uint_as_float((unsigned)(key >> 32));
    idx = ~((unsigned)(key & 0xFFFFFFFFull));
  } else {
    sc = -INFINITY; idx = 0u;
  }
  float4 av = a4[idx];
  float4 rv = r4[idx];
  float w = av.z - av.x, h = av.w - av.y;
  float cx = av.x + 0.5f * w, cy = av.y + 0.5f * h;
  float dx = rv.x * 0.1f, dy = rv.y * 0.1f, dw = rv.z * 0.2f, dh = rv.w * 0.2f;
  float pcx = cx + dx * w, pcy = cy + dy * h;
  float pw = (float)exp((double)dw) * w;
  float ph = (float)exp((double)dh) * h;
  float x1 = fminf(fmaxf(pcx - 0.5f * pw, 0.0f), W);
  float y1 = fminf(fmaxf(pcy - 0.5f * ph, 0.0f), H);
  float x2 = fminf(fmaxf(pcx + 0.5f * pw, 0.0f), W);
  float y2 = fminf(fmaxf(pcy + 0.5f * ph, 0.0f), H);
  *obox = make_float4(x1, y1, x2, y2);
  *oarea = (x2 - x1) * (y2 - y1);
  *ossc = sc;
  *oidx = idx;
}

// kAD: flat LDS gather (n<=2048) -> 512-bin bit-hist -> parallel suffix-scan
// threshold (boundary-guarded) -> compact <=512 -> sort-512 -> decode ->
// early-exit NMS. Exact iff no overflow, thr above TFIX bin boundary, and
// kept>=100; otherwise complete in-kernel legacy path from cls.
__global__ __launch_bounds__(BT) void kAD_sort_nms(
    const unsigned* __restrict__ ccnt, const u64* __restrict__ cand,
    const float* __restrict__ cls, int A,
    const float* __restrict__ anch, const float* __restrict__ reg,
    const float* __restrict__ dist,
    const int* __restrict__ img_h_p, const int* __restrict__ img_w_p,
    float* __restrict__ out_s, float* __restrict__ out_id,
    float* __restrict__ out_b, float* __restrict__ out_d)
{
#pragma clang fp contract(off)
  const int c = blockIdx.x;
  const int t = threadIdx.x;
  const int lane = t & 63;
  // carved LDS: slow path uses full regions; fast path aliases prefixes
  __shared__ __align__(16) char smem[61440];
  u64* candS = (u64*)smem;                          // 2048 u64 (fast: gathered keys | slow: sort buf)
  unsigned* histS = (unsigned*)(smem + 16384);      // slow: 4096 u32 | fast: 512 u32 at head
  u64* M = (u64*)(smem + 18432);                    // fast: 512 u64 (inside histS slow region)
  float4* box4 = (float4*)(smem + 32768);           // 1024 float4
  float* area  = (float*)(smem + 49152);            // 1024 f32
  float* ssc   = (float*)(smem + 53248);            // 1024 f32
  unsigned* sidb = (unsigned*)(smem + 57344);       // 1024 u32
  __shared__ unsigned scnt[SUBS];
  __shared__ unsigned sbase[SUBS + 1];
  __shared__ unsigned s_ovf, s_abv, s_push, s_thr, s_cnt, s_r0, s_r1;
  __shared__ int s_mode, s_cb;
  __shared__ float fx[192], fy[192], fX[192], fY[192], fA[192];
  __shared__ float wx[64], wy[64], wX[64], wY[64], wA[64];
  __shared__ u64 s_keep[16];
  __shared__ unsigned s_pre[16];
  __shared__ unsigned s_total;

  if (t == 0) { s_ovf = 0u; s_abv = 0u; s_push = 0u; s_cnt = 0u; s_total = 0u;
                s_r0 = 0u; s_r1 = 512u; s_mode = 1; }
  if (t < 16) { s_keep[t] = 0ull; s_pre[t] = 0u; }
  histS[t] = 0u;         // fast hist bins [0,512)
  M[t] = 0ull;
  if (t < SUBS) {
    unsigned nn = ccnt[c * SUBS + t];
    scnt[t] = nn > SUBCAP ? SUBCAP : nn;
    if (nn > SUBCAP) atomicOr(&s_ovf, 1u);
  }
  __syncthreads();
  if (t == 0) {
    unsigned a = 0;
    for (int s = 0; s < SUBS; s++) { sbase[s] = a; a += scnt[s]; }
    sbase[SUBS] = a;
  }
  __syncthreads();
  const unsigned n = sbase[SUBS];
  const bool fits = (s_ovf == 0u) && (n >= 1u) && (n <= 2048u);

  const float W = (float)img_w_p[0];
  const float H = (float)img_h_p[0];
  const float4* a4 = (const float4*)anch;
  const float4* r4 = (const float4*)reg;
  bool slow = true;

  if (fits) {
    // ---- flat gather of all candidates into LDS ----
    for (unsigned g = t; g < n; g += BT) {
      int s = 0;
      while (g >= sbase[s + 1]) s++;
      candS[g] = cand[((size_t)(c * SUBS + s)) * SUBCAP + (g - sbase[s])];
    }
    __syncthreads();
    // ---- 512-bin integer histogram on float bits in [0x3F700000, 0x3F800000) ----
    for (unsigned i = t; i < n; i += BT) {
      unsigned u = (unsigned)(candS[i] >> 32);
      if (u >= 0x3F800000u) atomicAdd(&s_abv, 1u);
      else if (u >= 0x3F700000u) atomicAdd(&histS[(u - 0x3F700000u) >> 11], 1u);
      // u < 0x3F700000 impossible: collected keys have s >= TFIX > 0.9375.
    }
    __syncthreads();
    // ---- parallel suffix sum (Hillis-Steele, 9 rounds) ----
    for (int d = 1; d < 512; d <<= 1) {
      unsigned add = (t + d < 512) ? histS[t + d] : 0u;
      __syncthreads();
      histS[t] += add;
      __syncthreads();
    }
    // ---- threshold pick: r0 = max b with tot>=256; r = min b>=r0 with tot<=512 ----
    {
      unsigned tot = s_abv + histS[t];
      if (tot >= 256u) atomicMax(&s_r0, (unsigned)t);
      __syncthreads();
      if ((unsigned)t >= s_r0 && tot <= 512u) atomicMin(&s_r1, (unsigned)t);
      __syncthreads();
      if (t == 0) {
        unsigned r = s_r1;
        unsigned a = (r < 512u) ? (s_abv + histS[r]) : s_abv;
        unsigned thr = 0x3F700000u + (r << 11);
        unsigned guard = ((__float_as_uint(TFIX) >> 11) + 1u) << 11;  // first bin fully above TFIX
        s_thr = thr;
        s_cnt = a;
        s_mode = (a >= 1u && a <= 512u && thr >= guard) ? 0 : 1;
      }
      __syncthreads();
    }
    if (s_mode == 0) {
      // ---- compact prefix into M ----
      const unsigned thr = s_thr;
      for (unsigned i = t; i < n; i += BT) {
        u64 key = candS[i];
        if ((unsigned)(key >> 32) >= thr) {
          unsigned p = atomicAdd(&s_push, 1u);
          if (p < 512u) M[p] = key;
        }
      }
      __syncthreads();
      // ---- hybrid bitonic sort of 512 desc (1 elem/thread) ----
      u64* SW = M;
      {
        u64 v = SW[t];
#pragma unroll
        for (int k = 2; k <= 64; k <<= 1) {
#pragma unroll
          for (int j = k >> 1; j > 0; j >>= 1) {
            u64 p = __shfl_xor(v, j);
            bool iLower = (lane & j) == 0;
            bool desc = (t & k) == 0;
            bool keepMax = (iLower == desc);
            bool pGreater = p > v;
            v = (keepMax == pGreater) ? p : v;
          }
        }
        SW[t] = v;
        __syncthreads();
        for (int k = 128; k <= 512; k <<= 1) {
          for (int j = k >> 1; j >= 64; j >>= 1) {
            if ((t & j) == 0) {
              u64 a = SW[t], b = SW[t ^ j];
              bool desc = ((t & k) == 0);
              if (desc ? (a < b) : (a > b)) { SW[t] = b; SW[t ^ j] = a; }
            }
            __syncthreads();
          }
          u64 v2 = SW[t];
          bool desc = ((t & k) == 0);
#pragma unroll
          for (int j = 32; j > 0; j >>= 1) {
            u64 p = __shfl_xor(v2, j);
            bool iLower = (lane & j) == 0;
            bool keepMax = (iLower == desc);
            bool pGreater = p > v2;
            v2 = (keepMax == pGreater) ? p : v2;
          }
          SW[t] = v2;
          __syncthreads();
        }
      }
      // ---- decode row t ----
      decode_one(SW[t], a4, r4, W, H, &box4[t], &area[t], &ssc[t], &sidb[t]);
      __syncthreads();
      if (t < 64)
        nms_scan64(8, box4, area, ssc, fx, fy, fX, fY, fA, wx, wy, wX, wY, wA,
                   s_keep, s_pre, &s_total, lane);
      __syncthreads();
      slow = (s_total < (unsigned)MAXD);   // kept>=100 => provably exact
    }
  }

  if (slow) {
    // ---- complete legacy path from cls (round-1 proven; correctness-only) ----
    if (t == 0) { s_cnt = 0u; s_total = 0u; }
    if (t < 16) { s_keep[t] = 0ull; s_pre[t] = 0u; }
    for (int i = t; i < 4096; i += BT) histS[i] = 0u;
    __syncthreads();
    for (int a = t; a < A; a += BT) {
      float s = cls[(size_t)a * NCLS + c];
      if (s > THR_SCORE) {
        int b = (int)(s * 4096.0f);
        b = b < 0 ? 0 : (b > 4095 ? 4095 : b);
        atomicAdd(&histS[b], 1u);
      }
    }
    __syncthreads();
    if (t == 0) {
      unsigned acc = 0;
      int cb = 0;
      for (int b = 4095; b >= 0; b--) {
        acc += histS[b];
        if (acc >= (unsigned)PRE) { cb = b; break; }
      }
      if (acc < (unsigned)PRE) cb = 0;
      while (acc > 2048u && cb < 4095) { acc -= histS[cb]; cb++; }
      s_cb = cb;
    }
    __syncthreads();
    const int cb = s_cb;
    for (int i = t; i < 2048; i += BT) candS[i] = 0ull;
    __syncthreads();
    for (int a = t; a < A; a += BT) {
      float s = cls[(size_t)a * NCLS + c];
      if (s > THR_SCORE) {
        int b = (int)(s * 4096.0f);
        b = b < 0 ? 0 : (b > 4095 ? 4095 : b);
        if (b >= cb) {
          unsigned p = atomicAdd(&s_cnt, 1u);
          if (p < 2048u)
            candS[p] = ((u64)__float_as_uint(s) << 32) | (u64)(~(unsigned)a);
        }
      }
    }
    __syncthreads();
    for (int k = 2; k <= 2048; k <<= 1) {
      for (int j = k >> 1; j > 0; j >>= 1) {
        for (int i = t; i < 2048; i += BT) {
          int ixj = i ^ j;
          if (ixj > i) {
            u64 va = candS[i], vb = candS[ixj];
            bool desc = ((i & k) == 0);
            if (desc ? (va < vb) : (va > vb)) { candS[i] = vb; candS[ixj] = va; }
          }
        }
        __syncthreads();
      }
    }
    for (int i = t; i < 1024; i += BT) {
      u64 key = (i < PRE) ? candS[i] : 0ull;
      decode_one(key, a4, r4, W, H, &box4[i], &area[i], &ssc[i], &sidb[i]);
      if (i >= PRE) ssc[i] = -INFINITY;
    }
    __syncthreads();
    if (t < 64)
      nms_scan64(16, box4, area, ssc, fx, fy, fX, fY, fA, wx, wy, wX, wY, wA,
                 s_keep, s_pre, &s_total, lane);
    __syncthreads();
  }

  // ---- output ----
  const unsigned total = s_total;
  for (int k = t; k < PRE; k += BT) {
    int w = k >> 6, b = k & 63;
    u64 kw = s_keep[w];
    if ((kw >> b) & 1ull) {
      unsigned rank = s_pre[w] + (unsigned)__popcll(kw & ((1ull << b) - 1ull));
      if (rank < MAXD) {
        int slot = c * MAXD + (int)rank;
        out_s[slot] = ssc[k];
        out_id[slot] = (float)c;
        ((float4*)out_b)[slot] = box4[k];
        out_d[slot] = dist[sidb[k]];
      }
    }
  }
  unsigned tk = total < (unsigned)MAXD ? total : (unsigned)MAXD;
  for (int r2 = (int)tk + t; r2 < MAXD; r2 += BT) {
    int slot = c * MAXD + r2;
    out_s[slot] = 0.0f;
    out_id[slot] = -1.0f;
    ((float4*)out_b)[slot] = make_float4(0.f, 0.f, 0.f, 0.f);
    out_d[slot] = 0.0f;
  }
}

// =====================================================================
// FALLBACK PATH (round-1, proven correct; used only if ws is too small)
// =====================================================================
#define NBUCK 4096
#define CANDF 2048

__global__ __launch_bounds__(256) void select_topk(
    const float* __restrict__ cls, int A,
    float* __restrict__ topscore, unsigned* __restrict__ topidx)
{
  const int c = blockIdx.x;
  const int t = threadIdx.x;
  __shared__ unsigned hist[NBUCK];
  __shared__ u64 cand[CANDF];
  __shared__ unsigned chunk[256];
  __shared__ int s_cb;
  __shared__ int s_cnt;
  for (int i = t; i < NBUCK; i += 256) hist[i] = 0u;
  if (t == 0) s_cnt = 0;
  __syncthreads();
  for (int a = t; a < A; a += 256) {
    float s = cls[(size_t)a * NCLS + c];
    if (s > THR_SCORE) {
      int b = (int)(s * (float)NBUCK);
      b = b < 0 ? 0 : (b > NBUCK - 1 ? NBUCK - 1 : b);
      atomicAdd(&hist[b], 1u);
    }
  }
  __syncthreads();
  {
    unsigned cs = 0;
    for (int i = 0; i < NBUCK / 256; i++) cs += hist[t * (NBUCK / 256) + i];
    chunk[t] = cs;
  }
  __syncthreads();
  if (t == 0) {
    unsigned acc = 0;
    int cb = 0;
    int ch;
    for (ch = 255; ch >= 0; ch--) {
      if (acc + chunk[ch] >= (unsigned)PRE) break;
      acc += chunk[ch];
    }
    if (ch < 0) cb = 0;
    else {
      const int bpc = NBUCK / 256;
      int b = ch * bpc + bpc - 1;
      for (; b >= ch * bpc; b--) { acc += hist[b]; if (acc >= (unsigned)PRE) break; }
      if (b < ch * bpc) b = ch * bpc;
      cb = b;
      while (acc > (unsigned)CANDF && cb < NBUCK - 1) { acc -= hist[cb]; cb++; }
    }
    s_cb = cb;
  }
  __syncthreads();
  const int cb = s_cb;
  for (int a = t; a < A; a += 256) {
    float s = cls[(size_t)a * NCLS + c];
    if (s > THR_SCORE) {
      int b = (int)(s * (float)NBUCK);
      b = b < 0 ? 0 : (b > NBUCK - 1 ? NBUCK - 1 : b);
      if (b >= cb) {
        int p = atomicAdd(&s_cnt, 1);
        if (p < CANDF)
          cand[p] = ((u64)__float_as_uint(s) << 32) | (u64)(~(unsigned)a);
      }
    }
  }
  __syncthreads();
  int n = s_cnt < CANDF ? s_cnt : CANDF;
  for (int i = n + t; i < CANDF; i += 256) cand[i] = 0ull;
  __syncthreads();
  for (int k = 2; k <= CANDF; k <<= 1) {
    for (int j = k >> 1; j > 0; j >>= 1) {
      for (int i = t; i < CANDF; i += 256) {
        int ixj = i ^ j;
        if (ixj > i) {
          u64 va = cand[i], vb = cand[ixj];
          bool desc = ((i & k) == 0);
          if (desc ? (va < vb) : (va > vb)) { cand[i] = vb; cand[ixj] = va; }
        }
      }
      __syncthreads();
    }
  }
  for (int k = t; k < PRE; k += 256) {
    u64 key = cand[k];
    float sc; unsigned idx;
    if (key != 0ull) { sc = __uint_as_float((unsigned)(key >> 32)); idx = ~((unsigned)(key & 0xFFFFFFFFull)); }
    else { sc = -INFINITY; idx = 0u; }
    topscore[c * PRE + k] = sc;
    topidx[c * PRE + k] = idx;
  }
}

__global__ __launch_bounds__(256) void nms_out(
    const float* __restrict__ anch, const float* __restrict__ reg,
    const float* __restrict__ dist,
    const float* __restrict__ topscore, const unsigned* __restrict__ topidx,
    const int* __restrict__ img_h_p, const int* __restrict__ img_w_p,
    float* __restrict__ out_s, float* __restrict__ out_id,
    float* __restrict__ out_b, float* __restrict__ out_d)
{
#pragma clang fp contract(off)
  const int c = blockIdx.x;
  const int t = threadIdx.x;
  __shared__ float bx[PRE], by[PRE], bX[PRE], bY[PRE], bar[PRE], ssc[PRE];
  __shared__ u64 supm[PRE * 16];
  __shared__ u64 keepw[16];
  __shared__ unsigned wpre[17];
  const float W = (float)img_w_p[0];
  const float H = (float)img_h_p[0];
  for (int k = t; k < PRE; k += 256) {
    float sc = topscore[c * PRE + k];
    unsigned idx = topidx[c * PRE + k];
    ssc[k] = sc;
    float a0 = anch[(size_t)idx * 4 + 0], a1 = anch[(size_t)idx * 4 + 1];
    float a2 = anch[(size_t)idx * 4 + 2], a3 = anch[(size_t)idx * 4 + 3];
    float r0 = reg[(size_t)idx * 4 + 0], r1 = reg[(size_t)idx * 4 + 1];
    float r2 = reg[(size_t)idx * 4 + 2], r3 = reg[(size_t)idx * 4 + 3];
    float w = a2 - a0, h = a3 - a1;
    float cx = a0 + 0.5f * w, cy = a1 + 0.5f * h;
    float dx = r0 * 0.1f, dy = r1 * 0.1f, dw = r2 * 0.2f, dh = r3 * 0.2f;
    float pcx = cx + dx * w, pcy = cy + dy * h;
    float pw = (float)exp((double)dw) * w;
    float ph = (float)exp((double)dh) * h;
    float x1 = fminf(fmaxf(pcx - 0.5f * pw, 0.0f), W);
    float y1 = fminf(fmaxf(pcy - 0.5f * ph, 0.0f), H);
    float x2 = fminf(fmaxf(pcx + 0.5f * pw, 0.0f), W);
    float y2 = fminf(fmaxf(pcy + 0.5f * ph, 0.0f), H);
    bx[k] = x1; by[k] = y1; bX[k] = x2; bY[k] = y2;
    bar[k] = (x2 - x1) * (y2 - y1);
  }
  __syncthreads();
  const int wave = t >> 6, lane = t & 63;
  for (int i = wave; i < PRE; i += 4) {
    float x1 = bx[i], y1 = by[i], X1 = bX[i], Y1 = bY[i], ai = bar[i];
    for (int g = 0; g < 16; g++) {
      int j = g * 64 + lane;
      bool s = false;
      if (j > i && j < PRE) {
        float ltx = fmaxf(x1, bx[j]);
        float lty = fmaxf(y1, by[j]);
        float rbx = fminf(X1, bX[j]);
        float rby = fminf(Y1, bY[j]);
        float ww = fmaxf(rbx - ltx, 0.0f);
        float hh = fmaxf(rby - lty, 0.0f);
        float inter = ww * hh;
        float iou = inter / ((ai + bar[j]) - inter + 1e-8f);
        s = iou > 0.5f;
      }
      u64 m = __ballot(s);
      if (lane == 0) supm[i * 16 + g] = m;
    }
  }
  __syncthreads();
  if (t < 64) {
    u64 kw = 0ull;
    if (t < 16) {
      for (int b = 0; b < 64; b++) {
        int k = t * 64 + b;
        if (k < PRE && ssc[k] != -INFINITY) kw |= (1ull << b);
      }
    }
    for (int i = 0; i < PRE; i++) {
      u64 ow = __shfl(kw, i >> 6);
      if ((ow >> (i & 63)) & 1ull) {
        if (t < 16) kw &= ~supm[i * 16 + t];
      }
    }
    if (t < 16) keepw[t] = kw;
  }
  __syncthreads();
  if (t == 0) {
    unsigned acc = 0;
    for (int w = 0; w < 16; w++) { wpre[w] = acc; acc += (unsigned)__popcll(keepw[w]); }
    wpre[16] = acc;
  }
  __syncthreads();
  const unsigned total = wpre[16];
  for (int k = t; k < PRE; k += 256) {
    int w = k >> 6, b = k & 63;
    u64 kw = keepw[w];
    if ((kw >> b) & 1ull) {
      unsigned rank = wpre[w] + (unsigned)__popcll(kw & ((1ull << b) - 1ull));
      if (rank < MAXD) {
        int slot = c * MAXD + (int)rank;
        out_s[slot] = ssc[k];
        out_id[slot] = (float)c;
        out_b[slot * 4 + 0] = bx[k];
        out_b[slot * 4 + 1] = by[k];
        out_b[slot * 4 + 2] = bX[k];
        out_b[slot * 4 + 3] = bY[k];
        out_d[slot] = dist[topidx[c * PRE + k]];
      }
    }
  }
  unsigned tk = total < MAXD ? total : MAXD;
  for (int r = (int)tk + t; r < MAXD; r += 256) {
    int slot = c * MAXD + r;
    out_s[slot] = 0.0f;
    out_id[slot] = -1.0f;
    out_b[slot * 4 + 0] = 0.0f; out_b[slot * 4 + 1] = 0.0f;
    out_b[slot * 4 + 2] = 0.0f; out_b[slot * 4 + 3] = 0.0f;
    out_d[slot] = 0.0f;
  }
}

// =====================================================================

static inline size_t align512(size_t x) { return (x + 511) & ~(size_t)511; }

extern "C" void kernel_launch(void* const* d_in, const int* in_sizes, int n_in,
                              void* d_out, int out_size, void* d_ws, size_t ws_size,
                              hipStream_t stream) {
  const float* cls  = (const float*)d_in[0];   // (1, A, 80)
  const float* reg  = (const float*)d_in[1];   // (1, A, 4)
  const float* dist = (const float*)d_in[2];   // (1, A, 1)
  const float* anch = (const float*)d_in[3];   // (1, A, 4)
  const int* img_h  = (const int*)d_in[4];
  const int* img_w  = (const int*)d_in[5];
  const int A = in_sizes[3] / 4;

  float* o = (float*)d_out;
  float* out_s  = o;                      // 8000
  float* out_id = o + NCLS * MAXD;        // 8000
  float* out_b  = o + 2 * NCLS * MAXD;    // 32000
  float* out_d  = o + 6 * NCLS * MAXD;    // 8000

  size_t off = 0;
  const size_t o_cand = off; off += align512((size_t)NCLS * SUBS * SUBCAP * sizeof(u64)); // 5.24 MB
  const size_t o_ccnt = off; off += align512((size_t)NCLS * SUBS * sizeof(unsigned));
  const size_t needed = off;

  if (ws_size >= needed) {
    char* ws = (char*)d_ws;
    u64* cand = (u64*)(ws + o_cand);
    unsigned* ccnt = (unsigned*)(ws + o_ccnt);
    const int total4 = A * 20;  // A*80/4
    const int k3grid = (total4 + 256 * K3K - 1) / (256 * K3K);

    k0_init<<<(NCLS * SUBS + 255) / 256, 256, 0, stream>>>(ccnt);
    k3_collect<<<k3grid, 256, 0, stream>>>((const vfloat4*)cls, total4, ccnt, cand);
    kAD_sort_nms<<<NCLS, BT, 0, stream>>>(ccnt, cand, cls, A, anch, reg, dist,
                                          img_h, img_w, out_s, out_id, out_b, out_d);
  } else {
    // fallback: proven round-1 path (needs only ~0.64 MB)
    float* topscore = (float*)d_ws;
    unsigned* topidx = (unsigned*)((char*)d_ws + NCLS * PRE * sizeof(float));
    select_topk<<<NCLS, 256, 0, stream>>>(cls, A, topscore, topidx);
    nms_out<<<NCLS, 256, 0, stream>>>(anch, reg, dist, topscore, topidx,
                                      img_h, img_w, out_s, out_id, out_b, out_d);
  }
}

// Round 15
// 54.327 us; speedup vs baseline: 2.3707x; 1.1693x over previous
//
#include <hip/hip_runtime.h>
#include <math.h>

#define NCLS 80
#define PRE 1000
#define MAXD 100
#define THR_SCORE 0.05f
#define TFIX 0.996f            // fixed collection threshold (fast path)

#define SEGCAP 16              // candidates per (block, class) segment
#define BT 512                 // kAD block threads
#define K3K 8                  // float4 loads per thread in k3 (MLP depth)

typedef unsigned long long u64;
typedef float vfloat4 __attribute__((ext_vector_type(4)));

__device__ __forceinline__ u64 readlane64(u64 v, int l) {
  unsigned lo = (unsigned)__builtin_amdgcn_readlane((int)(unsigned)v, l);
  unsigned hi = (unsigned)__builtin_amdgcn_readlane((int)(unsigned)(v >> 32), l);
  return ((u64)hi << 32) | lo;
}

// =====================================================================
// K3: tiled coalesced pass, 8-deep MLP, nt reads. Per-block private segments
// (LDS-atomic slots) -> no global atomics, no counter pre-zeroing needed.
__global__ __launch_bounds__(256) void k3_collect(
    const vfloat4* __restrict__ cls4, int total4,
    unsigned* __restrict__ cnt, u64* __restrict__ cand)
{
  __shared__ unsigned lcnt[NCLS];
  const int t = threadIdx.x;
  const int b = blockIdx.x;
  if (t < NCLS) lcnt[t] = 0u;
  __syncthreads();
  const int base = b * (256 * K3K) + t;
  vfloat4 v[K3K];
#pragma unroll
  for (int k = 0; k < K3K; k++) {
    int q = base + k * 256;
    if (q < total4) v[k] = __builtin_nontemporal_load(&cls4[q]);
    else v[k] = (vfloat4)(0.f);
  }
#pragma unroll
  for (int k = 0; k < K3K; k++) {
    int q = base + k * 256;
    if (q < total4) {
      int c0 = 4 * (q % 20);
      unsigned a = (unsigned)(q / 20);
      float sv[4] = {v[k].x, v[k].y, v[k].z, v[k].w};
#pragma unroll
      for (int e = 0; e < 4; e++) {
        float s = sv[e];
        if (s >= TFIX) {
          int c = c0 + e;
          unsigned p = atomicAdd(&lcnt[c], 1u);
          if (p < SEGCAP)
            cand[((size_t)b * NCLS + c) * SEGCAP + p] =
                ((u64)__float_as_uint(s) << 32) | (u64)(~a);
        }
      }
    }
  }
  __syncthreads();
  if (t < NCLS) cnt[(size_t)b * NCLS + t] = lcnt[t];
}

// NMS over sorted rows in LDS; wave 0 of the block (caller guards t<64).
__device__ __forceinline__ void nms_scan64(
    int windows, const float4* box4, const float* area, const float* ssc,
    float* fx, float* fy, float* fXX, float* fYY, float* fAA,
    float* wx, float* wy, float* wXX, float* wYY, float* wAA,
    u64* s_keep, unsigned* s_pre, unsigned* s_total, int lane)
{
#pragma clang fp contract(off)
  const double MID = 0x1.000001p-1;
  unsigned acc = 0;
  int nf = 0;
  for (int w = 0; w < windows; w++) {
    const int r = w * 64 + lane;
    const float4 rb = box4[r];
    const float ra = area[r];
    bool dead = (ssc[r] == -INFINITY);
    for (int f = 0; f < nf; f++) {
      float ltx = fmaxf(rb.x, fx[f]);
      float lty = fmaxf(rb.y, fy[f]);
      float rbx = fminf(rb.z, fXX[f]);
      float rby = fminf(rb.w, fYY[f]);
      float ww = fmaxf(rbx - ltx, 0.0f);
      float hh = fmaxf(rby - lty, 0.0f);
      float inter = ww * hh;
      float denom = ((ra + fAA[f]) - inter) + 1e-8f;
      dead = dead | ((double)inter > MID * (double)denom);
    }
    u64 alive = __ballot(!dead);
    u64 F = 0ull;
    if (alive) {
      wx[lane] = rb.x; wy[lane] = rb.y; wXX[lane] = rb.z; wYY[lane] = rb.w; wAA[lane] = ra;
      u64 Rw = 0ull;
#pragma unroll 4
      for (int i = 0; i < 64; i++) {
        float ltx = fmaxf(wx[i], rb.x);
        float lty = fmaxf(wy[i], rb.y);
        float rbx = fminf(wXX[i], rb.z);
        float rby = fminf(wYY[i], rb.w);
        float ww = fmaxf(rbx - ltx, 0.0f);
        float hh = fmaxf(rby - lty, 0.0f);
        float inter = ww * hh;
        float denom = ((wAA[i] + ra) - inter) + 1e-8f;
        bool io = (double)inter > MID * (double)denom;
        u64 m = __ballot(io & (lane > i));
        Rw = (lane == i) ? m : Rw;
      }
      while (alive) {
        int b = __builtin_ctzll(alive);
        F |= (1ull << b);
        u64 rbw = readlane64(Rw, b);
        alive &= ~(rbw | (1ull << b));
      }
      if ((F >> lane) & 1ull) {
        int pos = nf + (int)__popcll(F & ((1ull << lane) - 1ull));
        if (pos < 192) {
          fx[pos] = rb.x; fy[pos] = rb.y; fXX[pos] = rb.z; fYY[pos] = rb.w; fAA[pos] = ra;
        }
      }
    }
    if (lane == 0) { s_keep[w] = F; s_pre[w] = acc; }
    acc += (unsigned)__popcll(F);
    nf += (int)__popcll(F);
    if (acc >= (unsigned)MAXD) break;
  }
  if (lane == 0) *s_total = acc;
}

__device__ __forceinline__ void decode_one(
    u64 key, const float4* a4, const float4* r4, float W, float H,
    float4* obox, float* oarea, float* ossc, unsigned* oidx)
{
#pragma clang fp contract(off)
  float sc; unsigned idx;
  if (key != 0ull) {
    sc = __uint_as_float((unsigned)(key >> 32));
    idx = ~((unsigned)(key & 0xFFFFFFFFull));
  } else {
    sc = -INFINITY; idx = 0u;
  }
  float4 av = a4[idx];
  float4 rv = r4[idx];
  float w = av.z - av.x, h = av.w - av.y;
  float cx = av.x + 0.5f * w, cy = av.y + 0.5f * h;
  float dx = rv.x * 0.1f, dy = rv.y * 0.1f, dw = rv.z * 0.2f, dh = rv.w * 0.2f;
  float pcx = cx + dx * w, pcy = cy + dy * h;
  float pw = (float)exp((double)dw) * w;
  float ph = (float)exp((double)dh) * h;
  float x1 = fminf(fmaxf(pcx - 0.5f * pw, 0.0f), W);
  float y1 = fminf(fmaxf(pcy - 0.5f * ph, 0.0f), H);
  float x2 = fminf(fmaxf(pcx + 0.5f * pw, 0.0f), W);
  float y2 = fminf(fmaxf(pcy + 0.5f * ph, 0.0f), H);
  *obox = make_float4(x1, y1, x2, y2);
  *oarea = (x2 - x1) * (y2 - y1);
  *ossc = sc;
  *oidx = idx;
}

// kAD: segment gather -> 512-bin bit-hist -> suffix-scan threshold (guarded)
// -> compact <=512 -> sort-512 -> decode -> early-exit NMS. Exact iff no
// segment overflow, thr above TFIX bin boundary, and kept>=100; otherwise
// complete in-kernel legacy path from cls.
__global__ __launch_bounds__(BT) void kAD_sort_nms(
    const unsigned* __restrict__ cnt, const u64* __restrict__ cand, int nblk,
    const float* __restrict__ cls, int A,
    const float* __restrict__ anch, const float* __restrict__ reg,
    const float* __restrict__ dist,
    const int* __restrict__ img_h_p, const int* __restrict__ img_w_p,
    float* __restrict__ out_s, float* __restrict__ out_id,
    float* __restrict__ out_b, float* __restrict__ out_d)
{
#pragma clang fp contract(off)
  const int c = blockIdx.x;
  const int t = threadIdx.x;
  const int lane = t & 63;
  // carved LDS: slow path uses full regions; fast path aliases prefixes
  __shared__ __align__(16) char smem[61440];
  u64* candS = (u64*)smem;                          // 2048 u64 (fast: gathered keys | slow: sort buf)
  unsigned* histS = (unsigned*)(smem + 16384);      // slow: 4096 u32 | fast: 512 u32 at head
  u64* M = (u64*)(smem + 18432);                    // fast: 512 u64 (inside histS slow region)
  float4* box4 = (float4*)(smem + 32768);           // 1024 float4
  float* area  = (float*)(smem + 49152);            // 1024 f32
  float* ssc   = (float*)(smem + 53248);            // 1024 f32
  unsigned* sidb = (unsigned*)(smem + 57344);       // 1024 u32
  __shared__ unsigned s_ovf, s_abv, s_push, s_gn, s_thr, s_cnt, s_r0, s_r1;
  __shared__ int s_mode, s_cb;
  __shared__ float fx[192], fy[192], fX[192], fY[192], fA[192];
  __shared__ float wx[64], wy[64], wX[64], wY[64], wA[64];
  __shared__ u64 s_keep[16];
  __shared__ unsigned s_pre[16];
  __shared__ unsigned s_total;

  if (t == 0) { s_ovf = 0u; s_abv = 0u; s_push = 0u; s_gn = 0u; s_cnt = 0u;
                s_total = 0u; s_r0 = 0u; s_r1 = 512u; s_mode = 1; }
  if (t < 16) { s_keep[t] = 0ull; s_pre[t] = 0u; }
  histS[t] = 0u;         // fast hist bins [0,512)
  M[t] = 0ull;
  __syncthreads();

  // ---- gather per-block segments for this class into LDS ----
  for (int i = t; i < nblk; i += BT) {
    unsigned cv = cnt[(size_t)i * NCLS + c];
    if (cv > SEGCAP) {
      atomicOr(&s_ovf, 1u);
    } else if (cv) {
      unsigned basep = atomicAdd(&s_gn, cv);
      if (basep + cv <= 2048u) {
        const u64* src = cand + ((size_t)i * NCLS + c) * SEGCAP;
        for (unsigned j = 0; j < cv; j++) candS[basep + j] = src[j];
      } else {
        atomicOr(&s_ovf, 1u);
      }
    }
  }
  __syncthreads();
  const unsigned n = s_gn <= 2048u ? s_gn : 2048u;
  const bool fits = (s_ovf == 0u) && (n >= 1u);

  const float W = (float)img_w_p[0];
  const float H = (float)img_h_p[0];
  const float4* a4 = (const float4*)anch;
  const float4* r4 = (const float4*)reg;
  bool slow = true;

  if (fits) {
    // ---- 512-bin integer histogram on float bits in [0x3F700000, 0x3F800000) ----
    for (unsigned i = t; i < n; i += BT) {
      unsigned u = (unsigned)(candS[i] >> 32);
      if (u >= 0x3F800000u) atomicAdd(&s_abv, 1u);
      else if (u >= 0x3F700000u) atomicAdd(&histS[(u - 0x3F700000u) >> 11], 1u);
      // u < 0x3F700000 impossible: collected keys have s >= TFIX > 0.9375.
    }
    __syncthreads();
    // ---- parallel suffix sum (Hillis-Steele, 9 rounds) ----
    for (int d = 1; d < 512; d <<= 1) {
      unsigned add = (t + d < 512) ? histS[t + d] : 0u;
      __syncthreads();
      histS[t] += add;
      __syncthreads();
    }
    // ---- threshold pick: r0 = max b with tot>=256; r = min b>=r0 with tot<=512 ----
    {
      unsigned tot = s_abv + histS[t];
      if (tot >= 256u) atomicMax(&s_r0, (unsigned)t);
      __syncthreads();
      if ((unsigned)t >= s_r0 && tot <= 512u) atomicMin(&s_r1, (unsigned)t);
      __syncthreads();
      if (t == 0) {
        unsigned r = s_r1;
        unsigned a = (r < 512u) ? (s_abv + histS[r]) : s_abv;
        unsigned thr = 0x3F700000u + (r << 11);
        unsigned guard = ((__float_as_uint(TFIX) >> 11) + 1u) << 11;  // first bin fully above TFIX
        s_thr = thr;
        s_cnt = a;
        s_mode = (a >= 1u && a <= 512u && thr >= guard) ? 0 : 1;
      }
      __syncthreads();
    }
    if (s_mode == 0) {
      // ---- compact prefix into M ----
      const unsigned thr = s_thr;
      for (unsigned i = t; i < n; i += BT) {
        u64 key = candS[i];
        if ((unsigned)(key >> 32) >= thr) {
          unsigned p = atomicAdd(&s_push, 1u);
          if (p < 512u) M[p] = key;
        }
      }
      __syncthreads();
      // ---- hybrid bitonic sort of 512 desc (1 elem/thread) ----
      u64* SW = M;
      {
        u64 v = SW[t];
#pragma unroll
        for (int k = 2; k <= 64; k <<= 1) {
#pragma unroll
          for (int j = k >> 1; j > 0; j >>= 1) {
            u64 p = __shfl_xor(v, j);
            bool iLower = (lane & j) == 0;
            bool desc = (t & k) == 0;
            bool keepMax = (iLower == desc);
            bool pGreater = p > v;
            v = (keepMax == pGreater) ? p : v;
          }
        }
        SW[t] = v;
        __syncthreads();
        for (int k = 128; k <= 512; k <<= 1) {
          for (int j = k >> 1; j >= 64; j >>= 1) {
            if ((t & j) == 0) {
              u64 a = SW[t], b = SW[t ^ j];
              bool desc = ((t & k) == 0);
              if (desc ? (a < b) : (a > b)) { SW[t] = b; SW[t ^ j] = a; }
            }
            __syncthreads();
          }
          u64 v2 = SW[t];
          bool desc = ((t & k) == 0);
#pragma unroll
          for (int j = 32; j > 0; j >>= 1) {
            u64 p = __shfl_xor(v2, j);
            bool iLower = (lane & j) == 0;
            bool keepMax = (iLower == desc);
            bool pGreater = p > v2;
            v2 = (keepMax == pGreater) ? p : v2;
          }
          SW[t] = v2;
          __syncthreads();
        }
      }
      // ---- decode row t ----
      decode_one(SW[t], a4, r4, W, H, &box4[t], &area[t], &ssc[t], &sidb[t]);
      __syncthreads();
      if (t < 64)
        nms_scan64(8, box4, area, ssc, fx, fy, fX, fY, fA, wx, wy, wX, wY, wA,
                   s_keep, s_pre, &s_total, lane);
      __syncthreads();
      slow = (s_total < (unsigned)MAXD);   // kept>=100 => provably exact
    }
  }

  if (slow) {
    // ---- complete legacy path from cls (round-1 proven; correctness-only) ----
    if (t == 0) { s_cnt = 0u; s_total = 0u; }
    if (t < 16) { s_keep[t] = 0ull; s_pre[t] = 0u; }
    for (int i = t; i < 4096; i += BT) histS[i] = 0u;
    __syncthreads();
    for (int a = t; a < A; a += BT) {
      float s = cls[(size_t)a * NCLS + c];
      if (s > THR_SCORE) {
        int b = (int)(s * 4096.0f);
        b = b < 0 ? 0 : (b > 4095 ? 4095 : b);
        atomicAdd(&histS[b], 1u);
      }
    }
    __syncthreads();
    if (t == 0) {
      unsigned acc = 0;
      int cb = 0;
      for (int b = 4095; b >= 0; b--) {
        acc += histS[b];
        if (acc >= (unsigned)PRE) { cb = b; break; }
      }
      if (acc < (unsigned)PRE) cb = 0;
      while (acc > 2048u && cb < 4095) { acc -= histS[cb]; cb++; }
      s_cb = cb;
    }
    __syncthreads();
    const int cb = s_cb;
    for (int i = t; i < 2048; i += BT) candS[i] = 0ull;
    __syncthreads();
    for (int a = t; a < A; a += BT) {
      float s = cls[(size_t)a * NCLS + c];
      if (s > THR_SCORE) {
        int b = (int)(s * 4096.0f);
        b = b < 0 ? 0 : (b > 4095 ? 4095 : b);
        if (b >= cb) {
          unsigned p = atomicAdd(&s_cnt, 1u);
          if (p < 2048u)
            candS[p] = ((u64)__float_as_uint(s) << 32) | (u64)(~(unsigned)a);
        }
      }
    }
    __syncthreads();
    for (int k = 2; k <= 2048; k <<= 1) {
      for (int j = k >> 1; j > 0; j >>= 1) {
        for (int i = t; i < 2048; i += BT) {
          int ixj = i ^ j;
          if (ixj > i) {
            u64 va = candS[i], vb = candS[ixj];
            bool desc = ((i & k) == 0);
            if (desc ? (va < vb) : (va > vb)) { candS[i] = vb; candS[ixj] = va; }
          }
        }
        __syncthreads();
      }
    }
    for (int i = t; i < 1024; i += BT) {
      u64 key = (i < PRE) ? candS[i] : 0ull;
      decode_one(key, a4, r4, W, H, &box4[i], &area[i], &ssc[i], &sidb[i]);
      if (i >= PRE) ssc[i] = -INFINITY;
    }
    __syncthreads();
    if (t < 64)
      nms_scan64(16, box4, area, ssc, fx, fy, fX, fY, fA, wx, wy, wX, wY, wA,
                 s_keep, s_pre, &s_total, lane);
    __syncthreads();
  }

  // ---- output ----
  const unsigned total = s_total;
  for (int k = t; k < PRE; k += BT) {
    int w = k >> 6, b = k & 63;
    u64 kw = s_keep[w];
    if ((kw >> b) & 1ull) {
      unsigned rank = s_pre[w] + (unsigned)__popcll(kw & ((1ull << b) - 1ull));
      if (rank < MAXD) {
        int slot = c * MAXD + (int)rank;
        out_s[slot] = ssc[k];
        out_id[slot] = (float)c;
        ((float4*)out_b)[slot] = box4[k];
        out_d[slot] = dist[sidb[k]];
      }
    }
  }
  unsigned tk = total < (unsigned)MAXD ? total : (unsigned)MAXD;
  for (int r2 = (int)tk + t; r2 < MAXD; r2 += BT) {
    int slot = c * MAXD + r2;
    out_s[slot] = 0.0f;
    out_id[slot] = -1.0f;
    ((float4*)out_b)[slot] = make_float4(0.f, 0.f, 0.f, 0.f);
    out_d[slot] = 0.0f;
  }
}

// =====================================================================
// FALLBACK PATH (round-1, proven correct; used only if ws is too small)
// =====================================================================
#define NBUCK 4096
#define CANDF 2048

__global__ __launch_bounds__(256) void select_topk(
    const float* __restrict__ cls, int A,
    float* __restrict__ topscore, unsigned* __restrict__ topidx)
{
  const int c = blockIdx.x;
  const int t = threadIdx.x;
  __shared__ unsigned hist[NBUCK];
  __shared__ u64 cand[CANDF];
  __shared__ unsigned chunk[256];
  __shared__ int s_cb;
  __shared__ int s_cnt;
  for (int i = t; i < NBUCK; i += 256) hist[i] = 0u;
  if (t == 0) s_cnt = 0;
  __syncthreads();
  for (int a = t; a < A; a += 256) {
    float s = cls[(size_t)a * NCLS + c];
    if (s > THR_SCORE) {
      int b = (int)(s * (float)NBUCK);
      b = b < 0 ? 0 : (b > NBUCK - 1 ? NBUCK - 1 : b);
      atomicAdd(&hist[b], 1u);
    }
  }
  __syncthreads();
  {
    unsigned cs = 0;
    for (int i = 0; i < NBUCK / 256; i++) cs += hist[t * (NBUCK / 256) + i];
    chunk[t] = cs;
  }
  __syncthreads();
  if (t == 0) {
    unsigned acc = 0;
    int cb = 0;
    int ch;
    for (ch = 255; ch >= 0; ch--) {
      if (acc + chunk[ch] >= (unsigned)PRE) break;
      acc += chunk[ch];
    }
    if (ch < 0) cb = 0;
    else {
      const int bpc = NBUCK / 256;
      int b = ch * bpc + bpc - 1;
      for (; b >= ch * bpc; b--) { acc += hist[b]; if (acc >= (unsigned)PRE) break; }
      if (b < ch * bpc) b = ch * bpc;
      cb = b;
      while (acc > (unsigned)CANDF && cb < NBUCK - 1) { acc -= hist[cb]; cb++; }
    }
    s_cb = cb;
  }
  __syncthreads();
  const int cb = s_cb;
  for (int a = t; a < A; a += 256) {
    float s = cls[(size_t)a * NCLS + c];
    if (s > THR_SCORE) {
      int b = (int)(s * (float)NBUCK);
      b = b < 0 ? 0 : (b > NBUCK - 1 ? NBUCK - 1 : b);
      if (b >= cb) {
        int p = atomicAdd(&s_cnt, 1);
        if (p < CANDF)
          cand[p] = ((u64)__float_as_uint(s) << 32) | (u64)(~(unsigned)a);
      }
    }
  }
  __syncthreads();
  int n = s_cnt < CANDF ? s_cnt : CANDF;
  for (int i = n + t; i < CANDF; i += 256) cand[i] = 0ull;
  __syncthreads();
  for (int k = 2; k <= CANDF; k <<= 1) {
    for (int j = k >> 1; j > 0; j >>= 1) {
      for (int i = t; i < CANDF; i += 256) {
        int ixj = i ^ j;
        if (ixj > i) {
          u64 va = cand[i], vb = cand[ixj];
          bool desc = ((i & k) == 0);
          if (desc ? (va < vb) : (va > vb)) { cand[i] = vb; cand[ixj] = va; }
        }
      }
      __syncthreads();
    }
  }
  for (int k = t; k < PRE; k += 256) {
    u64 key = cand[k];
    float sc; unsigned idx;
    if (key != 0ull) { sc = __uint_as_float((unsigned)(key >> 32)); idx = ~((unsigned)(key & 0xFFFFFFFFull)); }
    else { sc = -INFINITY; idx = 0u; }
    topscore[c * PRE + k] = sc;
    topidx[c * PRE + k] = idx;
  }
}

__global__ __launch_bounds__(256) void nms_out(
    const float* __restrict__ anch, const float* __restrict__ reg,
    const float* __restrict__ dist,
    const float* __restrict__ topscore, const unsigned* __restrict__ topidx,
    const int* __restrict__ img_h_p, const int* __restrict__ img_w_p,
    float* __restrict__ out_s, float* __restrict__ out_id,
    float* __restrict__ out_b, float* __restrict__ out_d)
{
#pragma clang fp contract(off)
  const int c = blockIdx.x;
  const int t = threadIdx.x;
  __shared__ float bx[PRE], by[PRE], bX[PRE], bY[PRE], bar[PRE], ssc[PRE];
  __shared__ u64 supm[PRE * 16];
  __shared__ u64 keepw[16];
  __shared__ unsigned wpre[17];
  const float W = (float)img_w_p[0];
  const float H = (float)img_h_p[0];
  for (int k = t; k < PRE; k += 256) {
    float sc = topscore[c * PRE + k];
    unsigned idx = topidx[c * PRE + k];
    ssc[k] = sc;
    float a0 = anch[(size_t)idx * 4 + 0], a1 = anch[(size_t)idx * 4 + 1];
    float a2 = anch[(size_t)idx * 4 + 2], a3 = anch[(size_t)idx * 4 + 3];
    float r0 = reg[(size_t)idx * 4 + 0], r1 = reg[(size_t)idx * 4 + 1];
    float r2 = reg[(size_t)idx * 4 + 2], r3 = reg[(size_t)idx * 4 + 3];
    float w = a2 - a0, h = a3 - a1;
    float cx = a0 + 0.5f * w, cy = a1 + 0.5f * h;
    float dx = r0 * 0.1f, dy = r1 * 0.1f, dw = r2 * 0.2f, dh = r3 * 0.2f;
    float pcx = cx + dx * w, pcy = cy + dy * h;
    float pw = (float)exp((double)dw) * w;
    float ph = (float)exp((double)dh) * h;
    float x1 = fminf(fmaxf(pcx - 0.5f * pw, 0.0f), W);
    float y1 = fminf(fmaxf(pcy - 0.5f * ph, 0.0f), H);
    float x2 = fminf(fmaxf(pcx + 0.5f * pw, 0.0f), W);
    float y2 = fminf(fmaxf(pcy + 0.5f * ph, 0.0f), H);
    bx[k] = x1; by[k] = y1; bX[k] = x2; bY[k] = y2;
    bar[k] = (x2 - x1) * (y2 - y1);
  }
  __syncthreads();
  const int wave = t >> 6, lane = t & 63;
  for (int i = wave; i < PRE; i += 4) {
    float x1 = bx[i], y1 = by[i], X1 = bX[i], Y1 = bY[i], ai = bar[i];
    for (int g = 0; g < 16; g++) {
      int j = g * 64 + lane;
      bool s = false;
      if (j > i && j < PRE) {
        float ltx = fmaxf(x1, bx[j]);
        float lty = fmaxf(y1, by[j]);
        float rbx = fminf(X1, bX[j]);
        float rby = fminf(Y1, bY[j]);
        float ww = fmaxf(rbx - ltx, 0.0f);
        float hh = fmaxf(rby - lty, 0.0f);
        float inter = ww * hh;
        float iou = inter / ((ai + bar[j]) - inter + 1e-8f);
        s = iou > 0.5f;
      }
      u64 m = __ballot(s);
      if (lane == 0) supm[i * 16 + g] = m;
    }
  }
  __syncthreads();
  if (t < 64) {
    u64 kw = 0ull;
    if (t < 16) {
      for (int b = 0; b < 64; b++) {
        int k = t * 64 + b;
        if (k < PRE && ssc[k] != -INFINITY) kw |= (1ull << b);
      }
    }
    for (int i = 0; i < PRE; i++) {
      u64 ow = __shfl(kw, i >> 6);
      if ((ow >> (i & 63)) & 1ull) {
        if (t < 16) kw &= ~supm[i * 16 + t];
      }
    }
    if (t < 16) keepw[t] = kw;
  }
  __syncthreads();
  if (t == 0) {
    unsigned acc = 0;
    for (int w = 0; w < 16; w++) { wpre[w] = acc; acc += (unsigned)__popcll(keepw[w]); }
    wpre[16] = acc;
  }
  __syncthreads();
  const unsigned total = wpre[16];
  for (int k = t; k < PRE; k += 256) {
    int w = k >> 6, b = k & 63;
    u64 kw = keepw[w];
    if ((kw >> b) & 1ull) {
      unsigned rank = wpre[w] + (unsigned)__popcll(kw & ((1ull << b) - 1ull));
      if (rank < MAXD) {
        int slot = c * MAXD + (int)rank;
        out_s[slot] = ssc[k];
        out_id[slot] = (float)c;
        out_b[slot * 4 + 0] = bx[k];
        out_b[slot * 4 + 1] = by[k];
        out_b[slot * 4 + 2] = bX[k];
        out_b[slot * 4 + 3] = bY[k];
        out_d[slot] = dist[topidx[c * PRE + k]];
      }
    }
  }
  unsigned tk = total < MAXD ? total : MAXD;
  for (int r = (int)tk + t; r < MAXD; r += 256) {
    int slot = c * MAXD + r;
    out_s[slot] = 0.0f;
    out_id[slot] = -1.0f;
    out_b[slot * 4 + 0] = 0.0f; out_b[slot * 4 + 1] = 0.0f;
    out_b[slot * 4 + 2] = 0.0f; out_b[slot * 4 + 3] = 0.0f;
    out_d[slot] = 0.0f;
  }
}

// =====================================================================

static inline size_t align512(size_t x) { return (x + 511) & ~(size_t)511; }

extern "C" void kernel_launch(void* const* d_in, const int* in_sizes, int n_in,
                              void* d_out, int out_size, void* d_ws, size_t ws_size,
                              hipStream_t stream) {
  const float* cls  = (const float*)d_in[0];   // (1, A, 80)
  const float* reg  = (const float*)d_in[1];   // (1, A, 4)
  const float* dist = (const float*)d_in[2];   // (1, A, 1)
  const float* anch = (const float*)d_in[3];   // (1, A, 4)
  const int* img_h  = (const int*)d_in[4];
  const int* img_w  = (const int*)d_in[5];
  const int A = in_sizes[3] / 4;

  float* o = (float*)d_out;
  float* out_s  = o;                      // 8000
  float* out_id = o + NCLS * MAXD;        // 8000
  float* out_b  = o + 2 * NCLS * MAXD;    // 32000
  float* out_d  = o + 6 * NCLS * MAXD;    // 8000

  const int total4 = A * 20;  // A*80/4
  const int nblk = (total4 + 256 * K3K - 1) / (256 * K3K);   // k3 grid (~480)

  size_t off = 0;
  const size_t o_cand = off; off += align512((size_t)nblk * NCLS * SEGCAP * sizeof(u64)); // ~4.9 MB
  const size_t o_cnt  = off; off += align512((size_t)nblk * NCLS * sizeof(unsigned));     // ~154 KB
  const size_t needed = off;

  if (ws_size >= needed) {
    char* ws = (char*)d_ws;
    u64* cand = (u64*)(ws + o_cand);
    unsigned* cnt = (unsigned*)(ws + o_cnt);

    k3_collect<<<nblk, 256, 0, stream>>>((const vfloat4*)cls, total4, cnt, cand);
    kAD_sort_nms<<<NCLS, BT, 0, stream>>>(cnt, cand, nblk, cls, A, anch, reg, dist,
                                          img_h, img_w, out_s, out_id, out_b, out_d);
  } else {
    // fallback: proven round-1 path (needs only ~0.64 MB)
    float* topscore = (float*)d_ws;
    unsigned* topidx = (unsigned*)((char*)d_ws + NCLS * PRE * sizeof(float));
    select_topk<<<NCLS, 256, 0, stream>>>(cls, A, topscore, topidx);
    nms_out<<<NCLS, 256, 0, stream>>>(anch, reg, dist, topscore, topidx,
                                      img_h, img_w, out_s, out_id, out_b, out_d);
  }
}

// Round 16
// 44.198 us; speedup vs baseline: 2.9140x; 1.2292x over previous
//
#include <hip/hip_runtime.h>
#include <math.h>

#define NCLS 80
#define PRE 1000
#define MAXD 100
#define THR_SCORE 0.05f
#define TFIX 0.9985f           // fixed collection threshold (fast path)

#define SEGCAP 8               // candidates per (block, class) segment (1 cache line)
#define BT 512                 // kAD block threads
#define K3K 16                 // float4 loads per thread in k3 (MLP depth)

typedef unsigned long long u64;
typedef float vfloat4 __attribute__((ext_vector_type(4)));

__device__ __forceinline__ u64 readlane64(u64 v, int l) {
  unsigned lo = (unsigned)__builtin_amdgcn_readlane((int)(unsigned)v, l);
  unsigned hi = (unsigned)__builtin_amdgcn_readlane((int)(unsigned)(v >> 32), l);
  return ((u64)hi << 32) | lo;
}

// =====================================================================
// K3: tiled coalesced pass, 16-deep MLP, nt reads. Per-block private segments
// in TRANSPOSED layout (class-major) so kAD's gather is coalesced.
__global__ __launch_bounds__(256) void k3_collect(
    const vfloat4* __restrict__ cls4, int total4, int nblk,
    unsigned* __restrict__ cnt, u64* __restrict__ cand)
{
  __shared__ unsigned lcnt[NCLS];
  const int t = threadIdx.x;
  const int b = blockIdx.x;
  if (t < NCLS) lcnt[t] = 0u;
  __syncthreads();
  const int base = b * (256 * K3K) + t;
  vfloat4 v[K3K];
#pragma unroll
  for (int k = 0; k < K3K; k++) {
    int q = base + k * 256;
    if (q < total4) v[k] = __builtin_nontemporal_load(&cls4[q]);
    else v[k] = (vfloat4)(0.f);
  }
#pragma unroll
  for (int k = 0; k < K3K; k++) {
    int q = base + k * 256;
    if (q < total4) {
      int c0 = 4 * (q % 20);
      unsigned a = (unsigned)(q / 20);
      float sv[4] = {v[k].x, v[k].y, v[k].z, v[k].w};
#pragma unroll
      for (int e = 0; e < 4; e++) {
        float s = sv[e];
        if (s >= TFIX) {
          int c = c0 + e;
          unsigned p = atomicAdd(&lcnt[c], 1u);
          if (p < SEGCAP)
            cand[((size_t)c * nblk + b) * SEGCAP + p] =
                ((u64)__float_as_uint(s) << 32) | (u64)(~a);
        }
      }
    }
  }
  __syncthreads();
  if (t < NCLS) cnt[(size_t)t * nblk + b] = lcnt[t];
}

// NMS over sorted rows in LDS; wave 0 of the block (caller guards t<64).
__device__ __forceinline__ void nms_scan64(
    int windows, const float4* box4, const float* area, const float* ssc,
    float* fx, float* fy, float* fXX, float* fYY, float* fAA,
    float* wx, float* wy, float* wXX, float* wYY, float* wAA,
    u64* s_keep, unsigned* s_pre, unsigned* s_total, int lane)
{
#pragma clang fp contract(off)
  const double MID = 0x1.000001p-1;
  unsigned acc = 0;
  int nf = 0;
  for (int w = 0; w < windows; w++) {
    const int r = w * 64 + lane;
    const float4 rb = box4[r];
    const float ra = area[r];
    bool dead = (ssc[r] == -INFINITY);
    for (int f = 0; f < nf; f++) {
      float ltx = fmaxf(rb.x, fx[f]);
      float lty = fmaxf(rb.y, fy[f]);
      float rbx = fminf(rb.z, fXX[f]);
      float rby = fminf(rb.w, fYY[f]);
      float ww = fmaxf(rbx - ltx, 0.0f);
      float hh = fmaxf(rby - lty, 0.0f);
      float inter = ww * hh;
      float denom = ((ra + fAA[f]) - inter) + 1e-8f;
      dead = dead | ((double)inter > MID * (double)denom);
    }
    u64 alive = __ballot(!dead);
    u64 F = 0ull;
    if (alive) {
      wx[lane] = rb.x; wy[lane] = rb.y; wXX[lane] = rb.z; wYY[lane] = rb.w; wAA[lane] = ra;
      u64 Rw = 0ull;
#pragma unroll 4
      for (int i = 0; i < 64; i++) {
        float ltx = fmaxf(wx[i], rb.x);
        float lty = fmaxf(wy[i], rb.y);
        float rbx = fminf(wXX[i], rb.z);
        float rby = fminf(wYY[i], rb.w);
        float ww = fmaxf(rbx - ltx, 0.0f);
        float hh = fmaxf(rby - lty, 0.0f);
        float inter = ww * hh;
        float denom = ((wAA[i] + ra) - inter) + 1e-8f;
        bool io = (double)inter > MID * (double)denom;
        u64 m = __ballot(io & (lane > i));
        Rw = (lane == i) ? m : Rw;
      }
      while (alive) {
        int b = __builtin_ctzll(alive);
        F |= (1ull << b);
        u64 rbw = readlane64(Rw, b);
        alive &= ~(rbw | (1ull << b));
      }
      if ((F >> lane) & 1ull) {
        int pos = nf + (int)__popcll(F & ((1ull << lane) - 1ull));
        if (pos < 192) {
          fx[pos] = rb.x; fy[pos] = rb.y; fXX[pos] = rb.z; fYY[pos] = rb.w; fAA[pos] = ra;
        }
      }
    }
    if (lane == 0) { s_keep[w] = F; s_pre[w] = acc; }
    acc += (unsigned)__popcll(F);
    nf += (int)__popcll(F);
    if (acc >= (unsigned)MAXD) break;
  }
  if (lane == 0) *s_total = acc;
}

__device__ __forceinline__ void decode_one(
    u64 key, const float4* a4, const float4* r4, float W, float H,
    float4* obox, float* oarea, float* ossc, unsigned* oidx)
{
#pragma clang fp contract(off)
  float sc; unsigned idx;
  if (key != 0ull) {
    sc = __uint_as_float((unsigned)(key >> 32));
    idx = ~((unsigned)(key & 0xFFFFFFFFull));
  } else {
    sc = -INFINITY; idx = 0u;
  }
  float4 av = a4[idx];
  float4 rv = r4[idx];
  float w = av.z - av.x, h = av.w - av.y;
  float cx = av.x + 0.5f * w, cy = av.y + 0.5f * h;
  float dx = rv.x * 0.1f, dy = rv.y * 0.1f, dw = rv.z * 0.2f, dh = rv.w * 0.2f;
  float pcx = cx + dx * w, pcy = cy + dy * h;
  float pw = (float)exp((double)dw) * w;
  float ph = (float)exp((double)dh) * h;
  float x1 = fminf(fmaxf(pcx - 0.5f * pw, 0.0f), W);
  float y1 = fminf(fmaxf(pcy - 0.5f * ph, 0.0f), H);
  float x2 = fminf(fmaxf(pcx + 0.5f * pw, 0.0f), W);
  float y2 = fminf(fmaxf(pcy + 0.5f * ph, 0.0f), H);
  *obox = make_float4(x1, y1, x2, y2);
  *oarea = (x2 - x1) * (y2 - y1);
  *ossc = sc;
  *oidx = idx;
}

// kAD: coalesced segment gather (wave-scan offsets) -> direct sort-512 of the
// COMPLETE collected set -> decode -> early-exit NMS. Exact iff no segment
// overflow, n<=512, and kept>=100 ({s>=TFIX} is a prefix of the global order);
// otherwise complete in-kernel legacy path from cls.
__global__ __launch_bounds__(BT) void kAD_sort_nms(
    const unsigned* __restrict__ cnt, const u64* __restrict__ cand, int nblk,
    const float* __restrict__ cls, int A,
    const float* __restrict__ anch, const float* __restrict__ reg,
    const float* __restrict__ dist,
    const int* __restrict__ img_h_p, const int* __restrict__ img_w_p,
    float* __restrict__ out_s, float* __restrict__ out_id,
    float* __restrict__ out_b, float* __restrict__ out_d)
{
#pragma clang fp contract(off)
  const int c = blockIdx.x;
  const int t = threadIdx.x;
  const int lane = t & 63;
  // carved LDS: slow path uses full regions; fast path aliases prefixes
  __shared__ __align__(16) char smem[61440];
  u64* candS = (u64*)smem;                          // 2048 u64 (fast: 512 sort buf | slow: sort buf)
  unsigned* histS = (unsigned*)(smem + 16384);      // slow: 4096 u32
  float4* box4 = (float4*)(smem + 32768);           // 1024 float4
  float* area  = (float*)(smem + 49152);            // 1024 f32
  float* ssc   = (float*)(smem + 53248);            // 1024 f32
  unsigned* sidb = (unsigned*)(smem + 57344);       // 1024 u32
  __shared__ unsigned s_ovf, s_gn, s_cnt;
  __shared__ int s_cb;
  __shared__ float fx[192], fy[192], fX[192], fY[192], fA[192];
  __shared__ float wx[64], wy[64], wX[64], wY[64], wA[64];
  __shared__ u64 s_keep[16];
  __shared__ unsigned s_pre[16];
  __shared__ unsigned s_total;

  if (t == 0) { s_ovf = 0u; s_gn = 0u; s_cnt = 0u; s_total = 0u; }
  if (t < 16) { s_keep[t] = 0ull; s_pre[t] = 0u; }
  candS[t] = 0ull;   // fast sort buffer [0,512)
  __syncthreads();

  // ---- gather phase 1: coalesced counts + wave-scan offsets ----
  const int ROUNDS = (nblk + BT - 1) / BT;   // 2 for nblk=960
  unsigned my_off[4];
  unsigned my_cv[4];
  int my_i[4];
  for (int r = 0; r < ROUNDS && r < 4; r++) {
    int i = r * BT + t;
    unsigned cv = 0u;
    if (i < nblk) cv = cnt[(size_t)c * nblk + i];
    if (cv > SEGCAP) { atomicOr(&s_ovf, 1u); cv = 0u; }
    unsigned incl = cv;
#pragma unroll
    for (int d = 1; d < 64; d <<= 1) {
      unsigned x = __shfl_up(incl, d);
      if (lane >= d) incl += x;
    }
    unsigned wtot = __shfl(incl, 63);
    unsigned wbase = 0u;
    if (lane == 63) wbase = atomicAdd(&s_gn, wtot);
    wbase = __shfl(wbase, 63);
    my_off[r] = wbase + incl - cv;
    my_cv[r] = cv;
    my_i[r] = i;
  }
  __syncthreads();
  const unsigned n = s_gn;
  const bool fits = (s_ovf == 0u) && (n >= 1u) && (n <= 512u);

  const float W = (float)img_w_p[0];
  const float H = (float)img_h_p[0];
  const float4* a4 = (const float4*)anch;
  const float4* r4 = (const float4*)reg;
  bool slow = true;

  if (fits) {
    // ---- gather phase 2: copy segments (order irrelevant; sort fixes it) ----
    for (int r = 0; r < ROUNDS && r < 4; r++) {
      unsigned cv = my_cv[r];
      if (cv) {
        const u64* src = cand + ((size_t)c * nblk + my_i[r]) * SEGCAP;
        unsigned o = my_off[r];
        for (unsigned j = 0; j < cv; j++) candS[o + j] = src[j];
      }
    }
    __syncthreads();
    // ---- hybrid bitonic sort of 512 desc (1 elem/thread; proven) ----
    u64* SW = candS;
    {
      u64 v = SW[t];
#pragma unroll
      for (int k = 2; k <= 64; k <<= 1) {
#pragma unroll
        for (int j = k >> 1; j > 0; j >>= 1) {
          u64 p = __shfl_xor(v, j);
          bool iLower = (lane & j) == 0;
          bool desc = (t & k) == 0;
          bool keepMax = (iLower == desc);
          bool pGreater = p > v;
          v = (keepMax == pGreater) ? p : v;
        }
      }
      SW[t] = v;
      __syncthreads();
      for (int k = 128; k <= 512; k <<= 1) {
        for (int j = k >> 1; j >= 64; j >>= 1) {
          if ((t & j) == 0) {
            u64 a = SW[t], b = SW[t ^ j];
            bool desc = ((t & k) == 0);
            if (desc ? (a < b) : (a > b)) { SW[t] = b; SW[t ^ j] = a; }
          }
          __syncthreads();
        }
        u64 v2 = SW[t];
        bool desc = ((t & k) == 0);
#pragma unroll
        for (int j = 32; j > 0; j >>= 1) {
          u64 p = __shfl_xor(v2, j);
          bool iLower = (lane & j) == 0;
          bool keepMax = (iLower == desc);
          bool pGreater = p > v2;
          v2 = (keepMax == pGreater) ? p : v2;
        }
        SW[t] = v2;
        __syncthreads();
      }
    }
    // ---- decode row t ----
    decode_one(SW[t], a4, r4, W, H, &box4[t], &area[t], &ssc[t], &sidb[t]);
    __syncthreads();
    if (t < 64)
      nms_scan64(8, box4, area, ssc, fx, fy, fX, fY, fA, wx, wy, wX, wY, wA,
                 s_keep, s_pre, &s_total, lane);
    __syncthreads();
    slow = (s_total < (unsigned)MAXD);   // kept>=100 => provably exact
  }

  if (slow) {
    // ---- complete legacy path from cls (round-1 proven; correctness-only) ----
    if (t == 0) { s_cnt = 0u; s_total = 0u; }
    if (t < 16) { s_keep[t] = 0ull; s_pre[t] = 0u; }
    for (int i = t; i < 4096; i += BT) histS[i] = 0u;
    __syncthreads();
    for (int a = t; a < A; a += BT) {
      float s = cls[(size_t)a * NCLS + c];
      if (s > THR_SCORE) {
        int b = (int)(s * 4096.0f);
        b = b < 0 ? 0 : (b > 4095 ? 4095 : b);
        atomicAdd(&histS[b], 1u);
      }
    }
    __syncthreads();
    if (t == 0) {
      unsigned acc = 0;
      int cb = 0;
      for (int b = 4095; b >= 0; b--) {
        acc += histS[b];
        if (acc >= (unsigned)PRE) { cb = b; break; }
      }
      if (acc < (unsigned)PRE) cb = 0;
      while (acc > 2048u && cb < 4095) { acc -= histS[cb]; cb++; }
      s_cb = cb;
    }
    __syncthreads();
    const int cb = s_cb;
    for (int i = t; i < 2048; i += BT) candS[i] = 0ull;
    __syncthreads();
    for (int a = t; a < A; a += BT) {
      float s = cls[(size_t)a * NCLS + c];
      if (s > THR_SCORE) {
        int b = (int)(s * 4096.0f);
        b = b < 0 ? 0 : (b > 4095 ? 4095 : b);
        if (b >= cb) {
          unsigned p = atomicAdd(&s_cnt, 1u);
          if (p < 2048u)
            candS[p] = ((u64)__float_as_uint(s) << 32) | (u64)(~(unsigned)a);
        }
      }
    }
    __syncthreads();
    for (int k = 2; k <= 2048; k <<= 1) {
      for (int j = k >> 1; j > 0; j >>= 1) {
        for (int i = t; i < 2048; i += BT) {
          int ixj = i ^ j;
          if (ixj > i) {
            u64 va = candS[i], vb = candS[ixj];
            bool desc = ((i & k) == 0);
            if (desc ? (va < vb) : (va > vb)) { candS[i] = vb; candS[ixj] = va; }
          }
        }
        __syncthreads();
      }
    }
    for (int i = t; i < 1024; i += BT) {
      u64 key = (i < PRE) ? candS[i] : 0ull;
      decode_one(key, a4, r4, W, H, &box4[i], &area[i], &ssc[i], &sidb[i]);
      if (i >= PRE) ssc[i] = -INFINITY;
    }
    __syncthreads();
    if (t < 64)
      nms_scan64(16, box4, area, ssc, fx, fy, fX, fY, fA, wx, wy, wX, wY, wA,
                 s_keep, s_pre, &s_total, lane);
    __syncthreads();
  }

  // ---- output ----
  const unsigned total = s_total;
  for (int k = t; k < PRE; k += BT) {
    int w = k >> 6, b = k & 63;
    u64 kw = s_keep[w];
    if ((kw >> b) & 1ull) {
      unsigned rank = s_pre[w] + (unsigned)__popcll(kw & ((1ull << b) - 1ull));
      if (rank < MAXD) {
        int slot = c * MAXD + (int)rank;
        out_s[slot] = ssc[k];
        out_id[slot] = (float)c;
        ((float4*)out_b)[slot] = box4[k];
        out_d[slot] = dist[sidb[k]];
      }
    }
  }
  unsigned tk = total < (unsigned)MAXD ? total : (unsigned)MAXD;
  for (int r2 = (int)tk + t; r2 < MAXD; r2 += BT) {
    int slot = c * MAXD + r2;
    out_s[slot] = 0.0f;
    out_id[slot] = -1.0f;
    ((float4*)out_b)[slot] = make_float4(0.f, 0.f, 0.f, 0.f);
    out_d[slot] = 0.0f;
  }
}

// =====================================================================
// FALLBACK PATH (round-1, proven correct; used only if ws is too small)
// =====================================================================
#define NBUCK 4096
#define CANDF 2048

__global__ __launch_bounds__(256) void select_topk(
    const float* __restrict__ cls, int A,
    float* __restrict__ topscore, unsigned* __restrict__ topidx)
{
  const int c = blockIdx.x;
  const int t = threadIdx.x;
  __shared__ unsigned hist[NBUCK];
  __shared__ u64 cand[CANDF];
  __shared__ unsigned chunk[256];
  __shared__ int s_cb;
  __shared__ int s_cnt;
  for (int i = t; i < NBUCK; i += 256) hist[i] = 0u;
  if (t == 0) s_cnt = 0;
  __syncthreads();
  for (int a = t; a < A; a += 256) {
    float s = cls[(size_t)a * NCLS + c];
    if (s > THR_SCORE) {
      int b = (int)(s * (float)NBUCK);
      b = b < 0 ? 0 : (b > NBUCK - 1 ? NBUCK - 1 : b);
      atomicAdd(&hist[b], 1u);
    }
  }
  __syncthreads();
  {
    unsigned cs = 0;
    for (int i = 0; i < NBUCK / 256; i++) cs += hist[t * (NBUCK / 256) + i];
    chunk[t] = cs;
  }
  __syncthreads();
  if (t == 0) {
    unsigned acc = 0;
    int cb = 0;
    int ch;
    for (ch = 255; ch >= 0; ch--) {
      if (acc + chunk[ch] >= (unsigned)PRE) break;
      acc += chunk[ch];
    }
    if (ch < 0) cb = 0;
    else {
      const int bpc = NBUCK / 256;
      int b = ch * bpc + bpc - 1;
      for (; b >= ch * bpc; b--) { acc += hist[b]; if (acc >= (unsigned)PRE) break; }
      if (b < ch * bpc) b = ch * bpc;
      cb = b;
      while (acc > (unsigned)CANDF && cb < NBUCK - 1) { acc -= hist[cb]; cb++; }
    }
    s_cb = cb;
  }
  __syncthreads();
  const int cb = s_cb;
  for (int a = t; a < A; a += 256) {
    float s = cls[(size_t)a * NCLS + c];
    if (s > THR_SCORE) {
      int b = (int)(s * (float)NBUCK);
      b = b < 0 ? 0 : (b > NBUCK - 1 ? NBUCK - 1 : b);
      if (b >= cb) {
        int p = atomicAdd(&s_cnt, 1);
        if (p < CANDF)
          cand[p] = ((u64)__float_as_uint(s) << 32) | (u64)(~(unsigned)a);
      }
    }
  }
  __syncthreads();
  int n = s_cnt < CANDF ? s_cnt : CANDF;
  for (int i = n + t; i < CANDF; i += 256) cand[i] = 0ull;
  __syncthreads();
  for (int k = 2; k <= CANDF; k <<= 1) {
    for (int j = k >> 1; j > 0; j >>= 1) {
      for (int i = t; i < CANDF; i += 256) {
        int ixj = i ^ j;
        if (ixj > i) {
          u64 va = cand[i], vb = cand[ixj];
          bool desc = ((i & k) == 0);
          if (desc ? (va < vb) : (va > vb)) { cand[i] = vb; cand[ixj] = va; }
        }
      }
      __syncthreads();
    }
  }
  for (int k = t; k < PRE; k += 256) {
    u64 key = cand[k];
    float sc; unsigned idx;
    if (key != 0ull) { sc = __uint_as_float((unsigned)(key >> 32)); idx = ~((unsigned)(key & 0xFFFFFFFFull)); }
    else { sc = -INFINITY; idx = 0u; }
    topscore[c * PRE + k] = sc;
    topidx[c * PRE + k] = idx;
  }
}

__global__ __launch_bounds__(256) void nms_out(
    const float* __restrict__ anch, const float* __restrict__ reg,
    const float* __restrict__ dist,
    const float* __restrict__ topscore, const unsigned* __restrict__ topidx,
    const int* __restrict__ img_h_p, const int* __restrict__ img_w_p,
    float* __restrict__ out_s, float* __restrict__ out_id,
    float* __restrict__ out_b, float* __restrict__ out_d)
{
#pragma clang fp contract(off)
  const int c = blockIdx.x;
  const int t = threadIdx.x;
  __shared__ float bx[PRE], by[PRE], bX[PRE], bY[PRE], bar[PRE], ssc[PRE];
  __shared__ u64 supm[PRE * 16];
  __shared__ u64 keepw[16];
  __shared__ unsigned wpre[17];
  const float W = (float)img_w_p[0];
  const float H = (float)img_h_p[0];
  for (int k = t; k < PRE; k += 256) {
    float sc = topscore[c * PRE + k];
    unsigned idx = topidx[c * PRE + k];
    ssc[k] = sc;
    float a0 = anch[(size_t)idx * 4 + 0], a1 = anch[(size_t)idx * 4 + 1];
    float a2 = anch[(size_t)idx * 4 + 2], a3 = anch[(size_t)idx * 4 + 3];
    float r0 = reg[(size_t)idx * 4 + 0], r1 = reg[(size_t)idx * 4 + 1];
    float r2 = reg[(size_t)idx * 4 + 2], r3 = reg[(size_t)idx * 4 + 3];
    float w = a2 - a0, h = a3 - a1;
    float cx = a0 + 0.5f * w, cy = a1 + 0.5f * h;
    float dx = r0 * 0.1f, dy = r1 * 0.1f, dw = r2 * 0.2f, dh = r3 * 0.2f;
    float pcx = cx + dx * w, pcy = cy + dy * h;
    float pw = (float)exp((double)dw) * w;
    float ph = (float)exp((double)dh) * h;
    float x1 = fminf(fmaxf(pcx - 0.5f * pw, 0.0f), W);
    float y1 = fminf(fmaxf(pcy - 0.5f * ph, 0.0f), H);
    float x2 = fminf(fmaxf(pcx + 0.5f * pw, 0.0f), W);
    float y2 = fminf(fmaxf(pcy + 0.5f * ph, 0.0f), H);
    bx[k] = x1; by[k] = y1; bX[k] = x2; bY[k] = y2;
    bar[k] = (x2 - x1) * (y2 - y1);
  }
  __syncthreads();
  const int wave = t >> 6, lane = t & 63;
  for (int i = wave; i < PRE; i += 4) {
    float x1 = bx[i], y1 = by[i], X1 = bX[i], Y1 = bY[i], ai = bar[i];
    for (int g = 0; g < 16; g++) {
      int j = g * 64 + lane;
      bool s = false;
      if (j > i && j < PRE) {
        float ltx = fmaxf(x1, bx[j]);
        float lty = fmaxf(y1, by[j]);
        float rbx = fminf(X1, bX[j]);
        float rby = fminf(Y1, bY[j]);
        float ww = fmaxf(rbx - ltx, 0.0f);
        float hh = fmaxf(rby - lty, 0.0f);
        float inter = ww * hh;
        float iou = inter / ((ai + bar[j]) - inter + 1e-8f);
        s = iou > 0.5f;
      }
      u64 m = __ballot(s);
      if (lane == 0) supm[i * 16 + g] = m;
    }
  }
  __syncthreads();
  if (t < 64) {
    u64 kw = 0ull;
    if (t < 16) {
      for (int b = 0; b < 64; b++) {
        int k = t * 64 + b;
        if (k < PRE && ssc[k] != -INFINITY) kw |= (1ull << b);
      }
    }
    for (int i = 0; i < PRE; i++) {
      u64 ow = __shfl(kw, i >> 6);
      if ((ow >> (i & 63)) & 1ull) {
        if (t < 16) kw &= ~supm[i * 16 + t];
      }
    }
    if (t < 16) keepw[t] = kw;
  }
  __syncthreads();
  if (t == 0) {
    unsigned acc = 0;
    for (int w = 0; w < 16; w++) { wpre[w] = acc; acc += (unsigned)__popcll(keepw[w]); }
    wpre[16] = acc;
  }
  __syncthreads();
  const unsigned total = wpre[16];
  for (int k = t; k < PRE; k += 256) {
    int w = k >> 6, b = k & 63;
    u64 kw = keepw[w];
    if ((kw >> b) & 1ull) {
      unsigned rank = wpre[w] + (unsigned)__popcll(kw & ((1ull << b) - 1ull));
      if (rank < MAXD) {
        int slot = c * MAXD + (int)rank;
        out_s[slot] = ssc[k];
        out_id[slot] = (float)c;
        out_b[slot * 4 + 0] = bx[k];
        out_b[slot * 4 + 1] = by[k];
        out_b[slot * 4 + 2] = bX[k];
        out_b[slot * 4 + 3] = bY[k];
        out_d[slot] = dist[topidx[c * PRE + k]];
      }
    }
  }
  unsigned tk = total < MAXD ? total : MAXD;
  for (int r = (int)tk + t; r < MAXD; r += 256) {
    int slot = c * MAXD + r;
    out_s[slot] = 0.0f;
    out_id[slot] = -1.0f;
    out_b[slot * 4 + 0] = 0.0f; out_b[slot * 4 + 1] = 0.0f;
    out_b[slot * 4 + 2] = 0.0f; out_b[slot * 4 + 3] = 0.0f;
    out_d[slot] = 0.0f;
  }
}

// =====================================================================

static inline size_t align512(size_t x) { return (x + 511) & ~(size_t)511; }

extern "C" void kernel_launch(void* const* d_in, const int* in_sizes, int n_in,
                              void* d_out, int out_size, void* d_ws, size_t ws_size,
                              hipStream_t stream) {
  const float* cls  = (const float*)d_in[0];   // (1, A, 80)
  const float* reg  = (const float*)d_in[1];   // (1, A, 4)
  const float* dist = (const float*)d_in[2];   // (1, A, 1)
  const float* anch = (const float*)d_in[3];   // (1, A, 4)
  const int* img_h  = (const int*)d_in[4];
  const int* img_w  = (const int*)d_in[5];
  const int A = in_sizes[3] / 4;

  float* o = (float*)d_out;
  float* out_s  = o;                      // 8000
  float* out_id = o + NCLS * MAXD;        // 8000
  float* out_b  = o + 2 * NCLS * MAXD;    // 32000
  float* out_d  = o + 6 * NCLS * MAXD;    // 8000

  const int total4 = A * 20;  // A*80/4
  const int nblk = (total4 + 256 * K3K - 1) / (256 * K3K);   // k3 grid (~960)

  size_t off = 0;
  const size_t o_cand = off; off += align512((size_t)nblk * NCLS * SEGCAP * sizeof(u64)); // ~4.9 MB
  const size_t o_cnt  = off; off += align512((size_t)nblk * NCLS * sizeof(unsigned));     // ~307 KB
  const size_t needed = off;

  if (ws_size >= needed && nblk <= 4 * BT) {
    char* ws = (char*)d_ws;
    u64* cand = (u64*)(ws + o_cand);
    unsigned* cnt = (unsigned*)(ws + o_cnt);

    k3_collect<<<nblk, 256, 0, stream>>>((const vfloat4*)cls, total4, nblk, cnt, cand);
    kAD_sort_nms<<<NCLS, BT, 0, stream>>>(cnt, cand, nblk, cls, A, anch, reg, dist,
                                          img_h, img_w, out_s, out_id, out_b, out_d);
  } else {
    // fallback: proven round-1 path (needs only ~0.64 MB)
    float* topscore = (float*)d_ws;
    unsigned* topidx = (unsigned*)((char*)d_ws + NCLS * PRE * sizeof(float));
    select_topk<<<NCLS, 256, 0, stream>>>(cls, A, topscore, topidx);
    nms_out<<<NCLS, 256, 0, stream>>>(anch, reg, dist, topscore, topidx,
                                      img_h, img_w, out_s, out_id, out_b, out_d);
  }
}

// Round 17
// 44.041 us; speedup vs baseline: 2.9244x; 1.0036x over previous
//
#include <hip/hip_runtime.h>
#include <math.h>

#define NCLS 80
#define PRE 1000
#define MAXD 100
#define THR_SCORE 0.05f
#define TFIX 0.9985f           // fixed collection threshold (fast path)

#define SEGCAP 8               // candidates per (block, class) segment (1 cache line)
#define BT 512                 // kAD block threads
#define K3K 16                 // float4 loads per thread in k3 (MLP depth)

typedef unsigned long long u64;
typedef float vfloat4 __attribute__((ext_vector_type(4)));

__device__ __forceinline__ u64 readlane64(u64 v, int l) {
  unsigned lo = (unsigned)__builtin_amdgcn_readlane((int)(unsigned)v, l);
  unsigned hi = (unsigned)__builtin_amdgcn_readlane((int)(unsigned)(v >> 32), l);
  return ((u64)hi << 32) | lo;
}

// =====================================================================
// K3: tiled coalesced pass, 16-deep MLP, nt reads. Per-block private segments
// in TRANSPOSED layout (class-major) so kAD's gather is coalesced.
__global__ __launch_bounds__(256) void k3_collect(
    const vfloat4* __restrict__ cls4, int total4, int nblk,
    unsigned* __restrict__ cnt, u64* __restrict__ cand)
{
  __shared__ unsigned lcnt[NCLS];
  const int t = threadIdx.x;
  const int b = blockIdx.x;
  if (t < NCLS) lcnt[t] = 0u;
  __syncthreads();
  const int base = b * (256 * K3K) + t;
  vfloat4 v[K3K];
#pragma unroll
  for (int k = 0; k < K3K; k++) {
    int q = base + k * 256;
    if (q < total4) v[k] = __builtin_nontemporal_load(&cls4[q]);
    else v[k] = (vfloat4)(0.f);
  }
#pragma unroll
  for (int k = 0; k < K3K; k++) {
    int q = base + k * 256;
    if (q < total4) {
      int c0 = 4 * (q % 20);
      unsigned a = (unsigned)(q / 20);
      float sv[4] = {v[k].x, v[k].y, v[k].z, v[k].w};
#pragma unroll
      for (int e = 0; e < 4; e++) {
        float s = sv[e];
        if (s >= TFIX) {
          int c = c0 + e;
          unsigned p = atomicAdd(&lcnt[c], 1u);
          if (p < SEGCAP)
            cand[((size_t)c * nblk + b) * SEGCAP + p] =
                ((u64)__float_as_uint(s) << 32) | (u64)(~a);
        }
      }
    }
  }
  __syncthreads();
  if (t < NCLS) cnt[(size_t)t * nblk + b] = lcnt[t];
}

// NMS over sorted rows in LDS; wave 0 of the block (caller guards t<64).
__device__ __forceinline__ void nms_scan64(
    int windows, const float4* box4, const float* area, const float* ssc,
    float* fx, float* fy, float* fXX, float* fYY, float* fAA,
    float* wx, float* wy, float* wXX, float* wYY, float* wAA,
    u64* s_keep, unsigned* s_pre, unsigned* s_total, int lane)
{
#pragma clang fp contract(off)
  const double MID = 0x1.000001p-1;
  unsigned acc = 0;
  int nf = 0;
  for (int w = 0; w < windows; w++) {
    const int r = w * 64 + lane;
    const float4 rb = box4[r];
    const float ra = area[r];
    bool dead = (ssc[r] == -INFINITY);
    for (int f = 0; f < nf; f++) {
      float ltx = fmaxf(rb.x, fx[f]);
      float lty = fmaxf(rb.y, fy[f]);
      float rbx = fminf(rb.z, fXX[f]);
      float rby = fminf(rb.w, fYY[f]);
      float ww = fmaxf(rbx - ltx, 0.0f);
      float hh = fmaxf(rby - lty, 0.0f);
      float inter = ww * hh;
      float denom = ((ra + fAA[f]) - inter) + 1e-8f;
      dead = dead | ((double)inter > MID * (double)denom);
    }
    u64 alive = __ballot(!dead);
    u64 F = 0ull;
    if (alive) {
      wx[lane] = rb.x; wy[lane] = rb.y; wXX[lane] = rb.z; wYY[lane] = rb.w; wAA[lane] = ra;
      u64 Rw = 0ull;
#pragma unroll 4
      for (int i = 0; i < 64; i++) {
        float ltx = fmaxf(wx[i], rb.x);
        float lty = fmaxf(wy[i], rb.y);
        float rbx = fminf(wXX[i], rb.z);
        float rby = fminf(wYY[i], rb.w);
        float ww = fmaxf(rbx - ltx, 0.0f);
        float hh = fmaxf(rby - lty, 0.0f);
        float inter = ww * hh;
        float denom = ((wAA[i] + ra) - inter) + 1e-8f;
        bool io = (double)inter > MID * (double)denom;
        u64 m = __ballot(io & (lane > i));
        Rw = (lane == i) ? m : Rw;
      }
      while (alive) {
        int b = __builtin_ctzll(alive);
        F |= (1ull << b);
        u64 rbw = readlane64(Rw, b);
        alive &= ~(rbw | (1ull << b));
      }
      if ((F >> lane) & 1ull) {
        int pos = nf + (int)__popcll(F & ((1ull << lane) - 1ull));
        if (pos < 192) {
          fx[pos] = rb.x; fy[pos] = rb.y; fXX[pos] = rb.z; fYY[pos] = rb.w; fAA[pos] = ra;
        }
      }
    }
    if (lane == 0) { s_keep[w] = F; s_pre[w] = acc; }
    acc += (unsigned)__popcll(F);
    nf += (int)__popcll(F);
    if (acc >= (unsigned)MAXD) break;
  }
  if (lane == 0) *s_total = acc;
}

__device__ __forceinline__ void decode_one(
    u64 key, const float4* a4, const float4* r4, float W, float H,
    float4* obox, float* oarea, float* ossc, unsigned* oidx)
{
#pragma clang fp contract(off)
  float sc; unsigned idx;
  if (key != 0ull) {
    sc = __uint_as_float((unsigned)(key >> 32));
    idx = ~((unsigned)(key & 0xFFFFFFFFull));
  } else {
    sc = -INFINITY; idx = 0u;
  }
  float4 av = a4[idx];
  float4 rv = r4[idx];
  float w = av.z - av.x, h = av.w - av.y;
  float cx = av.x + 0.5f * w, cy = av.y + 0.5f * h;
  float dx = rv.x * 0.1f, dy = rv.y * 0.1f, dw = rv.z * 0.2f, dh = rv.w * 0.2f;
  float pcx = cx + dx * w, pcy = cy + dy * h;
  float pw = (float)exp((double)dw) * w;
  float ph = (float)exp((double)dh) * h;
  float x1 = fminf(fmaxf(pcx - 0.5f * pw, 0.0f), W);
  float y1 = fminf(fmaxf(pcy - 0.5f * ph, 0.0f), H);
  float x2 = fminf(fmaxf(pcx + 0.5f * pw, 0.0f), W);
  float y2 = fminf(fmaxf(pcy + 0.5f * ph, 0.0f), H);
  *obox = make_float4(x1, y1, x2, y2);
  *oarea = (x2 - x1) * (y2 - y1);
  *ossc = sc;
  *oidx = idx;
}

// kAD: coalesced segment gather (wave-scan offsets, vectorized 64B segment
// loads) -> direct sort-512 of the COMPLETE collected set -> decode ->
// early-exit NMS. Exact iff no segment overflow, n<=512, and kept>=100
// ({s>=TFIX} is a prefix of the global order); otherwise complete in-kernel
// legacy path from cls.
__global__ __launch_bounds__(BT) void kAD_sort_nms(
    const unsigned* __restrict__ cnt, const u64* __restrict__ cand, int nblk,
    const float* __restrict__ cls, int A,
    const float* __restrict__ anch, const float* __restrict__ reg,
    const float* __restrict__ dist,
    const int* __restrict__ img_h_p, const int* __restrict__ img_w_p,
    float* __restrict__ out_s, float* __restrict__ out_id,
    float* __restrict__ out_b, float* __restrict__ out_d)
{
#pragma clang fp contract(off)
  const int c = blockIdx.x;
  const int t = threadIdx.x;
  const int lane = t & 63;
  // carved LDS: slow path uses full regions; fast path aliases prefixes
  __shared__ __align__(16) char smem[61440];
  u64* candS = (u64*)smem;                          // 2048 u64 (fast: 512 sort buf | slow: sort buf)
  unsigned* histS = (unsigned*)(smem + 16384);      // slow: 4096 u32
  float4* box4 = (float4*)(smem + 32768);           // 1024 float4
  float* area  = (float*)(smem + 49152);            // 1024 f32
  float* ssc   = (float*)(smem + 53248);            // 1024 f32
  unsigned* sidb = (unsigned*)(smem + 57344);       // 1024 u32
  __shared__ unsigned s_ovf, s_gn, s_cnt;
  __shared__ int s_cb;
  __shared__ float fx[192], fy[192], fX[192], fY[192], fA[192];
  __shared__ float wx[64], wy[64], wX[64], wY[64], wA[64];
  __shared__ u64 s_keep[16];
  __shared__ unsigned s_pre[16];
  __shared__ unsigned s_total;

  if (t == 0) { s_ovf = 0u; s_gn = 0u; s_cnt = 0u; s_total = 0u; }
  if (t < 16) { s_keep[t] = 0ull; s_pre[t] = 0u; }
  candS[t] = 0ull;   // fast sort buffer [0,512)
  __syncthreads();

  // ---- gather phase 1: coalesced counts + wave-scan offsets ----
  const int ROUNDS = (nblk + BT - 1) / BT;   // 2 for nblk=960
  unsigned my_off[4];
  unsigned my_cv[4];
  int my_i[4];
  for (int r = 0; r < ROUNDS && r < 4; r++) {
    int i = r * BT + t;
    unsigned cv = 0u;
    if (i < nblk) cv = cnt[(size_t)c * nblk + i];
    if (cv > SEGCAP) { atomicOr(&s_ovf, 1u); cv = 0u; }
    unsigned incl = cv;
#pragma unroll
    for (int d = 1; d < 64; d <<= 1) {
      unsigned x = __shfl_up(incl, d);
      if (lane >= d) incl += x;
    }
    unsigned wtot = __shfl(incl, 63);
    unsigned wbase = 0u;
    if (lane == 63) wbase = atomicAdd(&s_gn, wtot);
    wbase = __shfl(wbase, 63);
    my_off[r] = wbase + incl - cv;
    my_cv[r] = cv;
    my_i[r] = i;
  }
  __syncthreads();
  const unsigned n = s_gn;
  const bool fits = (s_ovf == 0u) && (n >= 1u) && (n <= 512u);

  const float W = (float)img_w_p[0];
  const float H = (float)img_h_p[0];
  const float4* a4 = (const float4*)anch;
  const float4* r4 = (const float4*)reg;
  bool slow = true;

  if (fits) {
    // ---- gather phase 2: vectorized segment copy (4 independent 16B loads;
    // junk beyond cv discarded; compile-time store indices) ----
    for (int r = 0; r < ROUNDS && r < 4; r++) {
      unsigned cv = my_cv[r];
      if (cv) {
        const ulonglong2* src2 =
            (const ulonglong2*)(cand + ((size_t)c * nblk + my_i[r]) * SEGCAP);
        ulonglong2 s0 = src2[0];
        ulonglong2 s1 = src2[1];
        ulonglong2 s2 = src2[2];
        ulonglong2 s3 = src2[3];
        unsigned o = my_off[r];
        candS[o] = s0.x;
        if (cv > 1) candS[o + 1] = s0.y;
        if (cv > 2) candS[o + 2] = s1.x;
        if (cv > 3) candS[o + 3] = s1.y;
        if (cv > 4) candS[o + 4] = s2.x;
        if (cv > 5) candS[o + 5] = s2.y;
        if (cv > 6) candS[o + 6] = s3.x;
        if (cv > 7) candS[o + 7] = s3.y;
      }
    }
    __syncthreads();
    // ---- hybrid bitonic sort of 512 desc (1 elem/thread; proven) ----
    u64* SW = candS;
    {
      u64 v = SW[t];
#pragma unroll
      for (int k = 2; k <= 64; k <<= 1) {
#pragma unroll
        for (int j = k >> 1; j > 0; j >>= 1) {
          u64 p = __shfl_xor(v, j);
          bool iLower = (lane & j) == 0;
          bool desc = (t & k) == 0;
          bool keepMax = (iLower == desc);
          bool pGreater = p > v;
          v = (keepMax == pGreater) ? p : v;
        }
      }
      SW[t] = v;
      __syncthreads();
      for (int k = 128; k <= 512; k <<= 1) {
        for (int j = k >> 1; j >= 64; j >>= 1) {
          if ((t & j) == 0) {
            u64 a = SW[t], b = SW[t ^ j];
            bool desc = ((t & k) == 0);
            if (desc ? (a < b) : (a > b)) { SW[t] = b; SW[t ^ j] = a; }
          }
          __syncthreads();
        }
        u64 v2 = SW[t];
        bool desc = ((t & k) == 0);
#pragma unroll
        for (int j = 32; j > 0; j >>= 1) {
          u64 p = __shfl_xor(v2, j);
          bool iLower = (lane & j) == 0;
          bool keepMax = (iLower == desc);
          bool pGreater = p > v2;
          v2 = (keepMax == pGreater) ? p : v2;
        }
        SW[t] = v2;
        __syncthreads();
      }
    }
    // ---- decode row t ----
    decode_one(SW[t], a4, r4, W, H, &box4[t], &area[t], &ssc[t], &sidb[t]);
    __syncthreads();
    if (t < 64)
      nms_scan64(8, box4, area, ssc, fx, fy, fX, fY, fA, wx, wy, wX, wY, wA,
                 s_keep, s_pre, &s_total, lane);
    __syncthreads();
    slow = (s_total < (unsigned)MAXD);   // kept>=100 => provably exact
  }

  if (slow) {
    // ---- complete legacy path from cls (round-1 proven; correctness-only) ----
    if (t == 0) { s_cnt = 0u; s_total = 0u; }
    if (t < 16) { s_keep[t] = 0ull; s_pre[t] = 0u; }
    for (int i = t; i < 4096; i += BT) histS[i] = 0u;
    __syncthreads();
    for (int a = t; a < A; a += BT) {
      float s = cls[(size_t)a * NCLS + c];
      if (s > THR_SCORE) {
        int b = (int)(s * 4096.0f);
        b = b < 0 ? 0 : (b > 4095 ? 4095 : b);
        atomicAdd(&histS[b], 1u);
      }
    }
    __syncthreads();
    if (t == 0) {
      unsigned acc = 0;
      int cb = 0;
      for (int b = 4095; b >= 0; b--) {
        acc += histS[b];
        if (acc >= (unsigned)PRE) { cb = b; break; }
      }
      if (acc < (unsigned)PRE) cb = 0;
      while (acc > 2048u && cb < 4095) { acc -= histS[cb]; cb++; }
      s_cb = cb;
    }
    __syncthreads();
    const int cb = s_cb;
    for (int i = t; i < 2048; i += BT) candS[i] = 0ull;
    __syncthreads();
    for (int a = t; a < A; a += BT) {
      float s = cls[(size_t)a * NCLS + c];
      if (s > THR_SCORE) {
        int b = (int)(s * 4096.0f);
        b = b < 0 ? 0 : (b > 4095 ? 4095 : b);
        if (b >= cb) {
          unsigned p = atomicAdd(&s_cnt, 1u);
          if (p < 2048u)
            candS[p] = ((u64)__float_as_uint(s) << 32) | (u64)(~(unsigned)a);
        }
      }
    }
    __syncthreads();
    for (int k = 2; k <= 2048; k <<= 1) {
      for (int j = k >> 1; j > 0; j >>= 1) {
        for (int i = t; i < 2048; i += BT) {
          int ixj = i ^ j;
          if (ixj > i) {
            u64 va = candS[i], vb = candS[ixj];
            bool desc = ((i & k) == 0);
            if (desc ? (va < vb) : (va > vb)) { candS[i] = vb; candS[ixj] = va; }
          }
        }
        __syncthreads();
      }
    }
    for (int i = t; i < 1024; i += BT) {
      u64 key = (i < PRE) ? candS[i] : 0ull;
      decode_one(key, a4, r4, W, H, &box4[i], &area[i], &ssc[i], &sidb[i]);
      if (i >= PRE) ssc[i] = -INFINITY;
    }
    __syncthreads();
    if (t < 64)
      nms_scan64(16, box4, area, ssc, fx, fy, fX, fY, fA, wx, wy, wX, wY, wA,
                 s_keep, s_pre, &s_total, lane);
    __syncthreads();
  }

  // ---- output ----
  const unsigned total = s_total;
  for (int k = t; k < PRE; k += BT) {
    int w = k >> 6, b = k & 63;
    u64 kw = s_keep[w];
    if ((kw >> b) & 1ull) {
      unsigned rank = s_pre[w] + (unsigned)__popcll(kw & ((1ull << b) - 1ull));
      if (rank < MAXD) {
        int slot = c * MAXD + (int)rank;
        out_s[slot] = ssc[k];
        out_id[slot] = (float)c;
        ((float4*)out_b)[slot] = box4[k];
        out_d[slot] = dist[sidb[k]];
      }
    }
  }
  unsigned tk = total < (unsigned)MAXD ? total : (unsigned)MAXD;
  for (int r2 = (int)tk + t; r2 < MAXD; r2 += BT) {
    int slot = c * MAXD + r2;
    out_s[slot] = 0.0f;
    out_id[slot] = -1.0f;
    ((float4*)out_b)[slot] = make_float4(0.f, 0.f, 0.f, 0.f);
    out_d[slot] = 0.0f;
  }
}

// =====================================================================
// FALLBACK PATH (round-1, proven correct; used only if ws is too small)
// =====================================================================
#define NBUCK 4096
#define CANDF 2048

__global__ __launch_bounds__(256) void select_topk(
    const float* __restrict__ cls, int A,
    float* __restrict__ topscore, unsigned* __restrict__ topidx)
{
  const int c = blockIdx.x;
  const int t = threadIdx.x;
  __shared__ unsigned hist[NBUCK];
  __shared__ u64 cand[CANDF];
  __shared__ unsigned chunk[256];
  __shared__ int s_cb;
  __shared__ int s_cnt;
  for (int i = t; i < NBUCK; i += 256) hist[i] = 0u;
  if (t == 0) s_cnt = 0;
  __syncthreads();
  for (int a = t; a < A; a += 256) {
    float s = cls[(size_t)a * NCLS + c];
    if (s > THR_SCORE) {
      int b = (int)(s * (float)NBUCK);
      b = b < 0 ? 0 : (b > NBUCK - 1 ? NBUCK - 1 : b);
      atomicAdd(&hist[b], 1u);
    }
  }
  __syncthreads();
  {
    unsigned cs = 0;
    for (int i = 0; i < NBUCK / 256; i++) cs += hist[t * (NBUCK / 256) + i];
    chunk[t] = cs;
  }
  __syncthreads();
  if (t == 0) {
    unsigned acc = 0;
    int cb = 0;
    int ch;
    for (ch = 255; ch >= 0; ch--) {
      if (acc + chunk[ch] >= (unsigned)PRE) break;
      acc += chunk[ch];
    }
    if (ch < 0) cb = 0;
    else {
      const int bpc = NBUCK / 256;
      int b = ch * bpc + bpc - 1;
      for (; b >= ch * bpc; b--) { acc += hist[b]; if (acc >= (unsigned)PRE) break; }
      if (b < ch * bpc) b = ch * bpc;
      cb = b;
      while (acc > (unsigned)CANDF && cb < NBUCK - 1) { acc -= hist[cb]; cb++; }
    }
    s_cb = cb;
  }
  __syncthreads();
  const int cb = s_cb;
  for (int a = t; a < A; a += 256) {
    float s = cls[(size_t)a * NCLS + c];
    if (s > THR_SCORE) {
      int b = (int)(s * (float)NBUCK);
      b = b < 0 ? 0 : (b > NBUCK - 1 ? NBUCK - 1 : b);
      if (b >= cb) {
        int p = atomicAdd(&s_cnt, 1);
        if (p < CANDF)
          cand[p] = ((u64)__float_as_uint(s) << 32) | (u64)(~(unsigned)a);
      }
    }
  }
  __syncthreads();
  int n = s_cnt < CANDF ? s_cnt : CANDF;
  for (int i = n + t; i < CANDF; i += 256) cand[i] = 0ull;
  __syncthreads();
  for (int k = 2; k <= CANDF; k <<= 1) {
    for (int j = k >> 1; j > 0; j >>= 1) {
      for (int i = t; i < CANDF; i += 256) {
        int ixj = i ^ j;
        if (ixj > i) {
          u64 va = cand[i], vb = cand[ixj];
          bool desc = ((i & k) == 0);
          if (desc ? (va < vb) : (va > vb)) { cand[i] = vb; cand[ixj] = va; }
        }
      }
      __syncthreads();
    }
  }
  for (int k = t; k < PRE; k += 256) {
    u64 key = cand[k];
    float sc; unsigned idx;
    if (key != 0ull) { sc = __uint_as_float((unsigned)(key >> 32)); idx = ~((unsigned)(key & 0xFFFFFFFFull)); }
    else { sc = -INFINITY; idx = 0u; }
    topscore[c * PRE + k] = sc;
    topidx[c * PRE + k] = idx;
  }
}

__global__ __launch_bounds__(256) void nms_out(
    const float* __restrict__ anch, const float* __restrict__ reg,
    const float* __restrict__ dist,
    const float* __restrict__ topscore, const unsigned* __restrict__ topidx,
    const int* __restrict__ img_h_p, const int* __restrict__ img_w_p,
    float* __restrict__ out_s, float* __restrict__ out_id,
    float* __restrict__ out_b, float* __restrict__ out_d)
{
#pragma clang fp contract(off)
  const int c = blockIdx.x;
  const int t = threadIdx.x;
  __shared__ float bx[PRE], by[PRE], bX[PRE], bY[PRE], bar[PRE], ssc[PRE];
  __shared__ u64 supm[PRE * 16];
  __shared__ u64 keepw[16];
  __shared__ unsigned wpre[17];
  const float W = (float)img_w_p[0];
  const float H = (float)img_h_p[0];
  for (int k = t; k < PRE; k += 256) {
    float sc = topscore[c * PRE + k];
    unsigned idx = topidx[c * PRE + k];
    ssc[k] = sc;
    float a0 = anch[(size_t)idx * 4 + 0], a1 = anch[(size_t)idx * 4 + 1];
    float a2 = anch[(size_t)idx * 4 + 2], a3 = anch[(size_t)idx * 4 + 3];
    float r0 = reg[(size_t)idx * 4 + 0], r1 = reg[(size_t)idx * 4 + 1];
    float r2 = reg[(size_t)idx * 4 + 2], r3 = reg[(size_t)idx * 4 + 3];
    float w = a2 - a0, h = a3 - a1;
    float cx = a0 + 0.5f * w, cy = a1 + 0.5f * h;
    float dx = r0 * 0.1f, dy = r1 * 0.1f, dw = r2 * 0.2f, dh = r3 * 0.2f;
    float pcx = cx + dx * w, pcy = cy + dy * h;
    float pw = (float)exp((double)dw) * w;
    float ph = (float)exp((double)dh) * h;
    float x1 = fminf(fmaxf(pcx - 0.5f * pw, 0.0f), W);
    float y1 = fminf(fmaxf(pcy - 0.5f * ph, 0.0f), H);
    float x2 = fminf(fmaxf(pcx + 0.5f * pw, 0.0f), W);
    float y2 = fminf(fmaxf(pcy + 0.5f * ph, 0.0f), H);
    bx[k] = x1; by[k] = y1; bX[k] = x2; bY[k] = y2;
    bar[k] = (x2 - x1) * (y2 - y1);
  }
  __syncthreads();
  const int wave = t >> 6, lane = t & 63;
  for (int i = wave; i < PRE; i += 4) {
    float x1 = bx[i], y1 = by[i], X1 = bX[i], Y1 = bY[i], ai = bar[i];
    for (int g = 0; g < 16; g++) {
      int j = g * 64 + lane;
      bool s = false;
      if (j > i && j < PRE) {
        float ltx = fmaxf(x1, bx[j]);
        float lty = fmaxf(y1, by[j]);
        float rbx = fminf(X1, bX[j]);
        float rby = fminf(Y1, bY[j]);
        float ww = fmaxf(rbx - ltx, 0.0f);
        float hh = fmaxf(rby - lty, 0.0f);
        float inter = ww * hh;
        float iou = inter / ((ai + bar[j]) - inter + 1e-8f);
        s = iou > 0.5f;
      }
      u64 m = __ballot(s);
      if (lane == 0) supm[i * 16 + g] = m;
    }
  }
  __syncthreads();
  if (t < 64) {
    u64 kw = 0ull;
    if (t < 16) {
      for (int b = 0; b < 64; b++) {
        int k = t * 64 + b;
        if (k < PRE && ssc[k] != -INFINITY) kw |= (1ull << b);
      }
    }
    for (int i = 0; i < PRE; i++) {
      u64 ow = __shfl(kw, i >> 6);
      if ((ow >> (i & 63)) & 1ull) {
        if (t < 16) kw &= ~supm[i * 16 + t];
      }
    }
    if (t < 16) keepw[t] = kw;
  }
  __syncthreads();
  if (t == 0) {
    unsigned acc = 0;
    for (int w = 0; w < 16; w++) { wpre[w] = acc; acc += (unsigned)__popcll(keepw[w]); }
    wpre[16] = acc;
  }
  __syncthreads();
  const unsigned total = wpre[16];
  for (int k = t; k < PRE; k += 256) {
    int w = k >> 6, b = k & 63;
    u64 kw = keepw[w];
    if ((kw >> b) & 1ull) {
      unsigned rank = wpre[w] + (unsigned)__popcll(kw & ((1ull << b) - 1ull));
      if (rank < MAXD) {
        int slot = c * MAXD + (int)rank;
        out_s[slot] = ssc[k];
        out_id[slot] = (float)c;
        out_b[slot * 4 + 0] = bx[k];
        out_b[slot * 4 + 1] = by[k];
        out_b[slot * 4 + 2] = bX[k];
        out_b[slot * 4 + 3] = bY[k];
        out_d[slot] = dist[topidx[c * PRE + k]];
      }
    }
  }
  unsigned tk = total < MAXD ? total : MAXD;
  for (int r = (int)tk + t; r < MAXD; r += 256) {
    int slot = c * MAXD + r;
    out_s[slot] = 0.0f;
    out_id[slot] = -1.0f;
    out_b[slot * 4 + 0] = 0.0f; out_b[slot * 4 + 1] = 0.0f;
    out_b[slot * 4 + 2] = 0.0f; out_b[slot * 4 + 3] = 0.0f;
    out_d[slot] = 0.0f;
  }
}

// =====================================================================

static inline size_t align512(size_t x) { return (x + 511) & ~(size_t)511; }

extern "C" void kernel_launch(void* const* d_in, const int* in_sizes, int n_in,
                              void* d_out, int out_size, void* d_ws, size_t ws_size,
                              hipStream_t stream) {
  const float* cls  = (const float*)d_in[0];   // (1, A, 80)
  const float* reg  = (const float*)d_in[1];   // (1, A, 4)
  const float* dist = (const float*)d_in[2];   // (1, A, 1)
  const float* anch = (const float*)d_in[3];   // (1, A, 4)
  const int* img_h  = (const int*)d_in[4];
  const int* img_w  = (const int*)d_in[5];
  const int A = in_sizes[3] / 4;

  float* o = (float*)d_out;
  float* out_s  = o;                      // 8000
  float* out_id = o + NCLS * MAXD;        // 8000
  float* out_b  = o + 2 * NCLS * MAXD;    // 32000
  float* out_d  = o + 6 * NCLS * MAXD;    // 8000

  const int total4 = A * 20;  // A*80/4
  const int nblk = (total4 + 256 * K3K - 1) / (256 * K3K);   // k3 grid (~960)

  size_t off = 0;
  const size_t o_cand = off; off += align512((size_t)nblk * NCLS * SEGCAP * sizeof(u64)); // ~4.9 MB
  const size_t o_cnt  = off; off += align512((size_t)nblk * NCLS * sizeof(unsigned));     // ~307 KB
  const size_t needed = off;

  if (ws_size >= needed && nblk <= 4 * BT) {
    char* ws = (char*)d_ws;
    u64* cand = (u64*)(ws + o_cand);
    unsigned* cnt = (unsigned*)(ws + o_cnt);

    k3_collect<<<nblk, 256, 0, stream>>>((const vfloat4*)cls, total4, nblk, cnt, cand);
    kAD_sort_nms<<<NCLS, BT, 0, stream>>>(cnt, cand, nblk, cls, A, anch, reg, dist,
                                          img_h, img_w, out_s, out_id, out_b, out_d);
  } else {
    // fallback: proven round-1 path (needs only ~0.64 MB)
    float* topscore = (float*)d_ws;
    unsigned* topidx = (unsigned*)((char*)d_ws + NCLS * PRE * sizeof(float));
    select_topk<<<NCLS, 256, 0, stream>>>(cls, A, topscore, topidx);
    nms_out<<<NCLS, 256, 0, stream>>>(anch, reg, dist, topscore, topidx,
                                      img_h, img_w, out_s, out_id, out_b, out_d);
  }
}